// Round 1
// baseline (2443.899 us; speedup 1.0000x reference)
//
#include <hip/hip_runtime.h>
#include <math.h>

// ---------------- problem constants ----------------
// B=8, C=256, NH=8, CH=32, MLP_H=1024, EPS=1e-5
// scales: H = 56,28,14,7 ; N = H*H+1 ; R = B*N
static const int HS[4]     = {56, 28, 14, 7};
static const int NS[4]     = {3137, 785, 197, 50};
static const int ROWOFF[4] = {0, 25096, 31376, 32952};      // cumulative B*N
// output offsets (floats): x1 first, then xs0..xs3
static const size_t OUTOFF[4] = {25692160ull, 32116736ull, 33724416ull, 34127872ull};

#define DEV __device__ __forceinline__

// ---------------- x1 passthrough ----------------
__global__ void copy_f4(const float4* __restrict__ src, float4* __restrict__ dst, int n4) {
  for (int i = blockIdx.x * blockDim.x + threadIdx.x; i < n4; i += gridDim.x * blockDim.x)
    dst[i] = src[i];
}

// ---------------- CPE: depthwise 3x3 + bias + residual (cls row passthrough) ----------------
__global__ void cpe_kernel(const float* __restrict__ x, const float* __restrict__ w,
                           const float* __restrict__ bias, float* __restrict__ out,
                           int N, int H, int total) {
  int W = H;
  for (int idx = blockIdx.x * blockDim.x + threadIdx.x; idx < total; idx += gridDim.x * blockDim.x) {
    int c = idx & 255;
    int row = idx >> 8;
    int n = row % N;
    int b = row / N;
    float xv = x[idx];
    if (n == 0) { out[idx] = xv; continue; }
    int p = n - 1, h0 = p / W, w0 = p % W;
    float acc = bias[c];
    const float* wc = w + c * 9;
    #pragma unroll
    for (int kh = 0; kh < 3; ++kh) {
      int hh = h0 + kh - 1;
      if (hh < 0 || hh >= H) continue;
      #pragma unroll
      for (int kw = 0; kw < 3; ++kw) {
        int ww = w0 + kw - 1;
        if (ww < 0 || ww >= W) continue;
        acc += x[(((size_t)b * N) + 1 + hh * W + ww) * 256 + c] * wc[kh * 3 + kw];
      }
    }
    out[idx] = acc + xv;
  }
}

// ---------------- LayerNorm over C=256, one wave per row ----------------
__global__ void ln_kernel(const float* __restrict__ x, const float* __restrict__ g,
                          const float* __restrict__ bt, float* __restrict__ out, int rows) {
  int wid = threadIdx.x >> 6, lane = threadIdx.x & 63;
  int row = blockIdx.x * 4 + wid;
  if (row >= rows) return;
  const float* xr = x + (size_t)row * 256;
  float4 v = *(const float4*)(xr + lane * 4);
  float s = v.x + v.y + v.z + v.w;
  #pragma unroll
  for (int off = 32; off; off >>= 1) s += __shfl_down(s, off);
  s = __shfl(s, 0);
  float mu = s * (1.0f / 256.0f);
  float dx = v.x - mu, dy = v.y - mu, dz = v.z - mu, dw = v.w - mu;
  float q = dx * dx + dy * dy + dz * dz + dw * dw;
  #pragma unroll
  for (int off = 32; off; off >>= 1) q += __shfl_down(q, off);
  q = __shfl(q, 0);
  float rs = rsqrtf(q * (1.0f / 256.0f) + 1e-5f);
  float4 gg = *(const float4*)(g + lane * 4);
  float4 bb = *(const float4*)(bt + lane * 4);
  float4 o;
  o.x = dx * rs * gg.x + bb.x;
  o.y = dy * rs * gg.y + bb.y;
  o.z = dz * rs * gg.z + bb.z;
  o.w = dw * rs * gg.w + bb.w;
  *(float4*)(out + (size_t)row * 256 + lane * 4) = o;
}

// ---------------- generic fp32 GEMM: out[M,Nout] = A[M,K] @ Wt[Nout,K]^T (+bias)(+gelu)(+res) ----------------
template <bool GELU>
__launch_bounds__(256)
__global__ void gemm_nt(const float* __restrict__ A, const float* __restrict__ Wt,
                        const float* __restrict__ bias, const float* __restrict__ res,
                        float* __restrict__ out, int M, int K, int Nout) {
  __shared__ float As[16][68];
  __shared__ float Bs[16][68];
  int bm = blockIdx.x << 6, bn = blockIdx.y << 6;
  int t = threadIdx.x;
  int tm = (t >> 4) << 2, tn = (t & 15) << 2;
  int lr = t >> 2, lk = (t & 3) << 2;
  float acc[4][4] = {};
  int am = bm + lr;
  const float* arow = A + (size_t)am * K + lk;
  const float* brow = Wt + (size_t)(bn + lr) * K + lk;
  for (int k0 = 0; k0 < K; k0 += 16) {
    float4 av = (am < M) ? *(const float4*)(arow + k0) : make_float4(0.f, 0.f, 0.f, 0.f);
    float4 bv = *(const float4*)(brow + k0);
    As[lk + 0][lr] = av.x; As[lk + 1][lr] = av.y; As[lk + 2][lr] = av.z; As[lk + 3][lr] = av.w;
    Bs[lk + 0][lr] = bv.x; Bs[lk + 1][lr] = bv.y; Bs[lk + 2][lr] = bv.z; Bs[lk + 3][lr] = bv.w;
    __syncthreads();
    #pragma unroll
    for (int kk = 0; kk < 16; ++kk) {
      float a0 = As[kk][tm + 0], a1 = As[kk][tm + 1], a2 = As[kk][tm + 2], a3 = As[kk][tm + 3];
      float b0 = Bs[kk][tn + 0], b1 = Bs[kk][tn + 1], b2 = Bs[kk][tn + 2], b3 = Bs[kk][tn + 3];
      acc[0][0] += a0 * b0; acc[0][1] += a0 * b1; acc[0][2] += a0 * b2; acc[0][3] += a0 * b3;
      acc[1][0] += a1 * b0; acc[1][1] += a1 * b1; acc[1][2] += a1 * b2; acc[1][3] += a1 * b3;
      acc[2][0] += a2 * b0; acc[2][1] += a2 * b1; acc[2][2] += a2 * b2; acc[2][3] += a2 * b3;
      acc[3][0] += a3 * b0; acc[3][1] += a3 * b1; acc[3][2] += a3 * b2; acc[3][3] += a3 * b3;
    }
    __syncthreads();
  }
  #pragma unroll
  for (int i = 0; i < 4; ++i) {
    int m = bm + tm + i;
    if (m >= M) continue;
    #pragma unroll
    for (int j = 0; j < 4; ++j) {
      int ncol = bn + tn + j;
      float v = acc[i][j];
      if (bias) v += bias[ncol];
      if (GELU) v = 0.5f * v * (1.0f + erff(v * 0.70710678118654752f));
      size_t o = (size_t)m * Nout + ncol;
      if (res) v += res[o];
      out[o] = v;
    }
  }
}

// ---------------- softmax over tokens (axis=N) for k: per (b, cg) max & sumexp ----------------
__global__ void ksm_partial(const float* __restrict__ qkv, float* __restrict__ pm,
                            float* __restrict__ ps, int N, int CS, int NCH) {
  int b = blockIdx.y, ch = blockIdx.x, cg = threadIdx.x;
  int n0 = ch * CS, n1 = min(N, n0 + CS);
  float m = -1e30f, s = 0.f;
  for (int n = n0; n < n1; ++n) {
    float v = qkv[((size_t)(b * N + n)) * 768 + 256 + cg];
    float nm = fmaxf(m, v);
    s = s * __expf(m - nm) + __expf(v - nm);
    m = nm;
  }
  pm[(b * NCH + ch) * 256 + cg] = m;
  ps[(b * NCH + ch) * 256 + cg] = s;
}

__global__ void ksm_merge(const float* __restrict__ pm, const float* __restrict__ ps,
                          float* __restrict__ mx, float* __restrict__ se, int NCH) {
  int b = blockIdx.x, cg = threadIdx.x;
  float m = -1e30f, s = 0.f;
  for (int c = 0; c < NCH; ++c) {
    float mc = pm[(b * NCH + c) * 256 + cg];
    float sc = ps[(b * NCH + c) * 256 + cg];
    float nm = fmaxf(m, mc);
    s = s * __expf(m - nm) + sc * __expf(mc - nm);
    m = nm;
  }
  mx[b * 256 + cg] = m;
  se[b * 256 + cg] = s;
}

// ---------------- kv[b,h,i,j] = sum_n softmax(k)[n,i] * v[n,j] ----------------
__launch_bounds__(1024)
__global__ void kv_kernel(const float* __restrict__ qkv, const float* __restrict__ mx,
                          const float* __restrict__ se, float* __restrict__ kv, int N) {
  __shared__ float kl[32][33];
  __shared__ float vl[32][33];
  int b = blockIdx.x >> 3, h = blockIdx.x & 7;
  int t = threadIdx.x;
  int i = t >> 5, j = t & 31;
  float mexp = mx[b * 256 + h * 32 + j];  // for exp stage: column j of row (t>>5)
  float acc = 0.f;
  for (int n0 = 0; n0 < N; n0 += 32) {
    // load 32 rows x (32 k + 32 v)
    #pragma unroll
    for (int e = t; e < 2048; e += 1024) {
      int r = e >> 6, cc = e & 63;
      int n = n0 + r;
      if (cc < 32) kl[r][cc] = (n < N) ? qkv[((size_t)(b * N + n)) * 768 + 256 + h * 32 + cc] : -1e30f;
      else         vl[r][cc - 32] = (n < N) ? qkv[((size_t)(b * N + n)) * 768 + 512 + h * 32 + (cc - 32)] : 0.f;
    }
    __syncthreads();
    // exp stage: thread handles (row = t>>5, col = t&31)
    kl[i][j] = __expf(kl[i][j] - mexp);
    __syncthreads();
    #pragma unroll
    for (int nn = 0; nn < 32; ++nn) acc += kl[nn][i] * vl[nn][j];
    __syncthreads();
  }
  kv[(((size_t)b * 8 + h) * 32 + i) * 32 + j] = acc / se[b * 256 + h * 32 + i];
}

// ---------------- CRPE depthwise convs (3/5/7 over channel groups) on v ----------------
__global__ void crpe_kernel(const float* __restrict__ qkv,
                            const float* __restrict__ w3, const float* __restrict__ b3,
                            const float* __restrict__ w5, const float* __restrict__ b5,
                            const float* __restrict__ w7, const float* __restrict__ b7,
                            float* __restrict__ convv, int N, int H, int total) {
  int W = H, HW = H * W;
  for (int idx = blockIdx.x * blockDim.x + threadIdx.x; idx < total; idx += gridDim.x * blockDim.x) {
    int c = idx & 255;
    int pr = idx >> 8;
    int p = pr % HW;
    int b = pr / HW;
    int h0 = p / W, w0 = p % W;
    int ks;
    const float* wp;
    float acc;
    if (c < 64)       { ks = 3; wp = w3 + c * 9;          acc = b3[c]; }
    else if (c < 160) { ks = 5; wp = w5 + (c - 64) * 25;  acc = b5[c - 64]; }
    else              { ks = 7; wp = w7 + (c - 160) * 49; acc = b7[c - 160]; }
    int pad = ks >> 1;
    for (int kh = 0; kh < ks; ++kh) {
      int hh = h0 + kh - pad;
      if (hh < 0 || hh >= H) continue;
      for (int kw = 0; kw < ks; ++kw) {
        int ww = w0 + kw - pad;
        if (ww < 0 || ww >= W) continue;
        acc += qkv[(((size_t)b * N) + 1 + hh * W + ww) * 768 + 512 + c] * wp[kh * ks + kw];
      }
    }
    convv[idx] = acc;
  }
}

// ---------------- att: attp = CH^-0.5 * (q @ kv) + [n>0] q * conv_v ----------------
__global__ void att_combine(const float* __restrict__ qkv, const float* __restrict__ kvg,
                            const float* __restrict__ convv, float* __restrict__ attp,
                            int N, int HW) {
  __shared__ float kvl[8192];
  __shared__ float ql[256];
  int b = blockIdx.y;
  int n0 = blockIdx.x * 16;
  int t = threadIdx.x;
  for (int e = t; e < 8192; e += 256) kvl[e] = kvg[(size_t)b * 8192 + e];
  int h = t >> 5, j = t & 31;
  for (int nn = 0; nn < 16; ++nn) {
    int n = n0 + nn;
    if (n >= N) break;
    __syncthreads();
    ql[t] = qkv[((size_t)(b * N + n)) * 768 + t];
    __syncthreads();
    float fa = 0.f;
    const float* kvh = kvl + h * 1024;
    #pragma unroll
    for (int k = 0; k < 32; ++k) fa += ql[h * 32 + k] * kvh[k * 32 + j];
    float v = 0.17677669529663687f * fa;  // 32^-0.5
    if (n > 0) v += ql[t] * convv[(((size_t)b * HW) + (n - 1)) * 256 + t];
    attp[(((size_t)b * N) + n) * 256 + t] = v;
  }
}

// ---------------- cross-scale bilinear combine (jax half-pixel, edge-clamped) ----------------
DEV float bsample(const float* __restrict__ src, int b, int Ns, int Hs,
                  int oh, int ow, int Hi, int c) {
  float scale = (float)Hs / (float)Hi;
  float sy = (oh + 0.5f) * scale - 0.5f;
  float sx = (ow + 0.5f) * scale - 0.5f;
  float fy0 = floorf(sy), fx0 = floorf(sx);
  float fy = sy - fy0, fx = sx - fx0;
  int y0 = (int)fy0, x0 = (int)fx0;
  int y0c = min(max(y0, 0), Hs - 1), y1c = min(max(y0 + 1, 0), Hs - 1);
  int x0c = min(max(x0, 0), Hs - 1), x1c = min(max(x0 + 1, 0), Hs - 1);
  const float* base = src + ((size_t)b * Ns + 1) * 256 + c;
  float v00 = base[(size_t)(y0c * Hs + x0c) * 256];
  float v01 = base[(size_t)(y0c * Hs + x1c) * 256];
  float v10 = base[(size_t)(y1c * Hs + x0c) * 256];
  float v11 = base[(size_t)(y1c * Hs + x1c) * 256];
  return (1.f - fy) * ((1.f - fx) * v00 + fx * v01) + fy * ((1.f - fx) * v10 + fx * v11);
}

__global__ void combine_kernel(float* __restrict__ xi, const float* __restrict__ ci,
                               const float* __restrict__ srcA, int HsA, int NsA,
                               const float* __restrict__ srcB, int HsB, int NsB,
                               int Ni, int Hi, int total) {
  for (int idx = blockIdx.x * blockDim.x + threadIdx.x; idx < total; idx += gridDim.x * blockDim.x) {
    int c = idx & 255;
    int row = idx >> 8;
    int n = row % Ni;
    int b = row / Ni;
    float add = ci[idx];
    if (n == 0) {
      add += srcA[((size_t)b * NsA) * 256 + c] + srcB[((size_t)b * NsB) * 256 + c];
    } else {
      int p = n - 1, oh = p / Hi, ow = p % Hi;
      add += bsample(srcA, b, NsA, HsA, oh, ow, Hi, c);
      add += bsample(srcB, b, NsB, HsB, oh, ow, Hi, c);
    }
    xi[idx] += add;
  }
}

// ---------------- host ----------------
extern "C" void kernel_launch(void* const* d_in, const int* in_sizes, int n_in,
                              void* d_out, int out_size, void* d_ws, size_t ws_size,
                              hipStream_t stream) {
  const float* x1 = (const float*)d_in[0];
  const float* xin[4] = {(const float*)d_in[1], (const float*)d_in[2],
                         (const float*)d_in[3], (const float*)d_in[4]};
  const float* cpe_w  = (const float*)d_in[5];
  const float* cpe_b  = (const float*)d_in[6];
  const float* n1_g   = (const float*)d_in[7];
  const float* n1_b   = (const float*)d_in[8];
  const float* qkv_w  = (const float*)d_in[9];
  const float* proj_w = (const float*)d_in[10];
  const float* proj_b = (const float*)d_in[11];
  const float* crpe_w3 = (const float*)d_in[12];
  const float* crpe_b3 = (const float*)d_in[13];
  const float* crpe_w5 = (const float*)d_in[14];
  const float* crpe_b5 = (const float*)d_in[15];
  const float* crpe_w7 = (const float*)d_in[16];
  const float* crpe_b7 = (const float*)d_in[17];
  const float* n2_g   = (const float*)d_in[18];
  const float* n2_b   = (const float*)d_in[19];
  const float* fc1_w  = (const float*)d_in[20];
  const float* fc1_b  = (const float*)d_in[21];
  const float* fc2_w  = (const float*)d_in[22];
  const float* fc2_b  = (const float*)d_in[23];

  float* ws = (float*)d_ws;
  float* XI = ws;                       // 8,538,112
  float* CC = XI + 8538112;             // 8,538,112
  float* T1 = CC + 8538112;             // 6,424,576 (cur / attp)
  float* T2 = T1 + 6424576;             // 19,273,728 (qkv / mlp hidden)
  float* T3 = T2 + 19273728;            // 6,422,528 (conv_v)
  float* PM = T3 + 6422528;             // 65,536
  float* PS = PM + 65536;               // 65,536
  float* MX = PS + 65536;               // 2,048
  float* SE = MX + 2048;                // 2,048
  float* KV = SE + 2048;                // 65,536

  float* out = (float*)d_out;

  // x1 passthrough
  copy_f4<<<8192, 256, 0, stream>>>((const float4*)x1, (float4*)out, 25692160 / 4);

  // ---- phase 1: per-scale CPE + LN1 + factor-att ----
  for (int i = 0; i < 4; ++i) {
    int H = HS[i], N = NS[i], HW = H * H, R = 8 * N;
    float* xi = XI + (size_t)ROWOFF[i] * 256;
    float* ci = CC + (size_t)ROWOFF[i] * 256;
    int total = R * 256;
    int blocks = (total + 255) / 256; if (blocks > 8192) blocks = 8192;

    cpe_kernel<<<blocks, 256, 0, stream>>>(xin[i], cpe_w + i * 2304, cpe_b + i * 256, xi, N, H, total);
    ln_kernel<<<(R + 3) / 4, 256, 0, stream>>>(xi, n1_g + i * 256, n1_b + i * 256, T1, R);

    dim3 gq((R + 63) / 64, 12);
    gemm_nt<false><<<gq, 256, 0, stream>>>(T1, qkv_w + (size_t)i * 768 * 256, nullptr, nullptr, T2, R, 256, 768);

    int NCH = 32, CS = (N + NCH - 1) / NCH;
    ksm_partial<<<dim3(NCH, 8), 256, 0, stream>>>(T2, PM, PS, N, CS, NCH);
    ksm_merge<<<8, 256, 0, stream>>>(PM, PS, MX, SE, NCH);
    kv_kernel<<<64, 1024, 0, stream>>>(T2, MX, SE, KV, N);

    int ctotal = 8 * HW * 256;
    int cblocks = (ctotal + 255) / 256; if (cblocks > 8192) cblocks = 8192;
    crpe_kernel<<<cblocks, 256, 0, stream>>>(T2, crpe_w3 + i * 576, crpe_b3 + i * 64,
                                             crpe_w5 + i * 2400, crpe_b5 + i * 96,
                                             crpe_w7 + i * 4704, crpe_b7 + i * 96,
                                             T3, N, H, ctotal);

    att_combine<<<dim3((N + 15) / 16, 8), 256, 0, stream>>>(T2, KV, T3, T1, N, HW);

    dim3 gp((R + 63) / 64, 4);
    gemm_nt<false><<<gp, 256, 0, stream>>>(T1, proj_w + (size_t)i * 256 * 256, proj_b + i * 256,
                                           nullptr, ci, R, 256, 256);
  }

  // ---- phase 2: cross-scale bilinear combine (in-place into XI) ----
  const int SA[4] = {1, 2, 3, 2};
  const int SB[4] = {2, 0, 0, 0};
  for (int i = 0; i < 4; ++i) {
    int N = NS[i], H = HS[i], R = 8 * N, total = R * 256;
    int blocks = (total + 255) / 256; if (blocks > 8192) blocks = 8192;
    combine_kernel<<<blocks, 256, 0, stream>>>(
        XI + (size_t)ROWOFF[i] * 256, CC + (size_t)ROWOFF[i] * 256,
        CC + (size_t)ROWOFF[SA[i]] * 256, HS[SA[i]], NS[SA[i]],
        CC + (size_t)ROWOFF[SB[i]] * 256, HS[SB[i]], NS[SB[i]],
        N, H, total);
  }

  // ---- phase 3: LN2 + MLP (+residual), written straight to d_out ----
  for (int i = 0; i < 4; ++i) {
    int N = NS[i], R = 8 * N;
    float* xi = XI + (size_t)ROWOFF[i] * 256;
    ln_kernel<<<(R + 3) / 4, 256, 0, stream>>>(xi, n2_g + i * 256, n2_b + i * 256, T1, R);
    float* osec = out + OUTOFF[i];
    const int CHUNK = 8192;
    for (int r0 = 0; r0 < R; r0 += CHUNK) {
      int mrows = R - r0; if (mrows > CHUNK) mrows = CHUNK;
      dim3 g1((mrows + 63) / 64, 16);
      gemm_nt<true><<<g1, 256, 0, stream>>>(T1 + (size_t)r0 * 256, fc1_w, fc1_b, nullptr,
                                            T2, mrows, 256, 1024);
      dim3 g2((mrows + 63) / 64, 4);
      gemm_nt<false><<<g2, 256, 0, stream>>>(T2, fc2_w, fc2_b, xi + (size_t)r0 * 256,
                                             osec + (size_t)r0 * 256, mrows, 1024, 256);
    }
  }
}

// Round 2
// 1387.888 us; speedup vs baseline: 1.7609x; 1.7609x over previous
//
#include <hip/hip_runtime.h>
#include <math.h>

typedef unsigned short u16;
typedef __attribute__((ext_vector_type(8))) short bf16x8;
typedef __attribute__((ext_vector_type(4))) float f32x4;

static const int HS[4]     = {56, 28, 14, 7};
static const int NS[4]     = {3137, 785, 197, 50};
static const int ROWOFF[4] = {0, 25096, 31376, 32952};
static const size_t OUTOFF[4] = {25692160ull, 32116736ull, 33724416ull, 34127872ull};

#define DEV __device__ __forceinline__

DEV u16 f2bf(float x) {
  union { float f; unsigned u; } v; v.f = x;
  unsigned r = v.u + 0x7fffu + ((v.u >> 16) & 1u);
  return (u16)(r >> 16);
}

struct alignas(8) u16x4 { u16 x, y, z, w; };

// ---------------- weight fp32 -> bf16 ----------------
__global__ void cvt_bf16(const float* __restrict__ src, u16* __restrict__ dst, int n) {
  for (int i = blockIdx.x * blockDim.x + threadIdx.x; i < n; i += gridDim.x * blockDim.x)
    dst[i] = f2bf(src[i]);
}

// ---------------- x1 passthrough ----------------
__global__ void copy_f4(const float4* __restrict__ src, float4* __restrict__ dst, int n4) {
  for (int i = blockIdx.x * blockDim.x + threadIdx.x; i < n4; i += gridDim.x * blockDim.x)
    dst[i] = src[i];
}

// ---------------- CPE: depthwise 3x3 + bias + residual ----------------
__global__ void cpe_kernel(const float* __restrict__ x, const float* __restrict__ w,
                           const float* __restrict__ bias, float* __restrict__ out,
                           int N, int H, int total) {
  int W = H;
  for (int idx = blockIdx.x * blockDim.x + threadIdx.x; idx < total; idx += gridDim.x * blockDim.x) {
    int c = idx & 255;
    int row = idx >> 8;
    int n = row % N;
    int b = row / N;
    float xv = x[idx];
    if (n == 0) { out[idx] = xv; continue; }
    int p = n - 1, h0 = p / W, w0 = p % W;
    float acc = bias[c];
    const float* wc = w + c * 9;
    #pragma unroll
    for (int kh = 0; kh < 3; ++kh) {
      int hh = h0 + kh - 1;
      if (hh < 0 || hh >= H) continue;
      #pragma unroll
      for (int kw = 0; kw < 3; ++kw) {
        int ww = w0 + kw - 1;
        if (ww < 0 || ww >= W) continue;
        acc += x[(((size_t)b * N) + 1 + hh * W + ww) * 256 + c] * wc[kh * 3 + kw];
      }
    }
    out[idx] = acc + xv;
  }
}

// ---------------- LayerNorm over C=256, bf16 out ----------------
__global__ void ln_kernel(const float* __restrict__ x, const float* __restrict__ g,
                          const float* __restrict__ bt, u16* __restrict__ out, int rows) {
  int wid = threadIdx.x >> 6, lane = threadIdx.x & 63;
  int row = blockIdx.x * 4 + wid;
  if (row >= rows) return;
  const float* xr = x + (size_t)row * 256;
  float4 v = *(const float4*)(xr + lane * 4);
  float s = v.x + v.y + v.z + v.w;
  #pragma unroll
  for (int off = 32; off; off >>= 1) s += __shfl_down(s, off);
  s = __shfl(s, 0);
  float mu = s * (1.0f / 256.0f);
  float dx = v.x - mu, dy = v.y - mu, dz = v.z - mu, dw = v.w - mu;
  float q = dx * dx + dy * dy + dz * dz + dw * dw;
  #pragma unroll
  for (int off = 32; off; off >>= 1) q += __shfl_down(q, off);
  q = __shfl(q, 0);
  float rs = rsqrtf(q * (1.0f / 256.0f) + 1e-5f);
  float4 gg = *(const float4*)(g + lane * 4);
  float4 bb = *(const float4*)(bt + lane * 4);
  u16x4 o;
  o.x = f2bf(dx * rs * gg.x + bb.x);
  o.y = f2bf(dy * rs * gg.y + bb.y);
  o.z = f2bf(dz * rs * gg.z + bb.z);
  o.w = f2bf(dw * rs * gg.w + bb.w);
  *(u16x4*)(out + (size_t)row * 256 + lane * 4) = o;
}

// ---------------- bf16 MFMA GEMM: out[M,Nout] = A[M,K] @ W[Nout,K]^T ----------------
// A, W bf16; fp32 accumulate. LDS layout per tile: [BK/8 kblocks][128 rows][8 elems].
template <bool GELU, bool OUT_BF16>
__launch_bounds__(256)
__global__ void gemm_mfma(const u16* __restrict__ A, const u16* __restrict__ W,
                          const float* __restrict__ bias, const float* __restrict__ res,
                          void* __restrict__ outp, int M, int K, int Nout) {
  constexpr int BK = 64;
  __shared__ __align__(16) u16 lds[2 * 128 * BK];
  u16* aL = lds;
  u16* bL = lds + 128 * BK;

  int t = threadIdx.x, lane = t & 63, wv = t >> 6;
  int wr = wv >> 1, wc = wv & 1;
  int bm = blockIdx.x << 7, bn = blockIdx.y << 7;

  f32x4 acc[4][4] = {};

  // per-thread staging coordinates (slot s = q*128 + row), 4 issues x 256 slots
  int sq[4], srow[4];
  #pragma unroll
  for (int iss = 0; iss < 4; ++iss) {
    int s = iss * 256 + t;
    sq[iss] = s >> 7;
    srow[iss] = s & 127;
  }

  for (int k0 = 0; k0 < K; k0 += BK) {
    #pragma unroll
    for (int iss = 0; iss < 4; ++iss) {
      int gr = bm + srow[iss]; if (gr > M - 1) gr = M - 1;
      const u16* ga = A + (size_t)gr * K + k0 + sq[iss] * 8;
      __builtin_amdgcn_global_load_lds(
          (const __attribute__((address_space(1))) void*)ga,
          (__attribute__((address_space(3))) void*)(aL + (size_t)(iss * 256 + wv * 64) * 8),
          16, 0, 0);
      const u16* gb = W + (size_t)(bn + srow[iss]) * K + k0 + sq[iss] * 8;
      __builtin_amdgcn_global_load_lds(
          (const __attribute__((address_space(1))) void*)gb,
          (__attribute__((address_space(3))) void*)(bL + (size_t)(iss * 256 + wv * 64) * 8),
          16, 0, 0);
    }
    __syncthreads();
    #pragma unroll
    for (int kk = 0; kk < BK / 32; ++kk) {
      int qg = kk * 4 + (lane >> 4);
      bf16x8 af[4], bfr[4];
      #pragma unroll
      for (int m = 0; m < 4; ++m) {
        int slot = qg * 128 + wr * 64 + m * 16 + (lane & 15);
        af[m] = *(const bf16x8*)(aL + slot * 8);
      }
      #pragma unroll
      for (int n = 0; n < 4; ++n) {
        int slot = qg * 128 + wc * 64 + n * 16 + (lane & 15);
        bfr[n] = *(const bf16x8*)(bL + slot * 8);
      }
      #pragma unroll
      for (int m = 0; m < 4; ++m)
        #pragma unroll
        for (int n = 0; n < 4; ++n)
          acc[m][n] = __builtin_amdgcn_mfma_f32_16x16x32_bf16(af[m], bfr[n], acc[m][n], 0, 0, 0);
    }
    __syncthreads();
  }

  // epilogue: C/D layout col=lane&15, row=(lane>>4)*4+reg
  int rbase = bm + wr * 64 + (lane >> 4) * 4;
  int cbase = bn + wc * 64 + (lane & 15);
  #pragma unroll
  for (int m = 0; m < 4; ++m) {
    #pragma unroll
    for (int rg = 0; rg < 4; ++rg) {
      int r = rbase + m * 16 + rg;
      if (r >= M) continue;
      #pragma unroll
      for (int n = 0; n < 4; ++n) {
        int cc = cbase + n * 16;
        float v = acc[m][n][rg];
        if (bias) v += bias[cc];
        if (GELU) v = 0.5f * v * (1.0f + erff(v * 0.70710678118654752f));
        size_t o = (size_t)r * Nout + cc;
        if (res) v += res[o];
        if (OUT_BF16) ((u16*)outp)[o] = f2bf(v);
        else          ((float*)outp)[o] = v;
      }
    }
  }
}

// ---------------- softmax over tokens for k ----------------
__global__ void ksm_partial(const float* __restrict__ qkv, float* __restrict__ pm,
                            float* __restrict__ ps, int N, int CS, int NCH) {
  int b = blockIdx.y, ch = blockIdx.x, cg = threadIdx.x;
  int n0 = ch * CS, n1 = min(N, n0 + CS);
  float m = -1e30f, s = 0.f;
  for (int n = n0; n < n1; ++n) {
    float v = qkv[((size_t)(b * N + n)) * 768 + 256 + cg];
    float nm = fmaxf(m, v);
    s = s * __expf(m - nm) + __expf(v - nm);
    m = nm;
  }
  pm[(b * NCH + ch) * 256 + cg] = m;
  ps[(b * NCH + ch) * 256 + cg] = s;
}

__global__ void ksm_merge(const float* __restrict__ pm, const float* __restrict__ ps,
                          float* __restrict__ mx, float* __restrict__ se, int NCH) {
  int b = blockIdx.x, cg = threadIdx.x;
  float m = -1e30f, s = 0.f;
  for (int c = 0; c < NCH; ++c) {
    float mc = pm[(b * NCH + c) * 256 + cg];
    float sc = ps[(b * NCH + c) * 256 + cg];
    float nm = fmaxf(m, mc);
    s = s * __expf(m - nm) + sc * __expf(mc - nm);
    m = nm;
  }
  mx[b * 256 + cg] = m;
  se[b * 256 + cg] = s;
}

// ---------------- kv[b,h,i,j] = sum_n softmax(k)[n,i] * v[n,j] ----------------
__launch_bounds__(1024)
__global__ void kv_kernel(const float* __restrict__ qkv, const float* __restrict__ mx,
                          const float* __restrict__ se, float* __restrict__ kv, int N) {
  __shared__ float kl[32][33];
  __shared__ float vl[32][33];
  int b = blockIdx.x >> 3, h = blockIdx.x & 7;
  int t = threadIdx.x;
  int i = t >> 5, j = t & 31;
  float mexp = mx[b * 256 + h * 32 + j];
  float acc = 0.f;
  for (int n0 = 0; n0 < N; n0 += 32) {
    #pragma unroll
    for (int e = t; e < 2048; e += 1024) {
      int r = e >> 6, cc = e & 63;
      int n = n0 + r;
      if (cc < 32) kl[r][cc] = (n < N) ? qkv[((size_t)(b * N + n)) * 768 + 256 + h * 32 + cc] : -1e30f;
      else         vl[r][cc - 32] = (n < N) ? qkv[((size_t)(b * N + n)) * 768 + 512 + h * 32 + (cc - 32)] : 0.f;
    }
    __syncthreads();
    kl[i][j] = __expf(kl[i][j] - mexp);
    __syncthreads();
    #pragma unroll
    for (int nn = 0; nn < 32; ++nn) acc += kl[nn][i] * vl[nn][j];
    __syncthreads();
  }
  kv[(((size_t)b * 8 + h) * 32 + i) * 32 + j] = acc / se[b * 256 + h * 32 + i];
}

// ---------------- CRPE depthwise conv, templated kernel size, 4-wide register blocking ----------------
template <int KS, int C0, int CS>
__global__ void crpe_k(const float* __restrict__ qkv, const float* __restrict__ w,
                       const float* __restrict__ bias, float* __restrict__ convv,
                       int N, int H, int total) {
  int W = H, Wq = (W + 3) >> 2, HW = H * W;
  constexpr int pad = KS / 2;
  for (int idx = blockIdx.x * blockDim.x + threadIdx.x; idx < total; idx += gridDim.x * blockDim.x) {
    int c = idx % CS;
    int r = idx / CS;
    int qw = r % Wq; r /= Wq;
    int h0 = r % H;
    int b = r / H;
    int w0 = qw << 2;
    const float* wp = w + c * KS * KS;
    float bb = bias[c];
    float o0 = bb, o1 = bb, o2 = bb, o3 = bb;
    const float* vbase = qkv + ((size_t)b * N + 1) * 768 + 512 + C0 + c;
    #pragma unroll
    for (int kh = 0; kh < KS; ++kh) {
      int hh = h0 + kh - pad;
      if (hh < 0 || hh >= H) continue;
      const float* rowp = vbase + (size_t)hh * W * 768;
      float tv[KS + 3];
      #pragma unroll
      for (int j = 0; j < KS + 3; ++j) {
        int ww = w0 - pad + j;
        tv[j] = (ww >= 0 && ww < W) ? rowp[(size_t)ww * 768] : 0.f;
      }
      #pragma unroll
      for (int kw = 0; kw < KS; ++kw) {
        float wvv = wp[kh * KS + kw];
        o0 += tv[kw] * wvv;
        o1 += tv[kw + 1] * wvv;
        o2 += tv[kw + 2] * wvv;
        o3 += tv[kw + 3] * wvv;
      }
    }
    float* op = convv + ((size_t)b * HW + (size_t)h0 * W + w0) * 256 + C0 + c;
    op[0] = o0;
    if (w0 + 1 < W) op[256] = o1;
    if (w0 + 2 < W) op[512] = o2;
    if (w0 + 3 < W) op[768] = o3;
  }
}

// ---------------- att: attp = CH^-0.5 * (q @ kv) + [n>0] q * conv_v (bf16 out) ----------------
__global__ void att_combine(const float* __restrict__ qkv, const float* __restrict__ kvg,
                            const float* __restrict__ convv, u16* __restrict__ attp,
                            int N, int HW) {
  __shared__ float kvl[8192];
  __shared__ float ql[256];
  int b = blockIdx.y;
  int n0 = blockIdx.x * 16;
  int t = threadIdx.x;
  for (int e = t; e < 8192; e += 256) kvl[e] = kvg[(size_t)b * 8192 + e];
  int h = t >> 5, j = t & 31;
  for (int nn = 0; nn < 16; ++nn) {
    int n = n0 + nn;
    if (n >= N) break;
    __syncthreads();
    ql[t] = qkv[((size_t)(b * N + n)) * 768 + t];
    __syncthreads();
    float fa = 0.f;
    const float* kvh = kvl + h * 1024;
    #pragma unroll
    for (int k = 0; k < 32; ++k) fa += ql[h * 32 + k] * kvh[k * 32 + j];
    float v = 0.17677669529663687f * fa;
    if (n > 0) v += ql[t] * convv[(((size_t)b * HW) + (n - 1)) * 256 + t];
    attp[(((size_t)b * N) + n) * 256 + t] = f2bf(v);
  }
}

// ---------------- cross-scale bilinear combine ----------------
DEV float bsample(const float* __restrict__ src, int b, int Ns, int Hs,
                  int oh, int ow, int Hi, int c) {
  float scale = (float)Hs / (float)Hi;
  float sy = (oh + 0.5f) * scale - 0.5f;
  float sx = (ow + 0.5f) * scale - 0.5f;
  float fy0 = floorf(sy), fx0 = floorf(sx);
  float fy = sy - fy0, fx = sx - fx0;
  int y0 = (int)fy0, x0 = (int)fx0;
  int y0c = min(max(y0, 0), Hs - 1), y1c = min(max(y0 + 1, 0), Hs - 1);
  int x0c = min(max(x0, 0), Hs - 1), x1c = min(max(x0 + 1, 0), Hs - 1);
  const float* base = src + ((size_t)b * Ns + 1) * 256 + c;
  float v00 = base[(size_t)(y0c * Hs + x0c) * 256];
  float v01 = base[(size_t)(y0c * Hs + x1c) * 256];
  float v10 = base[(size_t)(y1c * Hs + x0c) * 256];
  float v11 = base[(size_t)(y1c * Hs + x1c) * 256];
  return (1.f - fy) * ((1.f - fx) * v00 + fx * v01) + fy * ((1.f - fx) * v10 + fx * v11);
}

__global__ void combine_kernel(float* __restrict__ xi, const float* __restrict__ ci,
                               const float* __restrict__ srcA, int HsA, int NsA,
                               const float* __restrict__ srcB, int HsB, int NsB,
                               int Ni, int Hi, int total) {
  for (int idx = blockIdx.x * blockDim.x + threadIdx.x; idx < total; idx += gridDim.x * blockDim.x) {
    int c = idx & 255;
    int row = idx >> 8;
    int n = row % Ni;
    int b = row / Ni;
    float add = ci[idx];
    if (n == 0) {
      add += srcA[((size_t)b * NsA) * 256 + c] + srcB[((size_t)b * NsB) * 256 + c];
    } else {
      int p = n - 1, oh = p / Hi, ow = p % Hi;
      add += bsample(srcA, b, NsA, HsA, oh, ow, Hi, c);
      add += bsample(srcB, b, NsB, HsB, oh, ow, Hi, c);
    }
    xi[idx] += add;
  }
}

// ---------------- host ----------------
extern "C" void kernel_launch(void* const* d_in, const int* in_sizes, int n_in,
                              void* d_out, int out_size, void* d_ws, size_t ws_size,
                              hipStream_t stream) {
  const float* x1 = (const float*)d_in[0];
  const float* xin[4] = {(const float*)d_in[1], (const float*)d_in[2],
                         (const float*)d_in[3], (const float*)d_in[4]};
  const float* cpe_w  = (const float*)d_in[5];
  const float* cpe_b  = (const float*)d_in[6];
  const float* n1_g   = (const float*)d_in[7];
  const float* n1_b   = (const float*)d_in[8];
  const float* qkv_w  = (const float*)d_in[9];
  const float* proj_w = (const float*)d_in[10];
  const float* proj_b = (const float*)d_in[11];
  const float* crpe_w3 = (const float*)d_in[12];
  const float* crpe_b3 = (const float*)d_in[13];
  const float* crpe_w5 = (const float*)d_in[14];
  const float* crpe_b5 = (const float*)d_in[15];
  const float* crpe_w7 = (const float*)d_in[16];
  const float* crpe_b7 = (const float*)d_in[17];
  const float* n2_g   = (const float*)d_in[18];
  const float* n2_b   = (const float*)d_in[19];
  const float* fc1_w  = (const float*)d_in[20];
  const float* fc1_b  = (const float*)d_in[21];
  const float* fc2_w  = (const float*)d_in[22];
  const float* fc2_b  = (const float*)d_in[23];

  float* ws = (float*)d_ws;
  float* XI = ws;                                 // 8,538,112 f32
  float* CC = XI + 8538112;                       // 8,538,112 f32
  u16*   T1 = (u16*)(CC + 8538112);               // 6,424,576 bf16 (3,212,288 f32 slots)
  float* T2 = CC + 8538112 + 3212288;             // 19,273,728 f32 (qkv fp32 / mlp hidden bf16)
  float* T3 = T2 + 19273728;                      // 6,422,528 f32 (conv_v)
  float* PM = T3 + 6422528;                       // 65,536
  float* PS = PM + 65536;                         // 65,536
  float* MX = PS + 65536;                         // 2,048
  float* SE = MX + 2048;                          // 2,048
  float* KV = SE + 2048;                          // 65,536
  u16*   WQ = (u16*)(KV + 65536);                 // 786,432 bf16
  u16*   WP = WQ + 786432;                        // 262,144 bf16
  u16*   W1 = WP + 262144;                        // 262,144 bf16
  u16*   W2 = W1 + 262144;                        // 262,144 bf16

  float* out = (float*)d_out;

  // weights -> bf16
  cvt_bf16<<<1536, 256, 0, stream>>>(qkv_w, WQ, 786432);
  cvt_bf16<<<512, 256, 0, stream>>>(proj_w, WP, 262144);
  cvt_bf16<<<512, 256, 0, stream>>>(fc1_w, W1, 262144);
  cvt_bf16<<<512, 256, 0, stream>>>(fc2_w, W2, 262144);

  // x1 passthrough
  copy_f4<<<8192, 256, 0, stream>>>((const float4*)x1, (float4*)out, 25692160 / 4);

  // ---- phase 1: per-scale CPE + LN1 + factor-att ----
  for (int i = 0; i < 4; ++i) {
    int H = HS[i], N = NS[i], HW = H * H, R = 8 * N;
    float* xi = XI + (size_t)ROWOFF[i] * 256;
    float* ci = CC + (size_t)ROWOFF[i] * 256;
    int total = R * 256;
    int blocks = (total + 255) / 256; if (blocks > 8192) blocks = 8192;

    cpe_kernel<<<blocks, 256, 0, stream>>>(xin[i], cpe_w + i * 2304, cpe_b + i * 256, xi, N, H, total);
    ln_kernel<<<(R + 3) / 4, 256, 0, stream>>>(xi, n1_g + i * 256, n1_b + i * 256, T1, R);

    dim3 gq((R + 127) / 128, 6);
    gemm_mfma<false, false><<<gq, 256, 0, stream>>>(T1, WQ + (size_t)i * 768 * 256,
                                                    nullptr, nullptr, T2, R, 256, 768);

    int NCH = 32, CS = (N + NCH - 1) / NCH;
    ksm_partial<<<dim3(NCH, 8), 256, 0, stream>>>(T2, PM, PS, N, CS, NCH);
    ksm_merge<<<8, 256, 0, stream>>>(PM, PS, MX, SE, NCH);
    kv_kernel<<<64, 1024, 0, stream>>>(T2, MX, SE, KV, N);

    int Wq = (H + 3) >> 2;
    {
      int t3 = 8 * H * Wq * 64;
      int b3 = (t3 + 255) / 256; if (b3 > 8192) b3 = 8192;
      crpe_k<3, 0, 64><<<b3, 256, 0, stream>>>(T2, crpe_w3 + i * 576, crpe_b3 + i * 64, T3, N, H, t3);
      int t5 = 8 * H * Wq * 96;
      int b5 = (t5 + 255) / 256; if (b5 > 8192) b5 = 8192;
      crpe_k<5, 64, 96><<<b5, 256, 0, stream>>>(T2, crpe_w5 + i * 2400, crpe_b5 + i * 96, T3, N, H, t5);
      crpe_k<7, 160, 96><<<b5, 256, 0, stream>>>(T2, crpe_w7 + i * 4704, crpe_b7 + i * 96, T3, N, H, t5);
    }

    att_combine<<<dim3((N + 15) / 16, 8), 256, 0, stream>>>(T2, KV, T3, T1, N, HW);

    dim3 gp((R + 127) / 128, 2);
    gemm_mfma<false, false><<<gp, 256, 0, stream>>>(T1, WP + (size_t)i * 65536,
                                                    proj_b + i * 256, nullptr, ci, R, 256, 256);
  }

  // ---- phase 2: cross-scale bilinear combine ----
  const int SA[4] = {1, 2, 3, 2};
  const int SB[4] = {2, 0, 0, 0};
  for (int i = 0; i < 4; ++i) {
    int N = NS[i], H = HS[i], R = 8 * N, total = R * 256;
    int blocks = (total + 255) / 256; if (blocks > 8192) blocks = 8192;
    combine_kernel<<<blocks, 256, 0, stream>>>(
        XI + (size_t)ROWOFF[i] * 256, CC + (size_t)ROWOFF[i] * 256,
        CC + (size_t)ROWOFF[SA[i]] * 256, HS[SA[i]], NS[SA[i]],
        CC + (size_t)ROWOFF[SB[i]] * 256, HS[SB[i]], NS[SB[i]],
        N, H, total);
  }

  // ---- phase 3: LN2 + MLP (+residual) -> d_out ----
  u16* T2h = (u16*)T2;
  for (int i = 0; i < 4; ++i) {
    int N = NS[i], R = 8 * N;
    float* xi = XI + (size_t)ROWOFF[i] * 256;
    ln_kernel<<<(R + 3) / 4, 256, 0, stream>>>(xi, n2_g + i * 256, n2_b + i * 256, T1, R);
    float* osec = out + OUTOFF[i];
    dim3 g1((R + 127) / 128, 8);
    gemm_mfma<true, true><<<g1, 256, 0, stream>>>(T1, W1, fc1_b, nullptr, (void*)T2h, R, 256, 1024);
    dim3 g2((R + 127) / 128, 2);
    gemm_mfma<false, false><<<g2, 256, 0, stream>>>(T2h, W2, fc2_b, xi, osec, R, 1024, 256);
  }
}

// Round 3
// 1200.777 us; speedup vs baseline: 2.0353x; 1.1558x over previous
//
#include <hip/hip_runtime.h>
#include <math.h>

typedef unsigned short u16;
typedef __attribute__((ext_vector_type(8))) short bf16x8;
typedef __attribute__((ext_vector_type(4))) float f32x4;

static const int HS[4]     = {56, 28, 14, 7};
static const int NS[4]     = {3137, 785, 197, 50};
static const int ROWOFF[4] = {0, 25096, 31376, 32952};
static const size_t OUTOFF[4] = {25692160ull, 32116736ull, 33724416ull, 34127872ull};

#define DEV __device__ __forceinline__

DEV u16 f2bf(float x) {
  union { float f; unsigned u; } v; v.f = x;
  unsigned r = v.u + 0x7fffu + ((v.u >> 16) & 1u);
  return (u16)(r >> 16);
}

struct alignas(8) u16x4 { u16 x, y, z, w; };

// ---------------- weight fp32 -> bf16 ----------------
__global__ void cvt_bf16(const float* __restrict__ src, u16* __restrict__ dst, int n) {
  for (int i = blockIdx.x * blockDim.x + threadIdx.x; i < n; i += gridDim.x * blockDim.x)
    dst[i] = f2bf(src[i]);
}

// ---------------- x1 passthrough ----------------
__global__ void copy_f4(const float4* __restrict__ src, float4* __restrict__ dst, int n4) {
  for (int i = blockIdx.x * blockDim.x + threadIdx.x; i < n4; i += gridDim.x * blockDim.x)
    dst[i] = src[i];
}

// ---------------- CPE: depthwise 3x3 + bias + residual ----------------
__global__ void cpe_kernel(const float* __restrict__ x, const float* __restrict__ w,
                           const float* __restrict__ bias, float* __restrict__ out,
                           int N, int H, int total) {
  int W = H;
  for (int idx = blockIdx.x * blockDim.x + threadIdx.x; idx < total; idx += gridDim.x * blockDim.x) {
    int c = idx & 255;
    int row = idx >> 8;
    int n = row % N;
    int b = row / N;
    float xv = x[idx];
    if (n == 0) { out[idx] = xv; continue; }
    int p = n - 1, h0 = p / W, w0 = p % W;
    float acc = bias[c];
    const float* wc = w + c * 9;
    #pragma unroll
    for (int kh = 0; kh < 3; ++kh) {
      int hh = h0 + kh - 1;
      if (hh < 0 || hh >= H) continue;
      #pragma unroll
      for (int kw = 0; kw < 3; ++kw) {
        int ww = w0 + kw - 1;
        if (ww < 0 || ww >= W) continue;
        acc += x[(((size_t)b * N) + 1 + hh * W + ww) * 256 + c] * wc[kh * 3 + kw];
      }
    }
    out[idx] = acc + xv;
  }
}

// ---------------- LayerNorm over C=256, bf16 out ----------------
__global__ void ln_kernel(const float* __restrict__ x, const float* __restrict__ g,
                          const float* __restrict__ bt, u16* __restrict__ out, int rows) {
  int wid = threadIdx.x >> 6, lane = threadIdx.x & 63;
  int row = blockIdx.x * 4 + wid;
  if (row >= rows) return;
  const float* xr = x + (size_t)row * 256;
  float4 v = *(const float4*)(xr + lane * 4);
  float s = v.x + v.y + v.z + v.w;
  #pragma unroll
  for (int off = 32; off; off >>= 1) s += __shfl_down(s, off);
  s = __shfl(s, 0);
  float mu = s * (1.0f / 256.0f);
  float dx = v.x - mu, dy = v.y - mu, dz = v.z - mu, dw = v.w - mu;
  float q = dx * dx + dy * dy + dz * dz + dw * dw;
  #pragma unroll
  for (int off = 32; off; off >>= 1) q += __shfl_down(q, off);
  q = __shfl(q, 0);
  float rs = rsqrtf(q * (1.0f / 256.0f) + 1e-5f);
  float4 gg = *(const float4*)(g + lane * 4);
  float4 bb = *(const float4*)(bt + lane * 4);
  u16x4 o;
  o.x = f2bf(dx * rs * gg.x + bb.x);
  o.y = f2bf(dy * rs * gg.y + bb.y);
  o.z = f2bf(dz * rs * gg.z + bb.z);
  o.w = f2bf(dw * rs * gg.w + bb.w);
  *(u16x4*)(out + (size_t)row * 256 + lane * 4) = o;
}

// ---------------- bf16 MFMA GEMM ----------------
template <bool GELU, bool OUT_BF16>
__launch_bounds__(256)
__global__ void gemm_mfma(const u16* __restrict__ A, const u16* __restrict__ W,
                          const float* __restrict__ bias, const float* __restrict__ res,
                          void* __restrict__ outp, int M, int K, int Nout) {
  constexpr int BK = 64;
  __shared__ __align__(16) u16 lds[2 * 128 * BK];
  u16* aL = lds;
  u16* bL = lds + 128 * BK;

  int t = threadIdx.x, lane = t & 63, wv = t >> 6;
  int wr = wv >> 1, wc = wv & 1;
  int bm = blockIdx.x << 7, bn = blockIdx.y << 7;

  f32x4 acc[4][4] = {};

  int sq[4], srow[4];
  #pragma unroll
  for (int iss = 0; iss < 4; ++iss) {
    int s = iss * 256 + t;
    sq[iss] = s >> 7;
    srow[iss] = s & 127;
  }

  for (int k0 = 0; k0 < K; k0 += BK) {
    #pragma unroll
    for (int iss = 0; iss < 4; ++iss) {
      int gr = bm + srow[iss]; if (gr > M - 1) gr = M - 1;
      const u16* ga = A + (size_t)gr * K + k0 + sq[iss] * 8;
      __builtin_amdgcn_global_load_lds(
          (const __attribute__((address_space(1))) void*)ga,
          (__attribute__((address_space(3))) void*)(aL + (size_t)(iss * 256 + wv * 64) * 8),
          16, 0, 0);
      const u16* gb = W + (size_t)(bn + srow[iss]) * K + k0 + sq[iss] * 8;
      __builtin_amdgcn_global_load_lds(
          (const __attribute__((address_space(1))) void*)gb,
          (__attribute__((address_space(3))) void*)(bL + (size_t)(iss * 256 + wv * 64) * 8),
          16, 0, 0);
    }
    __syncthreads();
    #pragma unroll
    for (int kk = 0; kk < BK / 32; ++kk) {
      int qg = kk * 4 + (lane >> 4);
      bf16x8 af[4], bfr[4];
      #pragma unroll
      for (int m = 0; m < 4; ++m) {
        int slot = qg * 128 + wr * 64 + m * 16 + (lane & 15);
        af[m] = *(const bf16x8*)(aL + slot * 8);
      }
      #pragma unroll
      for (int n = 0; n < 4; ++n) {
        int slot = qg * 128 + wc * 64 + n * 16 + (lane & 15);
        bfr[n] = *(const bf16x8*)(bL + slot * 8);
      }
      #pragma unroll
      for (int m = 0; m < 4; ++m)
        #pragma unroll
        for (int n = 0; n < 4; ++n)
          acc[m][n] = __builtin_amdgcn_mfma_f32_16x16x32_bf16(af[m], bfr[n], acc[m][n], 0, 0, 0);
    }
    __syncthreads();
  }

  int rbase = bm + wr * 64 + (lane >> 4) * 4;
  int cbase = bn + wc * 64 + (lane & 15);
  #pragma unroll
  for (int m = 0; m < 4; ++m) {
    #pragma unroll
    for (int rg = 0; rg < 4; ++rg) {
      int r = rbase + m * 16 + rg;
      if (r >= M) continue;
      #pragma unroll
      for (int n = 0; n < 4; ++n) {
        int cc = cbase + n * 16;
        float v = acc[m][n][rg];
        if (bias) v += bias[cc];
        if (GELU) v = 0.5f * v * (1.0f + erff(v * 0.70710678118654752f));
        size_t o = (size_t)r * Nout + cc;
        if (res) v += res[o];
        if (OUT_BF16) ((u16*)outp)[o] = f2bf(v);
        else          ((float*)outp)[o] = v;
      }
    }
  }
}

// ---------------- softmax over tokens for k ----------------
__global__ void ksm_partial(const float* __restrict__ qkv, float* __restrict__ pm,
                            float* __restrict__ ps, int N, int CS, int NCH) {
  int b = blockIdx.y, ch = blockIdx.x, cg = threadIdx.x;
  int n0 = ch * CS, n1 = min(N, n0 + CS);
  float m = -1e30f, s = 0.f;
  for (int n = n0; n < n1; ++n) {
    float v = qkv[((size_t)(b * N + n)) * 768 + 256 + cg];
    float nm = fmaxf(m, v);
    s = s * __expf(m - nm) + __expf(v - nm);
    m = nm;
  }
  pm[(b * NCH + ch) * 256 + cg] = m;
  ps[(b * NCH + ch) * 256 + cg] = s;
}

__global__ void ksm_merge(const float* __restrict__ pm, const float* __restrict__ ps,
                          float* __restrict__ mx, float* __restrict__ se, int NCH) {
  int b = blockIdx.x, cg = threadIdx.x;
  float m = -1e30f, s = 0.f;
  for (int c = 0; c < NCH; ++c) {
    float mc = pm[(b * NCH + c) * 256 + cg];
    float sc = ps[(b * NCH + c) * 256 + cg];
    float nm = fmaxf(m, mc);
    s = s * __expf(m - nm) + sc * __expf(mc - nm);
    m = nm;
  }
  mx[b * 256 + cg] = m;
  se[b * 256 + cg] = s;
}

// ---------------- kv partials: chunked over tokens ----------------
__launch_bounds__(1024)
__global__ void kv_partial(const float* __restrict__ qkv, const float* __restrict__ mx,
                           float* __restrict__ part, int N, int chunkrows, int NC) {
  __shared__ float kl[32][33];
  __shared__ float vl[32][33];
  int blk = blockIdx.x;
  int chunk = blk % NC;
  int bh = blk / NC;
  int b = bh >> 3, h = bh & 7;
  int t = threadIdx.x;
  int i = t >> 5, j = t & 31;
  float mexp = mx[b * 256 + h * 32 + j];
  float acc = 0.f;
  int n0s = chunk * chunkrows, n1s = min(N, n0s + chunkrows);
  for (int n0 = n0s; n0 < n1s; n0 += 32) {
    #pragma unroll
    for (int e = t; e < 2048; e += 1024) {
      int r = e >> 6, cc = e & 63;
      int n = n0 + r;
      bool ok = (n < n1s);
      if (cc < 32) kl[r][cc] = ok ? qkv[((size_t)(b * N + n)) * 768 + 256 + h * 32 + cc] : -1e30f;
      else         vl[r][cc - 32] = ok ? qkv[((size_t)(b * N + n)) * 768 + 512 + h * 32 + (cc - 32)] : 0.f;
    }
    __syncthreads();
    kl[i][j] = __expf(kl[i][j] - mexp);
    __syncthreads();
    #pragma unroll
    for (int nn = 0; nn < 32; ++nn) acc += kl[nn][i] * vl[nn][j];
    __syncthreads();
  }
  part[((size_t)bh * NC + chunk) * 1024 + t] = acc;
}

__global__ void kv_reduce(const float* __restrict__ part, const float* __restrict__ se,
                          float* __restrict__ kv, int NC) {
  int bh = blockIdx.x;
  int t = threadIdx.x;
  int i = t >> 5;
  int b = bh >> 3, h = bh & 7;
  float s = 0.f;
  for (int c = 0; c < NC; ++c) s += part[((size_t)bh * NC + c) * 1024 + t];
  kv[(size_t)bh * 1024 + t] = s / se[b * 256 + h * 32 + i];
}

// ---------------- CRPE depthwise conv, templated, 4-wide register blocking ----------------
template <int KS, int C0, int CS>
__global__ void crpe_k(const float* __restrict__ qkv, const float* __restrict__ w,
                       const float* __restrict__ bias, float* __restrict__ convv,
                       int N, int H, int total) {
  int W = H, Wq = (W + 3) >> 2, HW = H * W;
  constexpr int pad = KS / 2;
  for (int idx = blockIdx.x * blockDim.x + threadIdx.x; idx < total; idx += gridDim.x * blockDim.x) {
    int c = idx % CS;
    int r = idx / CS;
    int qw = r % Wq; r /= Wq;
    int h0 = r % H;
    int b = r / H;
    int w0 = qw << 2;
    const float* wp = w + c * KS * KS;
    float bb = bias[c];
    float o0 = bb, o1 = bb, o2 = bb, o3 = bb;
    const float* vbase = qkv + ((size_t)b * N + 1) * 768 + 512 + C0 + c;
    #pragma unroll
    for (int kh = 0; kh < KS; ++kh) {
      int hh = h0 + kh - pad;
      if (hh < 0 || hh >= H) continue;
      const float* rowp = vbase + (size_t)hh * W * 768;
      float tv[KS + 3];
      #pragma unroll
      for (int j = 0; j < KS + 3; ++j) {
        int ww = w0 - pad + j;
        tv[j] = (ww >= 0 && ww < W) ? rowp[(size_t)ww * 768] : 0.f;
      }
      #pragma unroll
      for (int kw = 0; kw < KS; ++kw) {
        float wvv = wp[kh * KS + kw];
        o0 += tv[kw] * wvv;
        o1 += tv[kw + 1] * wvv;
        o2 += tv[kw + 2] * wvv;
        o3 += tv[kw + 3] * wvv;
      }
    }
    float* op = convv + ((size_t)b * HW + (size_t)h0 * W + w0) * 256 + C0 + c;
    op[0] = o0;
    if (w0 + 1 < W) op[256] = o1;
    if (w0 + 2 < W) op[512] = o2;
    if (w0 + 3 < W) op[768] = o3;
  }
}

// ---------------- att: attp = CH^-0.5 * (q @ kv) + [n>0] q * conv_v (bf16 out) ----------------
__global__ void att_combine(const float* __restrict__ qkv, const float* __restrict__ kvg,
                            const float* __restrict__ convv, u16* __restrict__ attp,
                            int N, int HW) {
  __shared__ float kvl[8192];
  __shared__ float ql[256];
  int b = blockIdx.y;
  int n0 = blockIdx.x * 16;
  int t = threadIdx.x;
  for (int e = t; e < 8192; e += 256) kvl[e] = kvg[(size_t)b * 8192 + e];
  int h = t >> 5, j = t & 31;
  for (int nn = 0; nn < 16; ++nn) {
    int n = n0 + nn;
    if (n >= N) break;
    __syncthreads();
    ql[t] = qkv[((size_t)(b * N + n)) * 768 + t];
    __syncthreads();
    float fa = 0.f;
    const float* kvh = kvl + h * 1024;
    #pragma unroll
    for (int k = 0; k < 32; ++k) fa += ql[h * 32 + k] * kvh[k * 32 + j];
    float v = 0.17677669529663687f * fa;
    if (n > 0) v += ql[t] * convv[(((size_t)b * HW) + (n - 1)) * 256 + t];
    attp[(((size_t)b * N) + n) * 256 + t] = f2bf(v);
  }
}

// ---------------- cross-scale bilinear combine ----------------
DEV float bsample(const float* __restrict__ src, int b, int Ns, int Hs,
                  int oh, int ow, int Hi, int c) {
  float scale = (float)Hs / (float)Hi;
  float sy = (oh + 0.5f) * scale - 0.5f;
  float sx = (ow + 0.5f) * scale - 0.5f;
  float fy0 = floorf(sy), fx0 = floorf(sx);
  float fy = sy - fy0, fx = sx - fx0;
  int y0 = (int)fy0, x0 = (int)fx0;
  int y0c = min(max(y0, 0), Hs - 1), y1c = min(max(y0 + 1, 0), Hs - 1);
  int x0c = min(max(x0, 0), Hs - 1), x1c = min(max(x0 + 1, 0), Hs - 1);
  const float* base = src + ((size_t)b * Ns + 1) * 256 + c;
  float v00 = base[(size_t)(y0c * Hs + x0c) * 256];
  float v01 = base[(size_t)(y0c * Hs + x1c) * 256];
  float v10 = base[(size_t)(y1c * Hs + x0c) * 256];
  float v11 = base[(size_t)(y1c * Hs + x1c) * 256];
  return (1.f - fy) * ((1.f - fx) * v00 + fx * v01) + fy * ((1.f - fx) * v10 + fx * v11);
}

__global__ void combine_kernel(float* __restrict__ xi, const float* __restrict__ ci,
                               const float* __restrict__ srcA, int HsA, int NsA,
                               const float* __restrict__ srcB, int HsB, int NsB,
                               int Ni, int Hi, int total) {
  for (int idx = blockIdx.x * blockDim.x + threadIdx.x; idx < total; idx += gridDim.x * blockDim.x) {
    int c = idx & 255;
    int row = idx >> 8;
    int n = row % Ni;
    int b = row / Ni;
    float add = ci[idx];
    if (n == 0) {
      add += srcA[((size_t)b * NsA) * 256 + c] + srcB[((size_t)b * NsB) * 256 + c];
    } else {
      int p = n - 1, oh = p / Hi, ow = p % Hi;
      add += bsample(srcA, b, NsA, HsA, oh, ow, Hi, c);
      add += bsample(srcB, b, NsB, HsB, oh, ow, Hi, c);
    }
    xi[idx] += add;
  }
}

// ---------------- host ----------------
extern "C" void kernel_launch(void* const* d_in, const int* in_sizes, int n_in,
                              void* d_out, int out_size, void* d_ws, size_t ws_size,
                              hipStream_t stream) {
  const float* x1 = (const float*)d_in[0];
  const float* xin[4] = {(const float*)d_in[1], (const float*)d_in[2],
                         (const float*)d_in[3], (const float*)d_in[4]};
  const float* cpe_w  = (const float*)d_in[5];
  const float* cpe_b  = (const float*)d_in[6];
  const float* n1_g   = (const float*)d_in[7];
  const float* n1_b   = (const float*)d_in[8];
  const float* qkv_w  = (const float*)d_in[9];
  const float* proj_w = (const float*)d_in[10];
  const float* proj_b = (const float*)d_in[11];
  const float* crpe_w3 = (const float*)d_in[12];
  const float* crpe_b3 = (const float*)d_in[13];
  const float* crpe_w5 = (const float*)d_in[14];
  const float* crpe_b5 = (const float*)d_in[15];
  const float* crpe_w7 = (const float*)d_in[16];
  const float* crpe_b7 = (const float*)d_in[17];
  const float* n2_g   = (const float*)d_in[18];
  const float* n2_b   = (const float*)d_in[19];
  const float* fc1_w  = (const float*)d_in[20];
  const float* fc1_b  = (const float*)d_in[21];
  const float* fc2_w  = (const float*)d_in[22];
  const float* fc2_b  = (const float*)d_in[23];

  float* ws = (float*)d_ws;
  float* XI = ws;                                 // 8,538,112 f32
  float* CC = XI + 8538112;                       // 8,538,112 f32
  u16*   T1 = (u16*)(CC + 8538112);               // bf16, 3,212,288 f32 slots
  float* T2 = CC + 8538112 + 3212288;             // 19,273,728 f32
  float* T3 = T2 + 19273728;                      // 6,422,528 f32 (conv_v; doubles as kv partials)
  float* PM = T3 + 6422528;                       // 131,072
  float* PS = PM + 131072;                        // 131,072
  float* MX = PS + 131072;                        // 2,048
  float* SE = MX + 2048;                          // 2,048
  float* KV = SE + 2048;                          // 65,536
  u16*   WQ = (u16*)(KV + 65536);                 // 786,432 bf16
  u16*   WP = WQ + 786432;
  u16*   W1 = WP + 262144;
  u16*   W2 = W1 + 262144;

  float* out = (float*)d_out;

  cvt_bf16<<<1536, 256, 0, stream>>>(qkv_w, WQ, 786432);
  cvt_bf16<<<512, 256, 0, stream>>>(proj_w, WP, 262144);
  cvt_bf16<<<512, 256, 0, stream>>>(fc1_w, W1, 262144);
  cvt_bf16<<<512, 256, 0, stream>>>(fc2_w, W2, 262144);

  copy_f4<<<8192, 256, 0, stream>>>((const float4*)x1, (float4*)out, 25692160 / 4);

  // ---- phase 1 ----
  for (int i = 0; i < 4; ++i) {
    int H = HS[i], N = NS[i], HW = H * H, R = 8 * N;
    float* xi = XI + (size_t)ROWOFF[i] * 256;
    float* ci = CC + (size_t)ROWOFF[i] * 256;
    int total = R * 256;
    int blocks = (total + 255) / 256; if (blocks > 8192) blocks = 8192;

    cpe_kernel<<<blocks, 256, 0, stream>>>(xin[i], cpe_w + i * 2304, cpe_b + i * 256, xi, N, H, total);
    ln_kernel<<<(R + 3) / 4, 256, 0, stream>>>(xi, n1_g + i * 256, n1_b + i * 256, T1, R);

    dim3 gq((R + 127) / 128, 6);
    gemm_mfma<false, false><<<gq, 256, 0, stream>>>(T1, WQ + (size_t)i * 768 * 256,
                                                    nullptr, nullptr, T2, R, 256, 768);

    int NCH = 64, CS = (N + NCH - 1) / NCH;
    ksm_partial<<<dim3(NCH, 8), 256, 0, stream>>>(T2, PM, PS, N, CS, NCH);
    ksm_merge<<<8, 256, 0, stream>>>(PM, PS, MX, SE, NCH);

    int NC = (N + 99) / 100; if (NC > 32) NC = 32; if (NC < 1) NC = 1;
    int chunkrows = (N + NC - 1) / NC;
    kv_partial<<<64 * NC, 1024, 0, stream>>>(T2, MX, T3, N, chunkrows, NC);
    kv_reduce<<<64, 1024, 0, stream>>>(T3, SE, KV, NC);

    int Wq = (H + 3) >> 2;
    {
      int t3 = 8 * H * Wq * 64;
      int b3 = (t3 + 255) / 256; if (b3 > 8192) b3 = 8192;
      crpe_k<3, 0, 64><<<b3, 256, 0, stream>>>(T2, crpe_w3 + i * 576, crpe_b3 + i * 64, T3, N, H, t3);
      int t5 = 8 * H * Wq * 96;
      int b5 = (t5 + 255) / 256; if (b5 > 8192) b5 = 8192;
      crpe_k<5, 64, 96><<<b5, 256, 0, stream>>>(T2, crpe_w5 + i * 2400, crpe_b5 + i * 96, T3, N, H, t5);
      crpe_k<7, 160, 96><<<b5, 256, 0, stream>>>(T2, crpe_w7 + i * 4704, crpe_b7 + i * 96, T3, N, H, t5);
    }

    att_combine<<<dim3((N + 15) / 16, 8), 256, 0, stream>>>(T2, KV, T3, T1, N, HW);

    dim3 gp((R + 127) / 128, 2);
    gemm_mfma<false, false><<<gp, 256, 0, stream>>>(T1, WP + (size_t)i * 65536,
                                                    proj_b + i * 256, nullptr, ci, R, 256, 256);
  }

  // ---- phase 2 ----
  const int SA[4] = {1, 2, 3, 2};
  const int SB[4] = {2, 0, 0, 0};
  for (int i = 0; i < 4; ++i) {
    int N = NS[i], H = HS[i], R = 8 * N, total = R * 256;
    int blocks = (total + 255) / 256; if (blocks > 8192) blocks = 8192;
    combine_kernel<<<blocks, 256, 0, stream>>>(
        XI + (size_t)ROWOFF[i] * 256, CC + (size_t)ROWOFF[i] * 256,
        CC + (size_t)ROWOFF[SA[i]] * 256, HS[SA[i]], NS[SA[i]],
        CC + (size_t)ROWOFF[SB[i]] * 256, HS[SB[i]], NS[SB[i]],
        N, H, total);
  }

  // ---- phase 3 ----
  u16* T2h = (u16*)T2;
  for (int i = 0; i < 4; ++i) {
    int N = NS[i], R = 8 * N;
    float* xi = XI + (size_t)ROWOFF[i] * 256;
    ln_kernel<<<(R + 3) / 4, 256, 0, stream>>>(xi, n2_g + i * 256, n2_b + i * 256, T1, R);
    float* osec = out + OUTOFF[i];
    dim3 g1((R + 127) / 128, 8);
    gemm_mfma<true, true><<<g1, 256, 0, stream>>>(T1, W1, fc1_b, nullptr, (void*)T2h, R, 256, 1024);
    dim3 g2((R + 127) / 128, 2);
    gemm_mfma<false, false><<<g2, 256, 0, stream>>>(T2h, W2, fc2_b, xi, osec, R, 1024, 256);
  }
}

// Round 4
// 1046.846 us; speedup vs baseline: 2.3345x; 1.1470x over previous
//
#include <hip/hip_runtime.h>
#include <math.h>

typedef unsigned short u16;
typedef __attribute__((ext_vector_type(8))) short bf16x8;
typedef __attribute__((ext_vector_type(4))) float f32x4;

static const int HS[4]     = {56, 28, 14, 7};
static const int NS[4]     = {3137, 785, 197, 50};
static const int ROWOFF[4] = {0, 25096, 31376, 32952};
static const size_t OUTOFF[4] = {25692160ull, 32116736ull, 33724416ull, 34127872ull};

#define DEV __device__ __forceinline__

DEV u16 f2bf(float x) {
  union { float f; unsigned u; } v; v.f = x;
  unsigned r = v.u + 0x7fffu + ((v.u >> 16) & 1u);
  return (u16)(r >> 16);
}

DEV float fast_erf(float x) {
  // Abramowitz-Stegun 7.1.26, |err| <= 1.5e-7
  float ax = fabsf(x);
  float tt = 1.0f / (1.0f + 0.3275911f * ax);
  float y = tt * (0.254829592f + tt * (-0.284496736f + tt * (1.421413741f +
            tt * (-1.453152027f + tt * 1.061405429f))));
  float r = 1.0f - y * __expf(-ax * ax);
  return copysignf(r, x);
}

struct alignas(8) u16x4 { u16 x, y, z, w; };

// ---------------- weight fp32 -> bf16 ----------------
__global__ void cvt_bf16(const float* __restrict__ src, u16* __restrict__ dst, int n) {
  for (int i = blockIdx.x * blockDim.x + threadIdx.x; i < n; i += gridDim.x * blockDim.x)
    dst[i] = f2bf(src[i]);
}

// ---------------- x1 passthrough ----------------
__global__ void copy_f4(const float4* __restrict__ src, float4* __restrict__ dst, int n4) {
  for (int i = blockIdx.x * blockDim.x + threadIdx.x; i < n4; i += gridDim.x * blockDim.x)
    dst[i] = src[i];
}

// ---------------- CPE: depthwise 3x3 + bias + residual ----------------
__global__ void cpe_kernel(const float* __restrict__ x, const float* __restrict__ w,
                           const float* __restrict__ bias, float* __restrict__ out,
                           int N, int H, int total) {
  int W = H;
  for (int idx = blockIdx.x * blockDim.x + threadIdx.x; idx < total; idx += gridDim.x * blockDim.x) {
    int c = idx & 255;
    int row = idx >> 8;
    int n = row % N;
    int b = row / N;
    float xv = x[idx];
    if (n == 0) { out[idx] = xv; continue; }
    int p = n - 1, h0 = p / W, w0 = p % W;
    float acc = bias[c];
    const float* wc = w + c * 9;
    #pragma unroll
    for (int kh = 0; kh < 3; ++kh) {
      int hh = h0 + kh - 1;
      if (hh < 0 || hh >= H) continue;
      #pragma unroll
      for (int kw = 0; kw < 3; ++kw) {
        int ww = w0 + kw - 1;
        if (ww < 0 || ww >= W) continue;
        acc += x[(((size_t)b * N) + 1 + hh * W + ww) * 256 + c] * wc[kh * 3 + kw];
      }
    }
    out[idx] = acc + xv;
  }
}

// ---------------- LayerNorm over C=256, bf16 out ----------------
__global__ void ln_kernel(const float* __restrict__ x, const float* __restrict__ g,
                          const float* __restrict__ bt, u16* __restrict__ out, int rows) {
  int wid = threadIdx.x >> 6, lane = threadIdx.x & 63;
  int row = blockIdx.x * 4 + wid;
  if (row >= rows) return;
  const float* xr = x + (size_t)row * 256;
  float4 v = *(const float4*)(xr + lane * 4);
  float s = v.x + v.y + v.z + v.w;
  #pragma unroll
  for (int off = 32; off; off >>= 1) s += __shfl_down(s, off);
  s = __shfl(s, 0);
  float mu = s * (1.0f / 256.0f);
  float dx = v.x - mu, dy = v.y - mu, dz = v.z - mu, dw = v.w - mu;
  float q = dx * dx + dy * dy + dz * dz + dw * dw;
  #pragma unroll
  for (int off = 32; off; off >>= 1) q += __shfl_down(q, off);
  q = __shfl(q, 0);
  float rs = rsqrtf(q * (1.0f / 256.0f) + 1e-5f);
  float4 gg = *(const float4*)(g + lane * 4);
  float4 bb = *(const float4*)(bt + lane * 4);
  u16x4 o;
  o.x = f2bf(dx * rs * gg.x + bb.x);
  o.y = f2bf(dy * rs * gg.y + bb.y);
  o.z = f2bf(dz * rs * gg.z + bb.z);
  o.w = f2bf(dw * rs * gg.w + bb.w);
  *(u16x4*)(out + (size_t)row * 256 + lane * 4) = o;
}

// ---------------- bf16 MFMA GEMM v2: coalesced swizzled staging + dbuf ----------------
// LDS per matrix tile: [128 rows][64 k] with 16B-group XOR swizzle g ^= (row&7).
DEV void stage_tile(const u16* __restrict__ A, const u16* __restrict__ W,
                    u16* aD, u16* bD, int bm, int bn, int M, int K, int k0) {
  int t = threadIdx.x, wv = t >> 6;
  #pragma unroll
  for (int iss = 0; iss < 4; ++iss) {
    int s = iss * 256 + t;
    int row = s >> 3;
    int gel = ((s & 7) ^ (row & 7)) * 8;   // pre-swizzled source group
    int gr = bm + row; if (gr > M - 1) gr = M - 1;
    const u16* ga = A + (size_t)gr * K + k0 + gel;
    __builtin_amdgcn_global_load_lds(
        (const __attribute__((address_space(1))) void*)ga,
        (__attribute__((address_space(3))) void*)(aD + (size_t)(iss * 256 + wv * 64) * 8),
        16, 0, 0);
    const u16* gb = W + (size_t)(bn + row) * K + k0 + gel;
    __builtin_amdgcn_global_load_lds(
        (const __attribute__((address_space(1))) void*)gb,
        (__attribute__((address_space(3))) void*)(bD + (size_t)(iss * 256 + wv * 64) * 8),
        16, 0, 0);
  }
}

template <bool GELU, bool OUT_BF16>
__launch_bounds__(256, 2)
__global__ void gemm_mfma(const u16* __restrict__ A, const u16* __restrict__ W,
                          const float* __restrict__ bias, const float* __restrict__ res,
                          void* __restrict__ outp, int M, int K, int Nout, int nnt) {
  __shared__ __align__(16) u16 lds[2 * 2 * 128 * 64];   // 64 KB: [buf][A/B][row][64]

  // bijective XCD-chunk swizzle: each XCD owns a contiguous run of row-panel-major ids
  int nblk = gridDim.x;
  int orig = blockIdx.x;
  int q = nblk >> 3, r = nblk & 7;
  int xcd = orig & 7, lin = orig >> 3;
  int wg = (xcd < r ? xcd * (q + 1) : r * (q + 1) + (xcd - r) * q) + lin;
  int bm = (wg / nnt) << 7;
  int bn = (wg % nnt) << 7;

  int t = threadIdx.x, lane = t & 63, wv = t >> 6;
  int wr = wv >> 1, wc = wv & 1;
  f32x4 acc[4][4] = {};

  const int nt = K >> 6;
  stage_tile(A, W, lds, lds + 8192, bm, bn, M, K, 0);

  for (int tt = 0; tt < nt; ++tt) {
    __syncthreads();                       // drains vmcnt(0): buf[tt&1] ready
    if (tt + 1 < nt) {
      u16* aD = lds + ((tt + 1) & 1) * 16384;
      stage_tile(A, W, aD, aD + 8192, bm, bn, M, K, (tt + 1) << 6);
    }
    const u16* aS = lds + (tt & 1) * 16384;
    const u16* bS = aS + 8192;
    #pragma unroll
    for (int kk = 0; kk < 2; ++kk) {
      int qa = kk * 4 + (lane >> 4);
      bf16x8 af[4], bfr[4];
      #pragma unroll
      for (int m = 0; m < 4; ++m) {
        int row = wr * 64 + m * 16 + (lane & 15);
        int sg = qa ^ (row & 7);
        af[m] = *(const bf16x8*)(aS + row * 64 + sg * 8);
      }
      #pragma unroll
      for (int n = 0; n < 4; ++n) {
        int row = wc * 64 + n * 16 + (lane & 15);
        int sg = qa ^ (row & 7);
        bfr[n] = *(const bf16x8*)(bS + row * 64 + sg * 8);
      }
      #pragma unroll
      for (int m = 0; m < 4; ++m)
        #pragma unroll
        for (int n = 0; n < 4; ++n)
          acc[m][n] = __builtin_amdgcn_mfma_f32_16x16x32_bf16(af[m], bfr[n], acc[m][n], 0, 0, 0);
    }
  }

  int rbase = bm + wr * 64 + (lane >> 4) * 4;
  int cbase = bn + wc * 64 + (lane & 15);
  #pragma unroll
  for (int m = 0; m < 4; ++m) {
    #pragma unroll
    for (int rg = 0; rg < 4; ++rg) {
      int rr = rbase + m * 16 + rg;
      if (rr >= M) continue;
      #pragma unroll
      for (int n = 0; n < 4; ++n) {
        int cc = cbase + n * 16;
        float v = acc[m][n][rg];
        if (bias) v += bias[cc];
        if (GELU) v = 0.5f * v * (1.0f + fast_erf(v * 0.70710678118654752f));
        size_t o = (size_t)rr * Nout + cc;
        if (res) v += res[o];
        if (OUT_BF16) ((u16*)outp)[o] = f2bf(v);
        else          ((float*)outp)[o] = v;
      }
    }
  }
}

// ---------------- softmax over tokens for k ----------------
__global__ void ksm_partial(const float* __restrict__ qkv, float* __restrict__ pm,
                            float* __restrict__ ps, int N, int CS, int NCH) {
  int b = blockIdx.y, ch = blockIdx.x, cg = threadIdx.x;
  int n0 = ch * CS, n1 = min(N, n0 + CS);
  float m = -1e30f, s = 0.f;
  for (int n = n0; n < n1; ++n) {
    float v = qkv[((size_t)(b * N + n)) * 768 + 256 + cg];
    float nm = fmaxf(m, v);
    s = s * __expf(m - nm) + __expf(v - nm);
    m = nm;
  }
  pm[(b * NCH + ch) * 256 + cg] = m;
  ps[(b * NCH + ch) * 256 + cg] = s;
}

__global__ void ksm_merge(const float* __restrict__ pm, const float* __restrict__ ps,
                          float* __restrict__ mx, float* __restrict__ se, int NCH) {
  int b = blockIdx.x, cg = threadIdx.x;
  float m = -1e30f, s = 0.f;
  for (int c = 0; c < NCH; ++c) {
    float mc = pm[(b * NCH + c) * 256 + cg];
    float sc = ps[(b * NCH + c) * 256 + cg];
    float nm = fmaxf(m, mc);
    s = s * __expf(m - nm) + sc * __expf(mc - nm);
    m = nm;
  }
  mx[b * 256 + cg] = m;
  se[b * 256 + cg] = s;
}

// ---------------- kv partials: chunked over tokens ----------------
__launch_bounds__(1024)
__global__ void kv_partial(const float* __restrict__ qkv, const float* __restrict__ mx,
                           float* __restrict__ part, int N, int chunkrows, int NC) {
  __shared__ float kl[32][33];
  __shared__ float vl[32][33];
  int blk = blockIdx.x;
  int chunk = blk % NC;
  int bh = blk / NC;
  int b = bh >> 3, h = bh & 7;
  int t = threadIdx.x;
  int i = t >> 5, j = t & 31;
  float mexp = mx[b * 256 + h * 32 + j];
  float acc = 0.f;
  int n0s = chunk * chunkrows, n1s = min(N, n0s + chunkrows);
  for (int n0 = n0s; n0 < n1s; n0 += 32) {
    #pragma unroll
    for (int e = t; e < 2048; e += 1024) {
      int r = e >> 6, cc = e & 63;
      int n = n0 + r;
      bool ok = (n < n1s);
      if (cc < 32) kl[r][cc] = ok ? qkv[((size_t)(b * N + n)) * 768 + 256 + h * 32 + cc] : -1e30f;
      else         vl[r][cc - 32] = ok ? qkv[((size_t)(b * N + n)) * 768 + 512 + h * 32 + (cc - 32)] : 0.f;
    }
    __syncthreads();
    kl[i][j] = __expf(kl[i][j] - mexp);
    __syncthreads();
    #pragma unroll
    for (int nn = 0; nn < 32; ++nn) acc += kl[nn][i] * vl[nn][j];
    __syncthreads();
  }
  part[((size_t)bh * NC + chunk) * 1024 + t] = acc;
}

__global__ void kv_reduce(const float* __restrict__ part, const float* __restrict__ se,
                          float* __restrict__ kv, int NC) {
  int bh = blockIdx.x;
  int t = threadIdx.x;
  int i = t >> 5;
  int b = bh >> 3, h = bh & 7;
  float s = 0.f;
  for (int c = 0; c < NC; ++c) s += part[((size_t)bh * NC + c) * 1024 + t];
  kv[(size_t)bh * 1024 + t] = s / se[b * 256 + h * 32 + i];
}

// ---------------- CRPE depthwise conv, templated, 4-wide register blocking ----------------
template <int KS, int C0, int CS>
__global__ void crpe_k(const float* __restrict__ qkv, const float* __restrict__ w,
                       const float* __restrict__ bias, float* __restrict__ convv,
                       int N, int H, int total) {
  int W = H, Wq = (W + 3) >> 2, HW = H * W;
  constexpr int pad = KS / 2;
  for (int idx = blockIdx.x * blockDim.x + threadIdx.x; idx < total; idx += gridDim.x * blockDim.x) {
    int c = idx % CS;
    int r = idx / CS;
    int qw = r % Wq; r /= Wq;
    int h0 = r % H;
    int b = r / H;
    int w0 = qw << 2;
    const float* wp = w + c * KS * KS;
    float bb = bias[c];
    float o0 = bb, o1 = bb, o2 = bb, o3 = bb;
    const float* vbase = qkv + ((size_t)b * N + 1) * 768 + 512 + C0 + c;
    #pragma unroll
    for (int kh = 0; kh < KS; ++kh) {
      int hh = h0 + kh - pad;
      if (hh < 0 || hh >= H) continue;
      const float* rowp = vbase + (size_t)hh * W * 768;
      float tv[KS + 3];
      #pragma unroll
      for (int j = 0; j < KS + 3; ++j) {
        int ww = w0 - pad + j;
        tv[j] = (ww >= 0 && ww < W) ? rowp[(size_t)ww * 768] : 0.f;
      }
      #pragma unroll
      for (int kw = 0; kw < KS; ++kw) {
        float wvv = wp[kh * KS + kw];
        o0 += tv[kw] * wvv;
        o1 += tv[kw + 1] * wvv;
        o2 += tv[kw + 2] * wvv;
        o3 += tv[kw + 3] * wvv;
      }
    }
    float* op = convv + ((size_t)b * HW + (size_t)h0 * W + w0) * 256 + C0 + c;
    op[0] = o0;
    if (w0 + 1 < W) op[256] = o1;
    if (w0 + 2 < W) op[512] = o2;
    if (w0 + 3 < W) op[768] = o3;
  }
}

// ---------------- att: attp = CH^-0.5 * (q @ kv) + [n>0] q * conv_v (bf16 out) ----------------
__global__ void att_combine(const float* __restrict__ qkv, const float* __restrict__ kvg,
                            const float* __restrict__ convv, u16* __restrict__ attp,
                            int N, int HW) {
  __shared__ float kvl[8192];
  __shared__ float ql[256];
  int b = blockIdx.y;
  int n0 = blockIdx.x * 16;
  int t = threadIdx.x;
  for (int e = t; e < 8192; e += 256) kvl[e] = kvg[(size_t)b * 8192 + e];
  int h = t >> 5, j = t & 31;
  for (int nn = 0; nn < 16; ++nn) {
    int n = n0 + nn;
    if (n >= N) break;
    __syncthreads();
    ql[t] = qkv[((size_t)(b * N + n)) * 768 + t];
    __syncthreads();
    float fa = 0.f;
    const float* kvh = kvl + h * 1024;
    #pragma unroll
    for (int k = 0; k < 32; ++k) fa += ql[h * 32 + k] * kvh[k * 32 + j];
    float v = 0.17677669529663687f * fa;
    if (n > 0) v += ql[t] * convv[(((size_t)b * HW) + (n - 1)) * 256 + t];
    attp[(((size_t)b * N) + n) * 256 + t] = f2bf(v);
  }
}

// ---------------- cross-scale bilinear combine ----------------
DEV float bsample(const float* __restrict__ src, int b, int Ns, int Hs,
                  int oh, int ow, int Hi, int c) {
  float scale = (float)Hs / (float)Hi;
  float sy = (oh + 0.5f) * scale - 0.5f;
  float sx = (ow + 0.5f) * scale - 0.5f;
  float fy0 = floorf(sy), fx0 = floorf(sx);
  float fy = sy - fy0, fx = sx - fx0;
  int y0 = (int)fy0, x0 = (int)fx0;
  int y0c = min(max(y0, 0), Hs - 1), y1c = min(max(y0 + 1, 0), Hs - 1);
  int x0c = min(max(x0, 0), Hs - 1), x1c = min(max(x0 + 1, 0), Hs - 1);
  const float* base = src + ((size_t)b * Ns + 1) * 256 + c;
  float v00 = base[(size_t)(y0c * Hs + x0c) * 256];
  float v01 = base[(size_t)(y0c * Hs + x1c) * 256];
  float v10 = base[(size_t)(y1c * Hs + x0c) * 256];
  float v11 = base[(size_t)(y1c * Hs + x1c) * 256];
  return (1.f - fy) * ((1.f - fx) * v00 + fx * v01) + fy * ((1.f - fx) * v10 + fx * v11);
}

__global__ void combine_kernel(float* __restrict__ xi, const float* __restrict__ ci,
                               const float* __restrict__ srcA, int HsA, int NsA,
                               const float* __restrict__ srcB, int HsB, int NsB,
                               int Ni, int Hi, int total) {
  for (int idx = blockIdx.x * blockDim.x + threadIdx.x; idx < total; idx += gridDim.x * blockDim.x) {
    int c = idx & 255;
    int row = idx >> 8;
    int n = row % Ni;
    int b = row / Ni;
    float add = ci[idx];
    if (n == 0) {
      add += srcA[((size_t)b * NsA) * 256 + c] + srcB[((size_t)b * NsB) * 256 + c];
    } else {
      int p = n - 1, oh = p / Hi, ow = p % Hi;
      add += bsample(srcA, b, NsA, HsA, oh, ow, Hi, c);
      add += bsample(srcB, b, NsB, HsB, oh, ow, Hi, c);
    }
    xi[idx] += add;
  }
}

// ---------------- host ----------------
extern "C" void kernel_launch(void* const* d_in, const int* in_sizes, int n_in,
                              void* d_out, int out_size, void* d_ws, size_t ws_size,
                              hipStream_t stream) {
  const float* x1 = (const float*)d_in[0];
  const float* xin[4] = {(const float*)d_in[1], (const float*)d_in[2],
                         (const float*)d_in[3], (const float*)d_in[4]};
  const float* cpe_w  = (const float*)d_in[5];
  const float* cpe_b  = (const float*)d_in[6];
  const float* n1_g   = (const float*)d_in[7];
  const float* n1_b   = (const float*)d_in[8];
  const float* qkv_w  = (const float*)d_in[9];
  const float* proj_w = (const float*)d_in[10];
  const float* proj_b = (const float*)d_in[11];
  const float* crpe_w3 = (const float*)d_in[12];
  const float* crpe_b3 = (const float*)d_in[13];
  const float* crpe_w5 = (const float*)d_in[14];
  const float* crpe_b5 = (const float*)d_in[15];
  const float* crpe_w7 = (const float*)d_in[16];
  const float* crpe_b7 = (const float*)d_in[17];
  const float* n2_g   = (const float*)d_in[18];
  const float* n2_b   = (const float*)d_in[19];
  const float* fc1_w  = (const float*)d_in[20];
  const float* fc1_b  = (const float*)d_in[21];
  const float* fc2_w  = (const float*)d_in[22];
  const float* fc2_b  = (const float*)d_in[23];

  float* ws = (float*)d_ws;
  float* XI = ws;
  float* CC = XI + 8538112;
  u16*   T1 = (u16*)(CC + 8538112);
  float* T2 = CC + 8538112 + 3212288;
  float* T3 = T2 + 19273728;
  float* PM = T3 + 6422528;
  float* PS = PM + 131072;
  float* MX = PS + 131072;
  float* SE = MX + 2048;
  float* KV = SE + 2048;
  u16*   WQ = (u16*)(KV + 65536);
  u16*   WP = WQ + 786432;
  u16*   W1 = WP + 262144;
  u16*   W2 = W1 + 262144;

  float* out = (float*)d_out;

  cvt_bf16<<<1536, 256, 0, stream>>>(qkv_w, WQ, 786432);
  cvt_bf16<<<512, 256, 0, stream>>>(proj_w, WP, 262144);
  cvt_bf16<<<512, 256, 0, stream>>>(fc1_w, W1, 262144);
  cvt_bf16<<<512, 256, 0, stream>>>(fc2_w, W2, 262144);

  copy_f4<<<8192, 256, 0, stream>>>((const float4*)x1, (float4*)out, 25692160 / 4);

  // ---- phase 1 ----
  for (int i = 0; i < 4; ++i) {
    int H = HS[i], N = NS[i], HW = H * H, R = 8 * N;
    float* xi = XI + (size_t)ROWOFF[i] * 256;
    float* ci = CC + (size_t)ROWOFF[i] * 256;
    int total = R * 256;
    int blocks = (total + 255) / 256; if (blocks > 8192) blocks = 8192;

    cpe_kernel<<<blocks, 256, 0, stream>>>(xin[i], cpe_w + i * 2304, cpe_b + i * 256, xi, N, H, total);
    ln_kernel<<<(R + 3) / 4, 256, 0, stream>>>(xi, n1_g + i * 256, n1_b + i * 256, T1, R);

    int nmt = (R + 127) / 128;
    gemm_mfma<false, false><<<nmt * 6, 256, 0, stream>>>(T1, WQ + (size_t)i * 768 * 256,
                                                         nullptr, nullptr, T2, R, 256, 768, 6);

    int NCH = 64, CS = (N + NCH - 1) / NCH;
    ksm_partial<<<dim3(NCH, 8), 256, 0, stream>>>(T2, PM, PS, N, CS, NCH);
    ksm_merge<<<8, 256, 0, stream>>>(PM, PS, MX, SE, NCH);

    int NC = (N + 99) / 100; if (NC > 32) NC = 32; if (NC < 1) NC = 1;
    int chunkrows = (N + NC - 1) / NC;
    kv_partial<<<64 * NC, 1024, 0, stream>>>(T2, MX, T3, N, chunkrows, NC);
    kv_reduce<<<64, 1024, 0, stream>>>(T3, SE, KV, NC);

    int Wq = (H + 3) >> 2;
    {
      int t3 = 8 * H * Wq * 64;
      int b3 = (t3 + 255) / 256; if (b3 > 8192) b3 = 8192;
      crpe_k<3, 0, 64><<<b3, 256, 0, stream>>>(T2, crpe_w3 + i * 576, crpe_b3 + i * 64, T3, N, H, t3);
      int t5 = 8 * H * Wq * 96;
      int b5 = (t5 + 255) / 256; if (b5 > 8192) b5 = 8192;
      crpe_k<5, 64, 96><<<b5, 256, 0, stream>>>(T2, crpe_w5 + i * 2400, crpe_b5 + i * 96, T3, N, H, t5);
      crpe_k<7, 160, 96><<<b5, 256, 0, stream>>>(T2, crpe_w7 + i * 4704, crpe_b7 + i * 96, T3, N, H, t5);
    }

    att_combine<<<dim3((N + 15) / 16, 8), 256, 0, stream>>>(T2, KV, T3, T1, N, HW);

    gemm_mfma<false, false><<<nmt * 2, 256, 0, stream>>>(T1, WP + (size_t)i * 65536,
                                                         proj_b + i * 256, nullptr, ci, R, 256, 256, 2);
  }

  // ---- phase 2 ----
  const int SA[4] = {1, 2, 3, 2};
  const int SB[4] = {2, 0, 0, 0};
  for (int i = 0; i < 4; ++i) {
    int N = NS[i], H = HS[i], R = 8 * N, total = R * 256;
    int blocks = (total + 255) / 256; if (blocks > 8192) blocks = 8192;
    combine_kernel<<<blocks, 256, 0, stream>>>(
        XI + (size_t)ROWOFF[i] * 256, CC + (size_t)ROWOFF[i] * 256,
        CC + (size_t)ROWOFF[SA[i]] * 256, HS[SA[i]], NS[SA[i]],
        CC + (size_t)ROWOFF[SB[i]] * 256, HS[SB[i]], NS[SB[i]],
        N, H, total);
  }

  // ---- phase 3 ----
  u16* T2h = (u16*)T2;
  for (int i = 0; i < 4; ++i) {
    int N = NS[i], R = 8 * N;
    float* xi = XI + (size_t)ROWOFF[i] * 256;
    ln_kernel<<<(R + 3) / 4, 256, 0, stream>>>(xi, n2_g + i * 256, n2_b + i * 256, T1, R);
    float* osec = out + OUTOFF[i];
    int nmt = (R + 127) / 128;
    gemm_mfma<true, true><<<nmt * 8, 256, 0, stream>>>(T1, W1, fc1_b, nullptr, (void*)T2h, R, 256, 1024, 8);
    gemm_mfma<false, false><<<nmt * 2, 256, 0, stream>>>(T2h, W2, fc2_b, xi, osec, R, 1024, 256, 2);
  }
}

// Round 5
// 1005.707 us; speedup vs baseline: 2.4300x; 1.0409x over previous
//
#include <hip/hip_runtime.h>
#include <math.h>

typedef unsigned short u16;
typedef __attribute__((ext_vector_type(8))) short bf16x8;
typedef __attribute__((ext_vector_type(4))) float f32x4;

static const int HS[4]     = {56, 28, 14, 7};
static const int NS[4]     = {3137, 785, 197, 50};
static const int ROWOFF[4] = {0, 25096, 31376, 32952};
static const size_t OUTOFF[4] = {25692160ull, 32116736ull, 33724416ull, 34127872ull};
#define NP 3200  // planar token stride

#define DEV __device__ __forceinline__

DEV u16 f2bf(float x) {
  union { float f; unsigned u; } v; v.f = x;
  unsigned r = v.u + 0x7fffu + ((v.u >> 16) & 1u);
  return (u16)(r >> 16);
}
DEV float bf2f(u16 x) {
  union { unsigned u; float f; } v; v.u = ((unsigned)x) << 16;
  return v.f;
}

struct alignas(8) u16x4s { u16 x, y, z, w; };
struct alignas(16) U16x8 { u16 d[8]; };

// ---------------- weight fp32 -> bf16 ----------------
__global__ void cvt_bf16(const float* __restrict__ src, u16* __restrict__ dst, int n) {
  for (int i = blockIdx.x * blockDim.x + threadIdx.x; i < n; i += gridDim.x * blockDim.x)
    dst[i] = f2bf(src[i]);
}

// ---------------- x1 passthrough ----------------
__global__ void copy_f4(const float4* __restrict__ src, float4* __restrict__ dst, int n4) {
  for (int i = blockIdx.x * blockDim.x + threadIdx.x; i < n4; i += gridDim.x * blockDim.x)
    dst[i] = src[i];
}

// ---------------- CPE: depthwise 3x3 + bias + residual ----------------
__global__ void cpe_kernel(const float* __restrict__ x, const float* __restrict__ w,
                           const float* __restrict__ bias, float* __restrict__ out,
                           int N, int H, int total) {
  int W = H;
  for (int idx = blockIdx.x * blockDim.x + threadIdx.x; idx < total; idx += gridDim.x * blockDim.x) {
    int c = idx & 255;
    int row = idx >> 8;
    int n = row % N;
    int b = row / N;
    float xv = x[idx];
    if (n == 0) { out[idx] = xv; continue; }
    int p = n - 1, h0 = p / W, w0 = p % W;
    float acc = bias[c];
    const float* wc = w + c * 9;
    #pragma unroll
    for (int kh = 0; kh < 3; ++kh) {
      int hh = h0 + kh - 1;
      if (hh < 0 || hh >= H) continue;
      #pragma unroll
      for (int kw = 0; kw < 3; ++kw) {
        int ww = w0 + kw - 1;
        if (ww < 0 || ww >= W) continue;
        acc += x[(((size_t)b * N) + 1 + hh * W + ww) * 256 + c] * wc[kh * 3 + kw];
      }
    }
    out[idx] = acc + xv;
  }
}

// ---------------- LayerNorm over C=256, bf16 out ----------------
__global__ void ln_kernel(const float* __restrict__ x, const float* __restrict__ g,
                          const float* __restrict__ bt, u16* __restrict__ out, int rows) {
  int wid = threadIdx.x >> 6, lane = threadIdx.x & 63;
  int row = blockIdx.x * 4 + wid;
  if (row >= rows) return;
  const float* xr = x + (size_t)row * 256;
  float4 v = *(const float4*)(xr + lane * 4);
  float s = v.x + v.y + v.z + v.w;
  #pragma unroll
  for (int off = 32; off; off >>= 1) s += __shfl_down(s, off);
  s = __shfl(s, 0);
  float mu = s * (1.0f / 256.0f);
  float dx = v.x - mu, dy = v.y - mu, dz = v.z - mu, dw = v.w - mu;
  float q = dx * dx + dy * dy + dz * dz + dw * dw;
  #pragma unroll
  for (int off = 32; off; off >>= 1) q += __shfl_down(q, off);
  q = __shfl(q, 0);
  float rs = rsqrtf(q * (1.0f / 256.0f) + 1e-5f);
  float4 gg = *(const float4*)(g + lane * 4);
  float4 bb = *(const float4*)(bt + lane * 4);
  u16x4s o;
  o.x = f2bf(dx * rs * gg.x + bb.x);
  o.y = f2bf(dy * rs * gg.y + bb.y);
  o.z = f2bf(dz * rs * gg.z + bb.z);
  o.w = f2bf(dw * rs * gg.w + bb.w);
  *(u16x4s*)(out + (size_t)row * 256 + lane * 4) = o;
}

// ---------------- bf16 MFMA GEMM: swizzled staging + dbuf + LDS-transposed epilogue ----------------
DEV void stage_tile(const u16* __restrict__ A, const u16* __restrict__ W,
                    u16* aD, u16* bD, int bm, int bn, int M, int K, int k0) {
  int t = threadIdx.x, wv = t >> 6;
  #pragma unroll
  for (int iss = 0; iss < 4; ++iss) {
    int s = iss * 256 + t;
    int row = s >> 3;
    int gel = ((s & 7) ^ (row & 7)) * 8;
    int gr = bm + row; if (gr > M - 1) gr = M - 1;
    const u16* ga = A + (size_t)gr * K + k0 + gel;
    __builtin_amdgcn_global_load_lds(
        (const __attribute__((address_space(1))) void*)ga,
        (__attribute__((address_space(3))) void*)(aD + (size_t)(iss * 256 + wv * 64) * 8),
        16, 0, 0);
    const u16* gb = W + (size_t)(bn + row) * K + k0 + gel;
    __builtin_amdgcn_global_load_lds(
        (const __attribute__((address_space(1))) void*)gb,
        (__attribute__((address_space(3))) void*)(bD + (size_t)(iss * 256 + wv * 64) * 8),
        16, 0, 0);
  }
}

template <bool GELU, bool OUT_BF16>
__launch_bounds__(256, 2)
__global__ void gemm_mfma(const u16* __restrict__ A, const u16* __restrict__ W,
                          const float* __restrict__ bias, const float* __restrict__ res,
                          void* __restrict__ outp, int M, int K, int Nout, int nnt) {
  __shared__ __align__(16) float smem[128 * 136];
  u16* lds = (u16*)smem;

  int nblk = gridDim.x, orig = blockIdx.x;
  int q = nblk >> 3, r = nblk & 7;
  int xcd = orig & 7, lin = orig >> 3;
  int wg = (xcd < r ? xcd * (q + 1) : r * (q + 1) + (xcd - r) * q) + lin;
  int bm = (wg / nnt) << 7, bn = (wg % nnt) << 7;

  int t = threadIdx.x, lane = t & 63, wv = t >> 6;
  int wr = wv >> 1, wc = wv & 1;
  f32x4 acc[4][4] = {};

  const int nt = K >> 6;
  stage_tile(A, W, lds, lds + 8192, bm, bn, M, K, 0);

  for (int tt = 0; tt < nt; ++tt) {
    __syncthreads();
    if (tt + 1 < nt) {
      u16* aD = lds + ((tt + 1) & 1) * 16384;
      stage_tile(A, W, aD, aD + 8192, bm, bn, M, K, (tt + 1) << 6);
    }
    const u16* aS = lds + (tt & 1) * 16384;
    const u16* bS = aS + 8192;
    #pragma unroll
    for (int kk = 0; kk < 2; ++kk) {
      int qa = kk * 4 + (lane >> 4);
      bf16x8 af[4], bfr[4];
      #pragma unroll
      for (int m = 0; m < 4; ++m) {
        int row = wr * 64 + m * 16 + (lane & 15);
        int sg = qa ^ (row & 7);
        af[m] = *(const bf16x8*)(aS + row * 64 + sg * 8);
      }
      #pragma unroll
      for (int n = 0; n < 4; ++n) {
        int row = wc * 64 + n * 16 + (lane & 15);
        int sg = qa ^ (row & 7);
        bfr[n] = *(const bf16x8*)(bS + row * 64 + sg * 8);
      }
      #pragma unroll
      for (int m = 0; m < 4; ++m)
        #pragma unroll
        for (int n = 0; n < 4; ++n)
          acc[m][n] = __builtin_amdgcn_mfma_f32_16x16x32_bf16(af[m], bfr[n], acc[m][n], 0, 0, 0);
    }
  }

  // ---- epilogue: acc -> LDS (row-major, pad 136) -> vectorized global ----
  __syncthreads();
  int lrow = wr * 64 + ((lane >> 4) << 2);
  int lcol = wc * 64 + (lane & 15);
  #pragma unroll
  for (int m = 0; m < 4; ++m)
    #pragma unroll
    for (int n = 0; n < 4; ++n)
      #pragma unroll
      for (int rg = 0; rg < 4; ++rg)
        smem[(lrow + m * 16 + rg) * 136 + lcol + n * 16] = acc[m][n][rg];
  __syncthreads();

  int row = t >> 1, c0 = (t & 1) << 6;
  int gr = bm + row;
  if (gr >= M) return;
  int gc = bn + c0;
  const float* srcr = smem + row * 136 + c0;
  #pragma unroll
  for (int j = 0; j < 16; j += 2) {
    float4 a = *(const float4*)(srcr + j * 4);
    float4 b2 = *(const float4*)(srcr + j * 4 + 4);
    float v[8] = {a.x, a.y, a.z, a.w, b2.x, b2.y, b2.z, b2.w};
    if (bias) {
      float4 ba = *(const float4*)(bias + gc + j * 4);
      float4 bb = *(const float4*)(bias + gc + j * 4 + 4);
      v[0] += ba.x; v[1] += ba.y; v[2] += ba.z; v[3] += ba.w;
      v[4] += bb.x; v[5] += bb.y; v[6] += bb.z; v[7] += bb.w;
    }
    if (GELU) {
      #pragma unroll
      for (int e = 0; e < 8; ++e) v[e] = v[e] / (1.0f + __expf(-1.702f * v[e]));
    }
    if (res) {
      const float* rp = res + (size_t)gr * Nout + gc + j * 4;
      float4 ra = *(const float4*)(rp);
      float4 rb = *(const float4*)(rp + 4);
      v[0] += ra.x; v[1] += ra.y; v[2] += ra.z; v[3] += ra.w;
      v[4] += rb.x; v[5] += rb.y; v[6] += rb.z; v[7] += rb.w;
    }
    if (OUT_BF16) {
      U16x8 pk;
      #pragma unroll
      for (int e = 0; e < 8; ++e) pk.d[e] = f2bf(v[e]);
      *(U16x8*)((u16*)outp + (size_t)gr * Nout + gc + j * 4) = pk;
    } else {
      float* op = (float*)outp + (size_t)gr * Nout + gc + j * 4;
      *(float4*)op = make_float4(v[0], v[1], v[2], v[3]);
      *(float4*)(op + 4) = make_float4(v[4], v[5], v[6], v[7]);
    }
  }
}

// ---------------- transpose k,v (bf16 row-major [n][512]) -> planar [b][c][NP] ----------------
__global__ void tp_kernel(const u16* __restrict__ T2kv, u16* __restrict__ KP,
                          u16* __restrict__ VP, int N) {
  __shared__ u16 tl[64][66];
  int nt0 = blockIdx.x * 64, c0 = blockIdx.y * 64, b = blockIdx.z;
  int t = threadIdx.x;
  for (int e = t; e < 4096; e += 256) {
    int n_l = e >> 6, c_l = e & 63;
    int n = nt0 + n_l;
    tl[n_l][c_l] = (n < N) ? T2kv[((size_t)b * N + n) * 512 + c0 + c_l] : (u16)0;
  }
  __syncthreads();
  for (int e = t; e < 4096; e += 256) {
    int c_l = e >> 6, n_l = e & 63;
    int n = nt0 + n_l;
    if (n >= N) continue;
    int cg = c0 + c_l;
    u16 val = tl[n_l][c_l];
    if (cg < 256) KP[((size_t)(b * 256 + cg)) * NP + n] = val;
    else          VP[((size_t)(b * 256 + cg - 256)) * NP + n] = val;
  }
}

// ---------------- k softmax stats: one wave per (b, channel) ----------------
__global__ void ksm_kernel(const u16* __restrict__ KP, float* __restrict__ mx,
                           float* __restrict__ se, int N) {
  int b = blockIdx.y;
  int wv = threadIdx.x >> 6, lane = threadIdx.x & 63;
  int cg = blockIdx.x * 4 + wv;
  const u16* kp = KP + ((size_t)(b * 256 + cg)) * NP;
  float m = -1e30f, s = 0.f;
  for (int n = lane; n < N; n += 64) {
    float v = bf2f(kp[n]);
    float nm = fmaxf(m, v);
    s = s * __expf(m - nm) + __expf(v - nm);
    m = nm;
  }
  #pragma unroll
  for (int off = 1; off < 64; off <<= 1) {
    float mo = __shfl_xor(m, off), so = __shfl_xor(s, off);
    float nm = fmaxf(m, mo);
    s = s * __expf(m - nm) + so * __expf(mo - nm);
    m = nm;
  }
  if (lane == 0) { mx[b * 256 + cg] = m; se[b * 256 + cg] = s; }
}

// ---------------- kv partials from planar ----------------
__launch_bounds__(1024)
__global__ void kv_partial(const u16* __restrict__ KP, const u16* __restrict__ VP,
                           const float* __restrict__ mx, float* __restrict__ part,
                           int N, int chunkrows, int NC) {
  __shared__ float kl[32][65];
  __shared__ float vl[32][65];
  int blk = blockIdx.x;
  int chunk = blk % NC;
  int bh = blk / NC;
  int b = bh >> 3, h = bh & 7;
  int t = threadIdx.x;
  int i = t >> 5, j = t & 31;
  float acc = 0.f;
  int n0s = chunk * chunkrows, n1s = min(N, n0s + chunkrows);
  for (int n0 = n0s; n0 < n1s; n0 += 64) {
    #pragma unroll
    for (int e = t; e < 2048; e += 1024) {
      int c = e >> 6, nn = e & 63;
      int n = n0 + nn;
      bool ok = (n < n1s);
      kl[c][nn] = ok ? bf2f(KP[((size_t)(b * 256 + h * 32 + c)) * NP + n]) : -1e30f;
      vl[c][nn] = ok ? bf2f(VP[((size_t)(b * 256 + h * 32 + c)) * NP + n]) : 0.f;
    }
    __syncthreads();
    #pragma unroll
    for (int e = t; e < 2048; e += 1024) {
      int c = e >> 6, nn = e & 63;
      kl[c][nn] = __expf(kl[c][nn] - mx[b * 256 + h * 32 + c]);
    }
    __syncthreads();
    #pragma unroll
    for (int nn = 0; nn < 64; ++nn) acc += kl[i][nn] * vl[j][nn];
    __syncthreads();
  }
  part[((size_t)bh * NC + chunk) * 1024 + t] = acc;
}

__global__ void kv_reduce(const float* __restrict__ part, const float* __restrict__ se,
                          float* __restrict__ kv, int NC) {
  int bh = blockIdx.x;
  int t = threadIdx.x;
  int i = t >> 5;
  int b = bh >> 3, h = bh & 7;
  float s = 0.f;
  for (int c = 0; c < NC; ++c) s += part[((size_t)bh * NC + c) * 1024 + t];
  kv[(size_t)bh * 1024 + t] = s / se[b * 256 + h * 32 + i];
}

// ---------------- CRPE planar depthwise conv ----------------
template <int KS, int C0>
__global__ void crpe_k(const u16* __restrict__ VP, const float* __restrict__ w,
                       const float* __restrict__ bias, u16* __restrict__ CVP,
                       int H, int HW) {
  int c = blockIdx.x, b = blockIdx.y;
  int W_ = H;
  const u16* vp = VP + ((size_t)(b * 256 + C0 + c)) * NP;
  u16* op = CVP + ((size_t)(b * 256 + C0 + c)) * HW;
  float wreg[KS * KS];
  #pragma unroll
  for (int e = 0; e < KS * KS; ++e) wreg[e] = w[c * KS * KS + e];
  float bb = bias[c];
  constexpr int pad = KS / 2;
  for (int p = threadIdx.x; p < HW; p += 256) {
    int h = p / W_, w0 = p % W_;
    float acc = bb;
    #pragma unroll
    for (int kh = 0; kh < KS; ++kh) {
      int hh = h + kh - pad;
      if (hh < 0 || hh >= H) continue;
      #pragma unroll
      for (int kw = 0; kw < KS; ++kw) {
        int wx = w0 + kw - pad;
        if (wx < 0 || wx >= W_) continue;
        acc += bf2f(vp[1 + hh * W_ + wx]) * wreg[kh * KS + kw];
      }
    }
    op[p] = f2bf(acc);
  }
}

// ---------------- att: attp = CH^-0.5 * (q @ kv) + q * conv_v (bf16 out) ----------------
__global__ void att_combine(const float* __restrict__ q, const u16* __restrict__ CVP,
                            const float* __restrict__ kvg, u16* __restrict__ attp,
                            int N, int HW) {
  __shared__ float kvl[8192];
  __shared__ float ql[256];
  __shared__ float cl[16][260];
  int b = blockIdx.y;
  int n0 = blockIdx.x * 16;
  int t = threadIdx.x;
  for (int e = t; e < 8192; e += 256) kvl[e] = kvg[(size_t)b * 8192 + e];
  for (int e = t; e < 4096; e += 256) {
    int c = e >> 4, nn = e & 15;
    int n = n0 + nn;
    float v = 0.f;
    if (n >= 1 && n < N) v = bf2f(CVP[((size_t)(b * 256 + c)) * HW + n - 1]);
    cl[nn][c] = v;
  }
  int h = t >> 5, j = t & 31;
  for (int nn = 0; nn < 16; ++nn) {
    int n = n0 + nn;
    if (n >= N) break;
    __syncthreads();
    ql[t] = q[((size_t)(b * N + n)) * 256 + t];
    __syncthreads();
    float fa = 0.f;
    const float* kvh = kvl + h * 1024;
    #pragma unroll
    for (int k = 0; k < 32; ++k) fa += ql[h * 32 + k] * kvh[k * 32 + j];
    float v = 0.17677669529663687f * fa + ql[t] * cl[nn][t];
    attp[(((size_t)b * N) + n) * 256 + t] = f2bf(v);
  }
}

// ---------------- cross-scale bilinear combine ----------------
DEV float bsample(const float* __restrict__ src, int b, int Ns, int Hs,
                  int oh, int ow, int Hi, int c) {
  float scale = (float)Hs / (float)Hi;
  float sy = (oh + 0.5f) * scale - 0.5f;
  float sx = (ow + 0.5f) * scale - 0.5f;
  float fy0 = floorf(sy), fx0 = floorf(sx);
  float fy = sy - fy0, fx = sx - fx0;
  int y0 = (int)fy0, x0 = (int)fx0;
  int y0c = min(max(y0, 0), Hs - 1), y1c = min(max(y0 + 1, 0), Hs - 1);
  int x0c = min(max(x0, 0), Hs - 1), x1c = min(max(x0 + 1, 0), Hs - 1);
  const float* base = src + ((size_t)b * Ns + 1) * 256 + c;
  float v00 = base[(size_t)(y0c * Hs + x0c) * 256];
  float v01 = base[(size_t)(y0c * Hs + x1c) * 256];
  float v10 = base[(size_t)(y1c * Hs + x0c) * 256];
  float v11 = base[(size_t)(y1c * Hs + x1c) * 256];
  return (1.f - fy) * ((1.f - fx) * v00 + fx * v01) + fy * ((1.f - fx) * v10 + fx * v11);
}

__global__ void combine_kernel(float* __restrict__ xi, const float* __restrict__ ci,
                               const float* __restrict__ srcA, int HsA, int NsA,
                               const float* __restrict__ srcB, int HsB, int NsB,
                               int Ni, int Hi, int total) {
  for (int idx = blockIdx.x * blockDim.x + threadIdx.x; idx < total; idx += gridDim.x * blockDim.x) {
    int c = idx & 255;
    int row = idx >> 8;
    int n = row % Ni;
    int b = row / Ni;
    float add = ci[idx];
    if (n == 0) {
      add += srcA[((size_t)b * NsA) * 256 + c] + srcB[((size_t)b * NsB) * 256 + c];
    } else {
      int p = n - 1, oh = p / Hi, ow = p % Hi;
      add += bsample(srcA, b, NsA, HsA, oh, ow, Hi, c);
      add += bsample(srcB, b, NsB, HsB, oh, ow, Hi, c);
    }
    xi[idx] += add;
  }
}

// ---------------- host ----------------
extern "C" void kernel_launch(void* const* d_in, const int* in_sizes, int n_in,
                              void* d_out, int out_size, void* d_ws, size_t ws_size,
                              hipStream_t stream) {
  const float* x1 = (const float*)d_in[0];
  const float* xin[4] = {(const float*)d_in[1], (const float*)d_in[2],
                         (const float*)d_in[3], (const float*)d_in[4]};
  const float* cpe_w  = (const float*)d_in[5];
  const float* cpe_b  = (const float*)d_in[6];
  const float* n1_g   = (const float*)d_in[7];
  const float* n1_b   = (const float*)d_in[8];
  const float* qkv_w  = (const float*)d_in[9];
  const float* proj_w = (const float*)d_in[10];
  const float* proj_b = (const float*)d_in[11];
  const float* crpe_w3 = (const float*)d_in[12];
  const float* crpe_b3 = (const float*)d_in[13];
  const float* crpe_w5 = (const float*)d_in[14];
  const float* crpe_b5 = (const float*)d_in[15];
  const float* crpe_w7 = (const float*)d_in[16];
  const float* crpe_b7 = (const float*)d_in[17];
  const float* n2_g   = (const float*)d_in[18];
  const float* n2_b   = (const float*)d_in[19];
  const float* fc1_w  = (const float*)d_in[20];
  const float* fc1_b  = (const float*)d_in[21];
  const float* fc2_w  = (const float*)d_in[22];
  const float* fc2_b  = (const float*)d_in[23];

  float* ws = (float*)d_ws;
  float* XI  = ws;                         // 8,538,112
  float* CC  = XI + 8538112;               // 8,538,112
  u16*   T1  = (u16*)(CC + 8538112);       // 3,212,288 f32 slots (bf16 [R][256])
  float* T2q = CC + 8538112 + 3212288;     // 6,424,576 f32
  u16*   T2kv = (u16*)(T2q + 6424576);     // 6,424,576 f32 slots (bf16 [R][512])
  u16*   KP  = T2kv + 12849152;            // 3,276,800 f32 slots (bf16 planar)
  u16*   VP  = KP + 6553600;               // 3,276,800 f32 slots
  u16*   CVP = VP + 6553600;               // 3,211,264 f32 slots (bf16 planar conv / f32 kv partials)
  float* PRT = (float*)CVP;                // overlay: kv partials (<= 2,097,152 f32)
  float* MX  = (float*)(CVP + 6422528);    // 2,048
  float* SE  = MX + 2048;                  // 2,048
  float* KV  = SE + 2048;                  // 65,536
  u16*   WQ  = (u16*)(KV + 65536);         // 786,432 u16
  u16*   WP  = WQ + 786432;                // 262,144 u16
  u16*   W1  = WP + 262144;
  u16*   W2  = W1 + 262144;
  u16*   T2h = (u16*)T2q;                  // phase-3 overlay: mlp hidden bf16 [R][1024]

  float* out = (float*)d_out;

  cvt_bf16<<<1536, 256, 0, stream>>>(qkv_w, WQ, 786432);
  cvt_bf16<<<512, 256, 0, stream>>>(proj_w, WP, 262144);
  cvt_bf16<<<512, 256, 0, stream>>>(fc1_w, W1, 262144);
  cvt_bf16<<<512, 256, 0, stream>>>(fc2_w, W2, 262144);

  copy_f4<<<8192, 256, 0, stream>>>((const float4*)x1, (float4*)out, 25692160 / 4);

  // ---- phase 1 ----
  for (int i = 0; i < 4; ++i) {
    int H = HS[i], N = NS[i], HW = H * H, R = 8 * N;
    float* xi = XI + (size_t)ROWOFF[i] * 256;
    float* ci = CC + (size_t)ROWOFF[i] * 256;
    int total = R * 256;
    int blocks = (total + 255) / 256; if (blocks > 8192) blocks = 8192;

    cpe_kernel<<<blocks, 256, 0, stream>>>(xin[i], cpe_w + i * 2304, cpe_b + i * 256, xi, N, H, total);
    ln_kernel<<<(R + 3) / 4, 256, 0, stream>>>(xi, n1_g + i * 256, n1_b + i * 256, T1, R);

    int nmt = (R + 127) / 128;
    const u16* WQi = WQ + (size_t)i * 768 * 256;
    gemm_mfma<false, false><<<nmt * 2, 256, 0, stream>>>(T1, WQi, nullptr, nullptr, T2q, R, 256, 256, 2);
    gemm_mfma<false, true><<<nmt * 4, 256, 0, stream>>>(T1, WQi + 65536, nullptr, nullptr, T2kv, R, 256, 512, 4);

    tp_kernel<<<dim3((N + 63) / 64, 8, 8), 256, 0, stream>>>(T2kv, KP, VP, N);

    ksm_kernel<<<dim3(64, 8), 256, 0, stream>>>(KP, MX, SE, N);

    int NC = (N + 99) / 100; if (NC > 32) NC = 32; if (NC < 1) NC = 1;
    int chunkrows = (N + NC - 1) / NC;
    kv_partial<<<64 * NC, 1024, 0, stream>>>(KP, VP, MX, PRT, N, chunkrows, NC);
    kv_reduce<<<64, 1024, 0, stream>>>(PRT, SE, KV, NC);

    crpe_k<3, 0><<<dim3(64, 8), 256, 0, stream>>>(VP, crpe_w3 + i * 576, crpe_b3 + i * 64, CVP, H, HW);
    crpe_k<5, 64><<<dim3(96, 8), 256, 0, stream>>>(VP, crpe_w5 + i * 2400, crpe_b5 + i * 96, CVP, H, HW);
    crpe_k<7, 160><<<dim3(96, 8), 256, 0, stream>>>(VP, crpe_w7 + i * 4704, crpe_b7 + i * 96, CVP, H, HW);

    att_combine<<<dim3((N + 15) / 16, 8), 256, 0, stream>>>(T2q, CVP, KV, T1, N, HW);

    gemm_mfma<false, false><<<nmt * 2, 256, 0, stream>>>(T1, WP + (size_t)i * 65536,
                                                         proj_b + i * 256, nullptr, ci, R, 256, 256, 2);
  }

  // ---- phase 2 ----
  const int SA[4] = {1, 2, 3, 2};
  const int SB[4] = {2, 0, 0, 0};
  for (int i = 0; i < 4; ++i) {
    int N = NS[i], H = HS[i], R = 8 * N, total = R * 256;
    int blocks = (total + 255) / 256; if (blocks > 8192) blocks = 8192;
    combine_kernel<<<blocks, 256, 0, stream>>>(
        XI + (size_t)ROWOFF[i] * 256, CC + (size_t)ROWOFF[i] * 256,
        CC + (size_t)ROWOFF[SA[i]] * 256, HS[SA[i]], NS[SA[i]],
        CC + (size_t)ROWOFF[SB[i]] * 256, HS[SB[i]], NS[SB[i]],
        N, H, total);
  }

  // ---- phase 3 ----
  for (int i = 0; i < 4; ++i) {
    int N = NS[i], R = 8 * N;
    float* xi = XI + (size_t)ROWOFF[i] * 256;
    ln_kernel<<<(R + 3) / 4, 256, 0, stream>>>(xi, n2_g + i * 256, n2_b + i * 256, T1, R);
    float* osec = out + OUTOFF[i];
    int nmt = (R + 127) / 128;
    gemm_mfma<true, true><<<nmt * 8, 256, 0, stream>>>(T1, W1, fc1_b, nullptr, (void*)T2h, R, 256, 1024, 8);
    gemm_mfma<false, false><<<nmt * 2, 256, 0, stream>>>(T2h, W2, fc2_b, xi, osec, R, 1024, 256, 2);
  }
}

// Round 6
// 832.354 us; speedup vs baseline: 2.9361x; 1.2083x over previous
//
#include <hip/hip_runtime.h>
#include <math.h>

typedef unsigned short u16;
typedef __attribute__((ext_vector_type(8))) short bf16x8;
typedef __attribute__((ext_vector_type(4))) float f32x4;

static const int HS[4]     = {56, 28, 14, 7};
static const int NS[4]     = {3137, 785, 197, 50};
static const int ROWOFF[4] = {0, 25096, 31376, 32952};
static const size_t OUTOFF[4] = {25692160ull, 32116736ull, 33724416ull, 34127872ull};
#define NP 3200  // planar token stride

#define DEV __device__ __forceinline__

DEV u16 f2bf(float x) {
  union { float f; unsigned u; } v; v.f = x;
  unsigned r = v.u + 0x7fffu + ((v.u >> 16) & 1u);
  return (u16)(r >> 16);
}
DEV float bf2f(u16 x) {
  union { unsigned u; float f; } v; v.u = ((unsigned)x) << 16;
  return v.f;
}

struct alignas(8) u16x4s { u16 x, y, z, w; };
struct alignas(16) U16x8 { u16 d[8]; };

// ---------------- weight fp32 -> bf16 ----------------
__global__ void cvt_bf16(const float* __restrict__ src, u16* __restrict__ dst, int n) {
  for (int i = blockIdx.x * blockDim.x + threadIdx.x; i < n; i += gridDim.x * blockDim.x)
    dst[i] = f2bf(src[i]);
}

// ---------------- cpe weights [4][256][9] -> [4][9][256] ----------------
__global__ void tpw_cpe(const float* __restrict__ src, float* __restrict__ dst) {
  int i = blockIdx.y;
  int e = blockIdx.x * 256 + threadIdx.x;
  if (e < 2304) {
    int c = e / 9, k = e % 9;
    dst[i * 2304 + k * 256 + c] = src[i * 2304 + c * 9 + k];
  }
}

// ---------------- x1 passthrough ----------------
__global__ void copy_f4(const float4* __restrict__ src, float4* __restrict__ dst, int n4) {
  for (int i = blockIdx.x * blockDim.x + threadIdx.x; i < n4; i += gridDim.x * blockDim.x)
    dst[i] = src[i];
}

// ---------------- CPE: depthwise 3x3 + bias + residual, float4 channels ----------------
__global__ void cpe_kernel(const float* __restrict__ x, const float* __restrict__ wT,
                           const float* __restrict__ bias, float* __restrict__ out,
                           int N, int H, int total4) {
  int W = H;
  for (int idx = blockIdx.x * blockDim.x + threadIdx.x; idx < total4; idx += gridDim.x * blockDim.x) {
    int c4 = (idx & 63) << 2;
    int row = idx >> 6;
    int n = row % N;
    int b = row / N;
    float4 xv = *(const float4*)(x + (size_t)row * 256 + c4);
    float4 o = xv;
    if (n > 0) {
      int p = n - 1, h0 = p / W, w0 = p % W;
      float4 acc = *(const float4*)(bias + c4);
      #pragma unroll
      for (int kh = 0; kh < 3; ++kh) {
        int hh = h0 + kh - 1;
        if (hh < 0 || hh >= H) continue;
        #pragma unroll
        for (int kw = 0; kw < 3; ++kw) {
          int ww = w0 + kw - 1;
          if (ww < 0 || ww >= W) continue;
          float4 t = *(const float4*)(x + (((size_t)b * N) + 1 + hh * W + ww) * 256 + c4);
          float4 wv = *(const float4*)(wT + (kh * 3 + kw) * 256 + c4);
          acc.x += t.x * wv.x; acc.y += t.y * wv.y;
          acc.z += t.z * wv.z; acc.w += t.w * wv.w;
        }
      }
      o.x += acc.x; o.y += acc.y; o.z += acc.z; o.w += acc.w;
    }
    *(float4*)(out + (size_t)row * 256 + c4) = o;
  }
}

// ---------------- LayerNorm over C=256, bf16 out ----------------
__global__ void ln_kernel(const float* __restrict__ x, const float* __restrict__ g,
                          const float* __restrict__ bt, u16* __restrict__ out, int rows) {
  int wid = threadIdx.x >> 6, lane = threadIdx.x & 63;
  int row = blockIdx.x * 4 + wid;
  if (row >= rows) return;
  const float* xr = x + (size_t)row * 256;
  float4 v = *(const float4*)(xr + lane * 4);
  float s = v.x + v.y + v.z + v.w;
  #pragma unroll
  for (int off = 32; off; off >>= 1) s += __shfl_down(s, off);
  s = __shfl(s, 0);
  float mu = s * (1.0f / 256.0f);
  float dx = v.x - mu, dy = v.y - mu, dz = v.z - mu, dw = v.w - mu;
  float q = dx * dx + dy * dy + dz * dz + dw * dw;
  #pragma unroll
  for (int off = 32; off; off >>= 1) q += __shfl_down(q, off);
  q = __shfl(q, 0);
  float rs = rsqrtf(q * (1.0f / 256.0f) + 1e-5f);
  float4 gg = *(const float4*)(g + lane * 4);
  float4 bb = *(const float4*)(bt + lane * 4);
  u16x4s o;
  o.x = f2bf(dx * rs * gg.x + bb.x);
  o.y = f2bf(dy * rs * gg.y + bb.y);
  o.z = f2bf(dz * rs * gg.z + bb.z);
  o.w = f2bf(dw * rs * gg.w + bb.w);
  *(u16x4s*)(out + (size_t)row * 256 + lane * 4) = o;
}

// ---------------- bf16 MFMA GEMM: swizzled staging + dbuf + LDS-transposed epilogue ----------------
DEV void stage_tile(const u16* __restrict__ A, const u16* __restrict__ W,
                    u16* aD, u16* bD, int bm, int bn, int M, int K, int k0) {
  int t = threadIdx.x, wv = t >> 6;
  #pragma unroll
  for (int iss = 0; iss < 4; ++iss) {
    int s = iss * 256 + t;
    int row = s >> 3;
    int gel = ((s & 7) ^ (row & 7)) * 8;
    int gr = bm + row; if (gr > M - 1) gr = M - 1;
    const u16* ga = A + (size_t)gr * K + k0 + gel;
    __builtin_amdgcn_global_load_lds(
        (const __attribute__((address_space(1))) void*)ga,
        (__attribute__((address_space(3))) void*)(aD + (size_t)(iss * 256 + wv * 64) * 8),
        16, 0, 0);
    const u16* gb = W + (size_t)(bn + row) * K + k0 + gel;
    __builtin_amdgcn_global_load_lds(
        (const __attribute__((address_space(1))) void*)gb,
        (__attribute__((address_space(3))) void*)(bD + (size_t)(iss * 256 + wv * 64) * 8),
        16, 0, 0);
  }
}

template <bool GELU, bool OUT_BF16>
__launch_bounds__(256, 2)
__global__ void gemm_mfma(const u16* __restrict__ A, const u16* __restrict__ W,
                          const float* __restrict__ bias, const float* __restrict__ res,
                          void* __restrict__ outp, int M, int K, int Nout, int nnt) {
  __shared__ __align__(16) float smem[128 * 136];
  u16* lds = (u16*)smem;

  int nblk = gridDim.x, orig = blockIdx.x;
  int q = nblk >> 3, r = nblk & 7;
  int xcd = orig & 7, lin = orig >> 3;
  int wg = (xcd < r ? xcd * (q + 1) : r * (q + 1) + (xcd - r) * q) + lin;
  int bm = (wg / nnt) << 7, bn = (wg % nnt) << 7;

  int t = threadIdx.x, lane = t & 63, wv = t >> 6;
  int wr = wv >> 1, wc = wv & 1;
  f32x4 acc[4][4] = {};

  const int nt = K >> 6;
  stage_tile(A, W, lds, lds + 8192, bm, bn, M, K, 0);

  for (int tt = 0; tt < nt; ++tt) {
    __syncthreads();
    if (tt + 1 < nt) {
      u16* aD = lds + ((tt + 1) & 1) * 16384;
      stage_tile(A, W, aD, aD + 8192, bm, bn, M, K, (tt + 1) << 6);
    }
    const u16* aS = lds + (tt & 1) * 16384;
    const u16* bS = aS + 8192;
    #pragma unroll
    for (int kk = 0; kk < 2; ++kk) {
      int qa = kk * 4 + (lane >> 4);
      bf16x8 af[4], bfr[4];
      #pragma unroll
      for (int m = 0; m < 4; ++m) {
        int row = wr * 64 + m * 16 + (lane & 15);
        int sg = qa ^ (row & 7);
        af[m] = *(const bf16x8*)(aS + row * 64 + sg * 8);
      }
      #pragma unroll
      for (int n = 0; n < 4; ++n) {
        int row = wc * 64 + n * 16 + (lane & 15);
        int sg = qa ^ (row & 7);
        bfr[n] = *(const bf16x8*)(bS + row * 64 + sg * 8);
      }
      #pragma unroll
      for (int m = 0; m < 4; ++m)
        #pragma unroll
        for (int n = 0; n < 4; ++n)
          acc[m][n] = __builtin_amdgcn_mfma_f32_16x16x32_bf16(af[m], bfr[n], acc[m][n], 0, 0, 0);
    }
  }

  __syncthreads();
  int lrow = wr * 64 + ((lane >> 4) << 2);
  int lcol = wc * 64 + (lane & 15);
  #pragma unroll
  for (int m = 0; m < 4; ++m)
    #pragma unroll
    for (int n = 0; n < 4; ++n)
      #pragma unroll
      for (int rg = 0; rg < 4; ++rg)
        smem[(lrow + m * 16 + rg) * 136 + lcol + n * 16] = acc[m][n][rg];
  __syncthreads();

  int row = t >> 1, c0 = (t & 1) << 6;
  int gr = bm + row;
  if (gr >= M) return;
  int gc = bn + c0;
  const float* srcr = smem + row * 136 + c0;
  #pragma unroll
  for (int j = 0; j < 16; j += 2) {
    float4 a = *(const float4*)(srcr + j * 4);
    float4 b2 = *(const float4*)(srcr + j * 4 + 4);
    float v[8] = {a.x, a.y, a.z, a.w, b2.x, b2.y, b2.z, b2.w};
    if (bias) {
      float4 ba = *(const float4*)(bias + gc + j * 4);
      float4 bb = *(const float4*)(bias + gc + j * 4 + 4);
      v[0] += ba.x; v[1] += ba.y; v[2] += ba.z; v[3] += ba.w;
      v[4] += bb.x; v[5] += bb.y; v[6] += bb.z; v[7] += bb.w;
    }
    if (GELU) {
      #pragma unroll
      for (int e = 0; e < 8; ++e) v[e] = v[e] / (1.0f + __expf(-1.702f * v[e]));
    }
    if (res) {
      const float* rp = res + (size_t)gr * Nout + gc + j * 4;
      float4 ra = *(const float4*)(rp);
      float4 rb = *(const float4*)(rp + 4);
      v[0] += ra.x; v[1] += ra.y; v[2] += ra.z; v[3] += ra.w;
      v[4] += rb.x; v[5] += rb.y; v[6] += rb.z; v[7] += rb.w;
    }
    if (OUT_BF16) {
      U16x8 pk;
      #pragma unroll
      for (int e = 0; e < 8; ++e) pk.d[e] = f2bf(v[e]);
      *(U16x8*)((u16*)outp + (size_t)gr * Nout + gc + j * 4) = pk;
    } else {
      float* op = (float*)outp + (size_t)gr * Nout + gc + j * 4;
      *(float4*)op = make_float4(v[0], v[1], v[2], v[3]);
      *(float4*)(op + 4) = make_float4(v[4], v[5], v[6], v[7]);
    }
  }
}

// ---------------- transpose k,v -> planar [b][c][NP] + padded v image [b][c][h][64] ----------------
__global__ void tp_kernel(const u16* __restrict__ T2kv, u16* __restrict__ KP,
                          u16* __restrict__ VP, u16* __restrict__ VPI, int N, int H) {
  __shared__ u16 tl[64][66];
  int nt0 = blockIdx.x * 64, c0 = blockIdx.y * 64, b = blockIdx.z;
  int t = threadIdx.x;
  int W = H;
  for (int e = t; e < 4096; e += 256) {
    int n_l = e >> 6, c_l = e & 63;
    int n = nt0 + n_l;
    tl[n_l][c_l] = (n < N) ? T2kv[((size_t)b * N + n) * 512 + c0 + c_l] : (u16)0;
  }
  __syncthreads();
  for (int e = t; e < 4096; e += 256) {
    int c_l = e >> 6, n_l = e & 63;
    int n = nt0 + n_l;
    if (n >= N) continue;
    int cg = c0 + c_l;
    u16 val = tl[n_l][c_l];
    if (cg < 256) {
      KP[((size_t)(b * 256 + cg)) * NP + n] = val;
    } else {
      int cc = cg - 256;
      VP[((size_t)(b * 256 + cc)) * NP + n] = val;
      if (n >= 1) {
        int p = n - 1;
        VPI[(size_t)(b * 256 + cc) * (size_t)(H * 64) + (p / W) * 64 + (p % W)] = val;
      }
    }
  }
}

// ---------------- k softmax stats: one wave per (b, channel) ----------------
__global__ void ksm_kernel(const u16* __restrict__ KP, float* __restrict__ mx,
                           float* __restrict__ se, int N) {
  int b = blockIdx.y;
  int wv = threadIdx.x >> 6, lane = threadIdx.x & 63;
  int cg = blockIdx.x * 4 + wv;
  const u16* kp = KP + ((size_t)(b * 256 + cg)) * NP;
  float m = -1e30f, s = 0.f;
  for (int n = lane; n < N; n += 64) {
    float v = bf2f(kp[n]);
    float nm = fmaxf(m, v);
    s = s * __expf(m - nm) + __expf(v - nm);
    m = nm;
  }
  #pragma unroll
  for (int off = 1; off < 64; off <<= 1) {
    float mo = __shfl_xor(m, off), so = __shfl_xor(s, off);
    float nm = fmaxf(m, mo);
    s = s * __expf(m - nm) + so * __expf(mo - nm);
    m = nm;
  }
  if (lane == 0) { mx[b * 256 + cg] = m; se[b * 256 + cg] = s; }
}

// ---------------- kv partials from planar ----------------
__launch_bounds__(1024)
__global__ void kv_partial(const u16* __restrict__ KP, const u16* __restrict__ VP,
                           const float* __restrict__ mx, float* __restrict__ part,
                           int N, int chunkrows, int NC) {
  __shared__ float kl[32][65];
  __shared__ float vl[32][65];
  int blk = blockIdx.x;
  int chunk = blk % NC;
  int bh = blk / NC;
  int b = bh >> 3, h = bh & 7;
  int t = threadIdx.x;
  int i = t >> 5, j = t & 31;
  float acc = 0.f;
  int n0s = chunk * chunkrows, n1s = min(N, n0s + chunkrows);
  for (int n0 = n0s; n0 < n1s; n0 += 64) {
    #pragma unroll
    for (int e = t; e < 2048; e += 1024) {
      int c = e >> 6, nn = e & 63;
      int n = n0 + nn;
      bool ok = (n < n1s);
      kl[c][nn] = ok ? bf2f(KP[((size_t)(b * 256 + h * 32 + c)) * NP + n]) : -1e30f;
      vl[c][nn] = ok ? bf2f(VP[((size_t)(b * 256 + h * 32 + c)) * NP + n]) : 0.f;
    }
    __syncthreads();
    #pragma unroll
    for (int e = t; e < 2048; e += 1024) {
      int c = e >> 6, nn = e & 63;
      kl[c][nn] = __expf(kl[c][nn] - mx[b * 256 + h * 32 + c]);
    }
    __syncthreads();
    #pragma unroll
    for (int nn = 0; nn < 64; ++nn) acc += kl[i][nn] * vl[j][nn];
    __syncthreads();
  }
  part[((size_t)bh * NC + chunk) * 1024 + t] = acc;
}

__global__ void kv_reduce(const float* __restrict__ part, const float* __restrict__ se,
                          float* __restrict__ kv, int NC) {
  int bh = blockIdx.x;
  int t = threadIdx.x;
  int i = t >> 5;
  int b = bh >> 3, h = bh & 7;
  float s = 0.f;
  for (int c = 0; c < NC; ++c) s += part[((size_t)bh * NC + c) * 1024 + t];
  kv[(size_t)bh * 1024 + t] = s / se[b * 256 + h * 32 + i];
}

// ---------------- CRPE depthwise conv on padded planes: 8 outputs/thread ----------------
template <int KS, int C0, int CS>
__global__ void crpe_k(const u16* __restrict__ VPI, const float* __restrict__ w,
                       const float* __restrict__ bias, u16* __restrict__ CVPI,
                       int H, int RS) {
  constexpr int pad = KS / 2;
  int c = blockIdx.x, b = blockIdx.y, z = blockIdx.z;
  int G = (H + 7) >> 3;
  int hpb = (H + RS - 1) / RS;
  int h0b = z * hpb;
  int h1b = min(H, h0b + hpb);
  size_t plane = (size_t)(b * 256 + C0 + c) * (size_t)(H * 64);
  const u16* vp = VPI + plane;
  u16* op = CVPI + plane;
  float wreg[KS * KS];
  #pragma unroll
  for (int e = 0; e < KS * KS; ++e) wreg[e] = w[c * KS * KS + e];
  float bb = bias[c];
  int ntask = (h1b - h0b) * G;
  for (int task = threadIdx.x; task < ntask; task += 256) {
    int g = task % G;
    int h = h0b + task / G;
    int w0 = g << 3;
    float o[8];
    #pragma unroll
    for (int e = 0; e < 8; ++e) o[e] = bb;
    #pragma unroll
    for (int kh = 0; kh < KS; ++kh) {
      int hh = h + kh - pad;
      if (hh < 0 || hh >= H) continue;
      const u16* rowp = vp + hh * 64;
      U16x8 ch0 = {}, ch1, ch2;
      if (w0 >= 8) ch0 = *(const U16x8*)(rowp + w0 - 8);
      ch1 = *(const U16x8*)(rowp + w0);
      ch2 = *(const U16x8*)(rowp + w0 + 8);
      float tv[24];
      #pragma unroll
      for (int j = 8 - pad; j <= 15 + pad; ++j) {
        u16 raw = (j < 8) ? ch0.d[j] : (j < 16 ? ch1.d[j - 8] : ch2.d[j - 16]);
        tv[j] = bf2f(raw);
      }
      #pragma unroll
      for (int kw = 0; kw < KS; ++kw) {
        float wv = wreg[kh * KS + kw];
        #pragma unroll
        for (int e = 0; e < 8; ++e) o[e] += tv[8 + e + kw - pad] * wv;
      }
    }
    U16x8 pk;
    #pragma unroll
    for (int e = 0; e < 8; ++e) pk.d[e] = f2bf(o[e]);
    *(U16x8*)(op + h * 64 + w0) = pk;
  }
}

// ---------------- att: attp = CH^-0.5 * (q @ kv) + q * conv_v (bf16 out) ----------------
__global__ void att_combine(const float* __restrict__ q, const u16* __restrict__ CVPI,
                            const float* __restrict__ kvg, u16* __restrict__ attp,
                            int N, int H) {
  __shared__ float kvl[8192];
  __shared__ float ql[256];
  __shared__ float cl[16][260];
  int b = blockIdx.y;
  int n0 = blockIdx.x * 16;
  int t = threadIdx.x;
  int HW64 = H * 64;
  for (int e = t; e < 8192; e += 256) kvl[e] = kvg[(size_t)b * 8192 + e];
  for (int e = t; e < 4096; e += 256) {
    int c = e >> 4, nn = e & 15;
    int n = n0 + nn;
    float v = 0.f;
    if (n >= 1 && n < N) {
      int p = n - 1;
      v = bf2f(CVPI[(size_t)(b * 256 + c) * HW64 + (p / H) * 64 + (p % H)]);
    }
    cl[nn][c] = v;
  }
  int h = t >> 5, j = t & 31;
  for (int nn = 0; nn < 16; ++nn) {
    int n = n0 + nn;
    if (n >= N) break;
    __syncthreads();
    ql[t] = q[((size_t)(b * N + n)) * 256 + t];
    __syncthreads();
    float fa = 0.f;
    const float* kvh = kvl + h * 1024;
    #pragma unroll
    for (int k = 0; k < 32; ++k) fa += ql[h * 32 + k] * kvh[k * 32 + j];
    float v = 0.17677669529663687f * fa + ql[t] * cl[nn][t];
    attp[(((size_t)b * N) + n) * 256 + t] = f2bf(v);
  }
}

// ---------------- cross-scale bilinear combine, float4 channels ----------------
DEV float4 bsample4(const float* __restrict__ src, int b, int Ns, int Hs,
                    int oh, int ow, int Hi, int c4) {
  float scale = (float)Hs / (float)Hi;
  float sy = (oh + 0.5f) * scale - 0.5f;
  float sx = (ow + 0.5f) * scale - 0.5f;
  float fy0 = floorf(sy), fx0 = floorf(sx);
  float fy = sy - fy0, fx = sx - fx0;
  int y0 = (int)fy0, x0 = (int)fx0;
  int y0c = min(max(y0, 0), Hs - 1), y1c = min(max(y0 + 1, 0), Hs - 1);
  int x0c = min(max(x0, 0), Hs - 1), x1c = min(max(x0 + 1, 0), Hs - 1);
  const float* base = src + ((size_t)b * Ns + 1) * 256 + c4;
  float4 v00 = *(const float4*)(base + (size_t)(y0c * Hs + x0c) * 256);
  float4 v01 = *(const float4*)(base + (size_t)(y0c * Hs + x1c) * 256);
  float4 v10 = *(const float4*)(base + (size_t)(y1c * Hs + x0c) * 256);
  float4 v11 = *(const float4*)(base + (size_t)(y1c * Hs + x1c) * 256);
  float w00 = (1.f - fy) * (1.f - fx), w01 = (1.f - fy) * fx;
  float w10 = fy * (1.f - fx), w11 = fy * fx;
  float4 r;
  r.x = w00 * v00.x + w01 * v01.x + w10 * v10.x + w11 * v11.x;
  r.y = w00 * v00.y + w01 * v01.y + w10 * v10.y + w11 * v11.y;
  r.z = w00 * v00.z + w01 * v01.z + w10 * v10.z + w11 * v11.z;
  r.w = w00 * v00.w + w01 * v01.w + w10 * v10.w + w11 * v11.w;
  return r;
}

__global__ void combine_kernel(float* __restrict__ xi, const float* __restrict__ ci,
                               const float* __restrict__ srcA, int HsA, int NsA,
                               const float* __restrict__ srcB, int HsB, int NsB,
                               int Ni, int Hi, int total4) {
  for (int idx = blockIdx.x * blockDim.x + threadIdx.x; idx < total4; idx += gridDim.x * blockDim.x) {
    int c4 = (idx & 63) << 2;
    int row = idx >> 6;
    int n = row % Ni;
    int b = row / Ni;
    float4 add = *(const float4*)(ci + (size_t)row * 256 + c4);
    if (n == 0) {
      float4 a = *(const float4*)(srcA + ((size_t)b * NsA) * 256 + c4);
      float4 bb = *(const float4*)(srcB + ((size_t)b * NsB) * 256 + c4);
      add.x += a.x + bb.x; add.y += a.y + bb.y;
      add.z += a.z + bb.z; add.w += a.w + bb.w;
    } else {
      int p = n - 1, oh = p / Hi, ow = p % Hi;
      float4 a = bsample4(srcA, b, NsA, HsA, oh, ow, Hi, c4);
      float4 bb = bsample4(srcB, b, NsB, HsB, oh, ow, Hi, c4);
      add.x += a.x + bb.x; add.y += a.y + bb.y;
      add.z += a.z + bb.z; add.w += a.w + bb.w;
    }
    float* xp = xi + (size_t)row * 256 + c4;
    float4 cur = *(const float4*)xp;
    cur.x += add.x; cur.y += add.y; cur.z += add.z; cur.w += add.w;
    *(float4*)xp = cur;
  }
}

// ---------------- host ----------------
extern "C" void kernel_launch(void* const* d_in, const int* in_sizes, int n_in,
                              void* d_out, int out_size, void* d_ws, size_t ws_size,
                              hipStream_t stream) {
  const float* x1 = (const float*)d_in[0];
  const float* xin[4] = {(const float*)d_in[1], (const float*)d_in[2],
                         (const float*)d_in[3], (const float*)d_in[4]};
  const float* cpe_w  = (const float*)d_in[5];
  const float* cpe_b  = (const float*)d_in[6];
  const float* n1_g   = (const float*)d_in[7];
  const float* n1_b   = (const float*)d_in[8];
  const float* qkv_w  = (const float*)d_in[9];
  const float* proj_w = (const float*)d_in[10];
  const float* proj_b = (const float*)d_in[11];
  const float* crpe_w3 = (const float*)d_in[12];
  const float* crpe_b3 = (const float*)d_in[13];
  const float* crpe_w5 = (const float*)d_in[14];
  const float* crpe_b5 = (const float*)d_in[15];
  const float* crpe_w7 = (const float*)d_in[16];
  const float* crpe_b7 = (const float*)d_in[17];
  const float* n2_g   = (const float*)d_in[18];
  const float* n2_b   = (const float*)d_in[19];
  const float* fc1_w  = (const float*)d_in[20];
  const float* fc1_b  = (const float*)d_in[21];
  const float* fc2_w  = (const float*)d_in[22];
  const float* fc2_b  = (const float*)d_in[23];

  float* ws = (float*)d_ws;
  float* XI   = ws;                        // 8,538,112
  float* CC   = XI + 8538112;              // 8,538,112
  u16*   T1   = (u16*)(CC + 8538112);      // 3,212,288 f32 slots
  float* T2q  = (float*)(T1 + 6424576);    // 6,424,576 f32
  u16*   T2kv = (u16*)(T2q + 6424576);     // 6,424,576 f32 slots (adjacent: fc1-hidden overlay)
  u16*   KP   = T2kv + 12849152;           // 3,276,800 f32 slots
  u16*   VP   = KP + 6553600;              // 3,276,800 f32 slots
  u16*   VPI  = VP + 6553600;              // 3,670,016 f32 slots (2048 x 56 x 64 bf16 max)
  u16*   CVPI = VPI + 7340032;             // 3,670,016 f32 slots (overlay: kv partials f32)
  float* PRT  = (float*)CVPI;
  float* MX   = (float*)(CVPI + 7340032);  // 2,048
  float* SE   = MX + 2048;                 // 2,048
  float* KV   = SE + 2048;                 // 65,536
  u16*   WQ   = (u16*)(KV + 65536);        // 786,432 u16
  u16*   WP   = WQ + 786432;               // 262,144 u16
  u16*   W1   = WP + 262144;
  u16*   W2   = W1 + 262144;
  float* WT   = (float*)(W2 + 262144);     // 9,216 f32 (cpe weights transposed)
  u16*   T2h  = (u16*)T2q;                 // phase-3 overlay

  float* out = (float*)d_out;

  cvt_bf16<<<1536, 256, 0, stream>>>(qkv_w, WQ, 786432);
  cvt_bf16<<<512, 256, 0, stream>>>(proj_w, WP, 262144);
  cvt_bf16<<<512, 256, 0, stream>>>(fc1_w, W1, 262144);
  cvt_bf16<<<512, 256, 0, stream>>>(fc2_w, W2, 262144);
  tpw_cpe<<<dim3(9, 4), 256, 0, stream>>>(cpe_w, WT);

  copy_f4<<<8192, 256, 0, stream>>>((const float4*)x1, (float4*)out, 25692160 / 4);

  // ---- phase 1 ----
  for (int i = 0; i < 4; ++i) {
    int H = HS[i], N = NS[i], R = 8 * N;
    float* xi = XI + (size_t)ROWOFF[i] * 256;
    float* ci = CC + (size_t)ROWOFF[i] * 256;
    int total4 = R * 64;
    int blocks4 = (total4 + 255) / 256; if (blocks4 > 8192) blocks4 = 8192;

    cpe_kernel<<<blocks4, 256, 0, stream>>>(xin[i], WT + i * 2304, cpe_b + i * 256, xi, N, H, total4);
    ln_kernel<<<(R + 3) / 4, 256, 0, stream>>>(xi, n1_g + i * 256, n1_b + i * 256, T1, R);

    int nmt = (R + 127) / 128;
    const u16* WQi = WQ + (size_t)i * 768 * 256;
    gemm_mfma<false, false><<<nmt * 2, 256, 0, stream>>>(T1, WQi, nullptr, nullptr, T2q, R, 256, 256, 2);
    gemm_mfma<false, true><<<nmt * 4, 256, 0, stream>>>(T1, WQi + 65536, nullptr, nullptr, T2kv, R, 256, 512, 4);

    hipMemsetAsync(VPI, 0, (size_t)2048 * H * 64 * 2, stream);
    tp_kernel<<<dim3((N + 63) / 64, 8, 8), 256, 0, stream>>>(T2kv, KP, VP, VPI, N, H);

    ksm_kernel<<<dim3(64, 8), 256, 0, stream>>>(KP, MX, SE, N);

    int NC = (N + 99) / 100; if (NC > 32) NC = 32; if (NC < 1) NC = 1;
    int chunkrows = (N + NC - 1) / NC;
    kv_partial<<<64 * NC, 1024, 0, stream>>>(KP, VP, MX, PRT, N, chunkrows, NC);
    kv_reduce<<<64, 1024, 0, stream>>>(PRT, SE, KV, NC);

    int RS = (H >= 56) ? 2 : 1;
    crpe_k<3, 0, 64><<<dim3(64, 8, RS), 256, 0, stream>>>(VPI, crpe_w3 + i * 576, crpe_b3 + i * 64, CVPI, H, RS);
    crpe_k<5, 64, 96><<<dim3(96, 8, RS), 256, 0, stream>>>(VPI, crpe_w5 + i * 2400, crpe_b5 + i * 96, CVPI, H, RS);
    crpe_k<7, 160, 96><<<dim3(96, 8, RS), 256, 0, stream>>>(VPI, crpe_w7 + i * 4704, crpe_b7 + i * 96, CVPI, H, RS);

    att_combine<<<dim3((N + 15) / 16, 8), 256, 0, stream>>>(T2q, CVPI, KV, T1, N, H);

    gemm_mfma<false, false><<<nmt * 2, 256, 0, stream>>>(T1, WP + (size_t)i * 65536,
                                                         proj_b + i * 256, nullptr, ci, R, 256, 256, 2);
  }

  // ---- phase 2 ----
  const int SA[4] = {1, 2, 3, 2};
  const int SB[4] = {2, 0, 0, 0};
  for (int i = 0; i < 4; ++i) {
    int N = NS[i], H = HS[i], R = 8 * N, total4 = R * 64;
    int blocks4 = (total4 + 255) / 256; if (blocks4 > 8192) blocks4 = 8192;
    combine_kernel<<<blocks4, 256, 0, stream>>>(
        XI + (size_t)ROWOFF[i] * 256, CC + (size_t)ROWOFF[i] * 256,
        CC + (size_t)ROWOFF[SA[i]] * 256, HS[SA[i]], NS[SA[i]],
        CC + (size_t)ROWOFF[SB[i]] * 256, HS[SB[i]], NS[SB[i]],
        N, H, total4);
  }

  // ---- phase 3 ----
  for (int i = 0; i < 4; ++i) {
    int N = NS[i], R = 8 * N;
    float* xi = XI + (size_t)ROWOFF[i] * 256;
    ln_kernel<<<(R + 3) / 4, 256, 0, stream>>>(xi, n2_g + i * 256, n2_b + i * 256, T1, R);
    float* osec = out + OUTOFF[i];
    int nmt = (R + 127) / 128;
    gemm_mfma<true, true><<<nmt * 8, 256, 0, stream>>>(T1, W1, fc1_b, nullptr, (void*)T2h, R, 256, 1024, 8);
    gemm_mfma<false, false><<<nmt * 2, 256, 0, stream>>>(T2h, W2, fc2_b, xi, osec, R, 1024, 256, 2);
  }
}

// Round 7
// 698.114 us; speedup vs baseline: 3.5007x; 1.1923x over previous
//
#include <hip/hip_runtime.h>
#include <math.h>

typedef unsigned short u16;
typedef __attribute__((ext_vector_type(8))) short bf16x8;
typedef __attribute__((ext_vector_type(4))) float f32x4;

static const int HS[4]     = {56, 28, 14, 7};
static const int NS[4]     = {3137, 785, 197, 50};
static const int ROWOFF[4] = {0, 25096, 31376, 32952};
static const size_t OUTOFF[4] = {25692160ull, 32116736ull, 33724416ull, 34127872ull};
#define NP 3200  // planar token stride
#define RTOT 33352

#define DEV __device__ __forceinline__

DEV u16 f2bf(float x) {
  union { float f; unsigned u; } v; v.f = x;
  unsigned r = v.u + 0x7fffu + ((v.u >> 16) & 1u);
  return (u16)(r >> 16);
}
DEV float bf2f(u16 x) {
  union { unsigned u; float f; } v; v.u = ((unsigned)x) << 16;
  return v.f;
}

struct alignas(8) u16x4s { u16 x, y, z, w; };
struct alignas(16) U16x8 { u16 d[8]; };

// ---------------- weight fp32 -> bf16 ----------------
__global__ void cvt_bf16(const float* __restrict__ src, u16* __restrict__ dst, int n) {
  for (int i = blockIdx.x * blockDim.x + threadIdx.x; i < n; i += gridDim.x * blockDim.x)
    dst[i] = f2bf(src[i]);
}

// ---------------- cpe weights [4][256][9] -> [4][9][256] ----------------
__global__ void tpw_cpe(const float* __restrict__ src, float* __restrict__ dst) {
  int i = blockIdx.y;
  int e = blockIdx.x * 256 + threadIdx.x;
  if (e < 2304) {
    int c = e / 9, k = e % 9;
    dst[i * 2304 + k * 256 + c] = src[i * 2304 + c * 9 + k];
  }
}

// ---------------- x1 passthrough ----------------
__global__ void copy_f4(const float4* __restrict__ src, float4* __restrict__ dst, int n4) {
  for (int i = blockIdx.x * blockDim.x + threadIdx.x; i < n4; i += gridDim.x * blockDim.x)
    dst[i] = src[i];
}

// ---------------- CPE: depthwise 3x3 + bias + residual, float4 channels ----------------
__global__ void cpe_kernel(const float* __restrict__ x, const float* __restrict__ wT,
                           const float* __restrict__ bias, float* __restrict__ out,
                           int N, int H, int total4) {
  int W = H;
  for (int idx = blockIdx.x * blockDim.x + threadIdx.x; idx < total4; idx += gridDim.x * blockDim.x) {
    int c4 = (idx & 63) << 2;
    int row = idx >> 6;
    int n = row % N;
    int b = row / N;
    float4 xv = *(const float4*)(x + (size_t)row * 256 + c4);
    float4 o = xv;
    if (n > 0) {
      int p = n - 1, h0 = p / W, w0 = p % W;
      float4 acc = *(const float4*)(bias + c4);
      #pragma unroll
      for (int kh = 0; kh < 3; ++kh) {
        int hh = h0 + kh - 1;
        if (hh < 0 || hh >= H) continue;
        #pragma unroll
        for (int kw = 0; kw < 3; ++kw) {
          int ww = w0 + kw - 1;
          if (ww < 0 || ww >= W) continue;
          float4 t = *(const float4*)(x + (((size_t)b * N) + 1 + hh * W + ww) * 256 + c4);
          float4 wv = *(const float4*)(wT + (kh * 3 + kw) * 256 + c4);
          acc.x += t.x * wv.x; acc.y += t.y * wv.y;
          acc.z += t.z * wv.z; acc.w += t.w * wv.w;
        }
      }
      o.x += acc.x; o.y += acc.y; o.z += acc.z; o.w += acc.w;
    }
    *(float4*)(out + (size_t)row * 256 + c4) = o;
  }
}

// ---------------- LayerNorm over C=256, bf16 out ----------------
__global__ void ln_kernel(const float* __restrict__ x, const float* __restrict__ g,
                          const float* __restrict__ bt, u16* __restrict__ out, int rows) {
  int wid = threadIdx.x >> 6, lane = threadIdx.x & 63;
  int row = blockIdx.x * 4 + wid;
  if (row >= rows) return;
  const float* xr = x + (size_t)row * 256;
  float4 v = *(const float4*)(xr + lane * 4);
  float s = v.x + v.y + v.z + v.w;
  #pragma unroll
  for (int off = 32; off; off >>= 1) s += __shfl_down(s, off);
  s = __shfl(s, 0);
  float mu = s * (1.0f / 256.0f);
  float dx = v.x - mu, dy = v.y - mu, dz = v.z - mu, dw = v.w - mu;
  float q = dx * dx + dy * dy + dz * dz + dw * dw;
  #pragma unroll
  for (int off = 32; off; off >>= 1) q += __shfl_down(q, off);
  q = __shfl(q, 0);
  float rs = rsqrtf(q * (1.0f / 256.0f) + 1e-5f);
  float4 gg = *(const float4*)(g + lane * 4);
  float4 bb = *(const float4*)(bt + lane * 4);
  u16x4s o;
  o.x = f2bf(dx * rs * gg.x + bb.x);
  o.y = f2bf(dy * rs * gg.y + bb.y);
  o.z = f2bf(dz * rs * gg.z + bb.z);
  o.w = f2bf(dw * rs * gg.w + bb.w);
  *(u16x4s*)(out + (size_t)row * 256 + lane * 4) = o;
}

// ---------------- shared MFMA GEMM core (swizzled staging + dbuf + LDS epilogue) ----------------
DEV void stage_tile(const u16* __restrict__ A, const u16* __restrict__ W,
                    u16* aD, u16* bD, int bm, int bn, int M, int K, int k0) {
  int t = threadIdx.x, wv = t >> 6;
  #pragma unroll
  for (int iss = 0; iss < 4; ++iss) {
    int s = iss * 256 + t;
    int row = s >> 3;
    int gel = ((s & 7) ^ (row & 7)) * 8;
    int gr = bm + row; if (gr > M - 1) gr = M - 1;
    const u16* ga = A + (size_t)gr * K + k0 + gel;
    __builtin_amdgcn_global_load_lds(
        (const __attribute__((address_space(1))) void*)ga,
        (__attribute__((address_space(3))) void*)(aD + (size_t)(iss * 256 + wv * 64) * 8),
        16, 0, 0);
    const u16* gb = W + (size_t)(bn + row) * K + k0 + gel;
    __builtin_amdgcn_global_load_lds(
        (const __attribute__((address_space(1))) void*)gb,
        (__attribute__((address_space(3))) void*)(bD + (size_t)(iss * 256 + wv * 64) * 8),
        16, 0, 0);
  }
}

template <bool GELU, bool OUT_BF16>
DEV void gemm_core(const u16* __restrict__ A, const u16* __restrict__ W,
                   const float* __restrict__ bias, const float* __restrict__ res,
                   void* __restrict__ outp, int M, int K, int Nout,
                   int bm, int bn, float* smem) {
  u16* lds = (u16*)smem;
  int t = threadIdx.x, lane = t & 63, wv = t >> 6;
  int wr = wv >> 1, wc = wv & 1;
  f32x4 acc[4][4] = {};

  const int nt = K >> 6;
  stage_tile(A, W, lds, lds + 8192, bm, bn, M, K, 0);

  for (int tt = 0; tt < nt; ++tt) {
    __syncthreads();
    if (tt + 1 < nt) {
      u16* aD = lds + ((tt + 1) & 1) * 16384;
      stage_tile(A, W, aD, aD + 8192, bm, bn, M, K, (tt + 1) << 6);
    }
    const u16* aS = lds + (tt & 1) * 16384;
    const u16* bS = aS + 8192;
    #pragma unroll
    for (int kk = 0; kk < 2; ++kk) {
      int qa = kk * 4 + (lane >> 4);
      bf16x8 af[4], bfr[4];
      #pragma unroll
      for (int m = 0; m < 4; ++m) {
        int row = wr * 64 + m * 16 + (lane & 15);
        int sg = qa ^ (row & 7);
        af[m] = *(const bf16x8*)(aS + row * 64 + sg * 8);
      }
      #pragma unroll
      for (int n = 0; n < 4; ++n) {
        int row = wc * 64 + n * 16 + (lane & 15);
        int sg = qa ^ (row & 7);
        bfr[n] = *(const bf16x8*)(bS + row * 64 + sg * 8);
      }
      #pragma unroll
      for (int m = 0; m < 4; ++m)
        #pragma unroll
        for (int n = 0; n < 4; ++n)
          acc[m][n] = __builtin_amdgcn_mfma_f32_16x16x32_bf16(af[m], bfr[n], acc[m][n], 0, 0, 0);
    }
  }

  __syncthreads();
  int lrow = wr * 64 + ((lane >> 4) << 2);
  int lcol = wc * 64 + (lane & 15);
  #pragma unroll
  for (int m = 0; m < 4; ++m)
    #pragma unroll
    for (int n = 0; n < 4; ++n)
      #pragma unroll
      for (int rg = 0; rg < 4; ++rg)
        smem[(lrow + m * 16 + rg) * 136 + lcol + n * 16] = acc[m][n][rg];
  __syncthreads();

  int row = t >> 1, c0 = (t & 1) << 6;
  int gr = bm + row;
  if (gr >= M) return;
  int gc = bn + c0;
  const float* srcr = smem + row * 136 + c0;
  #pragma unroll
  for (int j = 0; j < 16; j += 2) {
    float4 a = *(const float4*)(srcr + j * 4);
    float4 b2 = *(const float4*)(srcr + j * 4 + 4);
    float v[8] = {a.x, a.y, a.z, a.w, b2.x, b2.y, b2.z, b2.w};
    if (bias) {
      float4 ba = *(const float4*)(bias + gc + j * 4);
      float4 bb = *(const float4*)(bias + gc + j * 4 + 4);
      v[0] += ba.x; v[1] += ba.y; v[2] += ba.z; v[3] += ba.w;
      v[4] += bb.x; v[5] += bb.y; v[6] += bb.z; v[7] += bb.w;
    }
    if (GELU) {
      #pragma unroll
      for (int e = 0; e < 8; ++e) v[e] = v[e] / (1.0f + __expf(-1.702f * v[e]));
    }
    if (res) {
      const float* rp = res + (size_t)gr * Nout + gc + j * 4;
      float4 ra = *(const float4*)(rp);
      float4 rb = *(const float4*)(rp + 4);
      v[0] += ra.x; v[1] += ra.y; v[2] += ra.z; v[3] += ra.w;
      v[4] += rb.x; v[5] += rb.y; v[6] += rb.z; v[7] += rb.w;
    }
    if (OUT_BF16) {
      U16x8 pk;
      #pragma unroll
      for (int e = 0; e < 8; ++e) pk.d[e] = f2bf(v[e]);
      *(U16x8*)((u16*)outp + (size_t)gr * Nout + gc + j * 4) = pk;
    } else {
      float* op = (float*)outp + (size_t)gr * Nout + gc + j * 4;
      *(float4*)op = make_float4(v[0], v[1], v[2], v[3]);
      *(float4*)(op + 4) = make_float4(v[4], v[5], v[6], v[7]);
    }
  }
}

DEV int xcd_swizzle(int orig, int nblk) {
  int q = nblk >> 3, r = nblk & 7;
  int xcd = orig & 7, lin = orig >> 3;
  return (xcd < r ? xcd * (q + 1) : r * (q + 1) + (xcd - r) * q) + lin;
}

// ---------------- plain single-matrix GEMM ----------------
template <bool GELU, bool OUT_BF16>
__launch_bounds__(256, 2)
__global__ void gemm_mfma(const u16* __restrict__ A, const u16* __restrict__ W,
                          const float* __restrict__ bias, const float* __restrict__ res,
                          void* __restrict__ outp, int M, int K, int Nout, int nnt) {
  __shared__ __align__(16) float smem[128 * 136];
  int wg = xcd_swizzle(blockIdx.x, gridDim.x);
  int bm = (wg / nnt) << 7, bn = (wg % nnt) << 7;
  gemm_core<GELU, OUT_BF16>(A, W, bias, res, outp, M, K, Nout, bm, bn, smem);
}

// ---------------- grouped GEMM over 4 scales ----------------
struct GrpArgs {
  const u16* A[4];
  const u16* W[4];
  const float* bias[4];
  size_t outoff[4];
  int M[4];
  int pref[5];
};

template <bool OUT_BF16>
__launch_bounds__(256, 2)
__global__ void gemm_grp(GrpArgs ga, void* __restrict__ outbase, int K, int Nout, int nnt) {
  __shared__ __align__(16) float smem[128 * 136];
  int wg = xcd_swizzle(blockIdx.x, gridDim.x);
  int i = (wg >= ga.pref[1]) + (wg >= ga.pref[2]) + (wg >= ga.pref[3]);
  int local = wg - ga.pref[i];
  int bm = (local / nnt) << 7, bn = (local % nnt) << 7;
  void* outp = OUT_BF16 ? (void*)((u16*)outbase + ga.outoff[i])
                        : (void*)((float*)outbase + ga.outoff[i]);
  gemm_core<false, OUT_BF16>(ga.A[i], ga.W[i], ga.bias[i], nullptr, outp,
                             ga.M[i], K, Nout, bm, bn, smem);
}

// ---------------- transpose k,v (from T2 [n][768], cols 256..767) -> planar + padded image ----------------
__global__ void tp_kernel(const u16* __restrict__ T2, u16* __restrict__ KP,
                          u16* __restrict__ VP, u16* __restrict__ VPI, int N, int H) {
  __shared__ u16 tl[64][66];
  int nt0 = blockIdx.x * 64, c0 = blockIdx.y * 64, b = blockIdx.z;
  int t = threadIdx.x;
  int W = H;
  for (int e = t; e < 4096; e += 256) {
    int n_l = e >> 6, c_l = e & 63;
    int n = nt0 + n_l;
    tl[n_l][c_l] = (n < N) ? T2[((size_t)b * N + n) * 768 + 256 + c0 + c_l] : (u16)0;
  }
  __syncthreads();
  for (int e = t; e < 4096; e += 256) {
    int c_l = e >> 6, n_l = e & 63;
    int n = nt0 + n_l;
    if (n >= N) continue;
    int cg = c0 + c_l;
    u16 val = tl[n_l][c_l];
    if (cg < 256) {
      KP[((size_t)(b * 256 + cg)) * NP + n] = val;
    } else {
      int cc = cg - 256;
      VP[((size_t)(b * 256 + cc)) * NP + n] = val;
      if (n >= 1) {
        int p = n - 1;
        VPI[(size_t)(b * 256 + cc) * (size_t)(H * 64) + (p / W) * 64 + (p % W)] = val;
      }
    }
  }
}

// ---------------- k softmax stats ----------------
__global__ void ksm_kernel(const u16* __restrict__ KP, float* __restrict__ mx,
                           float* __restrict__ se, int N) {
  int b = blockIdx.y;
  int wv = threadIdx.x >> 6, lane = threadIdx.x & 63;
  int cg = blockIdx.x * 4 + wv;
  const u16* kp = KP + ((size_t)(b * 256 + cg)) * NP;
  float m = -1e30f, s = 0.f;
  for (int n = lane; n < N; n += 64) {
    float v = bf2f(kp[n]);
    float nm = fmaxf(m, v);
    s = s * __expf(m - nm) + __expf(v - nm);
    m = nm;
  }
  #pragma unroll
  for (int off = 1; off < 64; off <<= 1) {
    float mo = __shfl_xor(m, off), so = __shfl_xor(s, off);
    float nm = fmaxf(m, mo);
    s = s * __expf(m - nm) + so * __expf(mo - nm);
    m = nm;
  }
  if (lane == 0) { mx[b * 256 + cg] = m; se[b * 256 + cg] = s; }
}

// ---------------- kv partials from planar ----------------
__launch_bounds__(1024)
__global__ void kv_partial(const u16* __restrict__ KP, const u16* __restrict__ VP,
                           const float* __restrict__ mx, float* __restrict__ part,
                           int N, int chunkrows, int NC) {
  __shared__ float kl[32][65];
  __shared__ float vl[32][65];
  int blk = blockIdx.x;
  int chunk = blk % NC;
  int bh = blk / NC;
  int b = bh >> 3, h = bh & 7;
  int t = threadIdx.x;
  int i = t >> 5, j = t & 31;
  float acc = 0.f;
  int n0s = chunk * chunkrows, n1s = min(N, n0s + chunkrows);
  for (int n0 = n0s; n0 < n1s; n0 += 64) {
    #pragma unroll
    for (int e = t; e < 2048; e += 1024) {
      int c = e >> 6, nn = e & 63;
      int n = n0 + nn;
      bool ok = (n < n1s);
      kl[c][nn] = ok ? bf2f(KP[((size_t)(b * 256 + h * 32 + c)) * NP + n]) : -1e30f;
      vl[c][nn] = ok ? bf2f(VP[((size_t)(b * 256 + h * 32 + c)) * NP + n]) : 0.f;
    }
    __syncthreads();
    #pragma unroll
    for (int e = t; e < 2048; e += 1024) {
      int c = e >> 6, nn = e & 63;
      kl[c][nn] = __expf(kl[c][nn] - mx[b * 256 + h * 32 + c]);
    }
    __syncthreads();
    #pragma unroll
    for (int nn = 0; nn < 64; ++nn) acc += kl[i][nn] * vl[j][nn];
    __syncthreads();
  }
  part[((size_t)bh * NC + chunk) * 1024 + t] = acc;
}

__global__ void kv_reduce(const float* __restrict__ part, const float* __restrict__ se,
                          float* __restrict__ kv, int NC) {
  int bh = blockIdx.x;
  int t = threadIdx.x;
  int i = t >> 5;
  int b = bh >> 3, h = bh & 7;
  float s = 0.f;
  for (int c = 0; c < NC; ++c) s += part[((size_t)bh * NC + c) * 1024 + t];
  kv[(size_t)bh * 1024 + t] = s / se[b * 256 + h * 32 + i];
}

// ---------------- CRPE depthwise conv on padded planes: 8 outputs/thread ----------------
template <int KS, int C0, int CS>
__global__ void crpe_k(const u16* __restrict__ VPI, const float* __restrict__ w,
                       const float* __restrict__ bias, u16* __restrict__ CVPI,
                       int H, int RS) {
  constexpr int pad = KS / 2;
  int c = blockIdx.x, b = blockIdx.y, z = blockIdx.z;
  int G = (H + 7) >> 3;
  int hpb = (H + RS - 1) / RS;
  int h0b = z * hpb;
  int h1b = min(H, h0b + hpb);
  size_t plane = (size_t)(b * 256 + C0 + c) * (size_t)(H * 64);
  const u16* vp = VPI + plane;
  u16* op = CVPI + plane;
  float wreg[KS * KS];
  #pragma unroll
  for (int e = 0; e < KS * KS; ++e) wreg[e] = w[c * KS * KS + e];
  float bb = bias[c];
  int ntask = (h1b - h0b) * G;
  for (int task = threadIdx.x; task < ntask; task += 256) {
    int g = task % G;
    int h = h0b + task / G;
    int w0 = g << 3;
    float o[8];
    #pragma unroll
    for (int e = 0; e < 8; ++e) o[e] = bb;
    #pragma unroll
    for (int kh = 0; kh < KS; ++kh) {
      int hh = h + kh - pad;
      if (hh < 0 || hh >= H) continue;
      const u16* rowp = vp + hh * 64;
      U16x8 ch0 = {}, ch1, ch2;
      if (w0 >= 8) ch0 = *(const U16x8*)(rowp + w0 - 8);
      ch1 = *(const U16x8*)(rowp + w0);
      ch2 = *(const U16x8*)(rowp + w0 + 8);
      float tv[24];
      #pragma unroll
      for (int j = 8 - pad; j <= 15 + pad; ++j) {
        u16 raw = (j < 8) ? ch0.d[j] : (j < 16 ? ch1.d[j - 8] : ch2.d[j - 16]);
        tv[j] = bf2f(raw);
      }
      #pragma unroll
      for (int kw = 0; kw < KS; ++kw) {
        float wv = wreg[kh * KS + kw];
        #pragma unroll
        for (int e = 0; e < 8; ++e) o[e] += tv[8 + e + kw - pad] * wv;
      }
    }
    U16x8 pk;
    #pragma unroll
    for (int e = 0; e < 8; ++e) pk.d[e] = f2bf(o[e]);
    *(U16x8*)(op + h * 64 + w0) = pk;
  }
}

// ---------------- att: attp = CH^-0.5 * (q @ kv) + q * conv_v (bf16 out) ----------------
__global__ void att_combine(const u16* __restrict__ T2, const u16* __restrict__ CVPI,
                            const float* __restrict__ kvg, u16* __restrict__ attp,
                            int N, int H) {
  __shared__ float kvl[8192];
  __shared__ float ql[256];
  __shared__ float cl[16][260];
  int b = blockIdx.y;
  int n0 = blockIdx.x * 16;
  int t = threadIdx.x;
  int HW64 = H * 64;
  for (int e = t; e < 8192; e += 256) kvl[e] = kvg[(size_t)b * 8192 + e];
  for (int e = t; e < 4096; e += 256) {
    int c = e >> 4, nn = e & 15;
    int n = n0 + nn;
    float v = 0.f;
    if (n >= 1 && n < N) {
      int p = n - 1;
      v = bf2f(CVPI[(size_t)(b * 256 + c) * HW64 + (p / H) * 64 + (p % H)]);
    }
    cl[nn][c] = v;
  }
  int h = t >> 5, j = t & 31;
  for (int nn = 0; nn < 16; ++nn) {
    int n = n0 + nn;
    if (n >= N) break;
    __syncthreads();
    ql[t] = bf2f(T2[((size_t)(b * N + n)) * 768 + t]);
    __syncthreads();
    float fa = 0.f;
    const float* kvh = kvl + h * 1024;
    #pragma unroll
    for (int k = 0; k < 32; ++k) fa += ql[h * 32 + k] * kvh[k * 32 + j];
    float v = 0.17677669529663687f * fa + ql[t] * cl[nn][t];
    attp[(((size_t)b * N) + n) * 256 + t] = f2bf(v);
  }
}

// ---------------- cross-scale bilinear combine, float4 channels ----------------
DEV float4 bsample4(const float* __restrict__ src, int b, int Ns, int Hs,
                    int oh, int ow, int Hi, int c4) {
  float scale = (float)Hs / (float)Hi;
  float sy = (oh + 0.5f) * scale - 0.5f;
  float sx = (ow + 0.5f) * scale - 0.5f;
  float fy0 = floorf(sy), fx0 = floorf(sx);
  float fy = sy - fy0, fx = sx - fx0;
  int y0 = (int)fy0, x0 = (int)fx0;
  int y0c = min(max(y0, 0), Hs - 1), y1c = min(max(y0 + 1, 0), Hs - 1);
  int x0c = min(max(x0, 0), Hs - 1), x1c = min(max(x0 + 1, 0), Hs - 1);
  const float* base = src + ((size_t)b * Ns + 1) * 256 + c4;
  float4 v00 = *(const float4*)(base + (size_t)(y0c * Hs + x0c) * 256);
  float4 v01 = *(const float4*)(base + (size_t)(y0c * Hs + x1c) * 256);
  float4 v10 = *(const float4*)(base + (size_t)(y1c * Hs + x0c) * 256);
  float4 v11 = *(const float4*)(base + (size_t)(y1c * Hs + x1c) * 256);
  float w00 = (1.f - fy) * (1.f - fx), w01 = (1.f - fy) * fx;
  float w10 = fy * (1.f - fx), w11 = fy * fx;
  float4 r;
  r.x = w00 * v00.x + w01 * v01.x + w10 * v10.x + w11 * v11.x;
  r.y = w00 * v00.y + w01 * v01.y + w10 * v10.y + w11 * v11.y;
  r.z = w00 * v00.z + w01 * v01.z + w10 * v10.z + w11 * v11.z;
  r.w = w00 * v00.w + w01 * v01.w + w10 * v10.w + w11 * v11.w;
  return r;
}

__global__ void combine_kernel(float* __restrict__ xi, const float* __restrict__ ci,
                               const float* __restrict__ srcA, int HsA, int NsA,
                               const float* __restrict__ srcB, int HsB, int NsB,
                               int Ni, int Hi, int total4) {
  for (int idx = blockIdx.x * blockDim.x + threadIdx.x; idx < total4; idx += gridDim.x * blockDim.x) {
    int c4 = (idx & 63) << 2;
    int row = idx >> 6;
    int n = row % Ni;
    int b = row / Ni;
    float4 add = *(const float4*)(ci + (size_t)row * 256 + c4);
    if (n == 0) {
      float4 a = *(const float4*)(srcA + ((size_t)b * NsA) * 256 + c4);
      float4 bb = *(const float4*)(srcB + ((size_t)b * NsB) * 256 + c4);
      add.x += a.x + bb.x; add.y += a.y + bb.y;
      add.z += a.z + bb.z; add.w += a.w + bb.w;
    } else {
      int p = n - 1, oh = p / Hi, ow = p % Hi;
      float4 a = bsample4(srcA, b, NsA, HsA, oh, ow, Hi, c4);
      float4 bb = bsample4(srcB, b, NsB, HsB, oh, ow, Hi, c4);
      add.x += a.x + bb.x; add.y += a.y + bb.y;
      add.z += a.z + bb.z; add.w += a.w + bb.w;
    }
    float* xp = xi + (size_t)row * 256 + c4;
    float4 cur = *(const float4*)xp;
    cur.x += add.x; cur.y += add.y; cur.z += add.z; cur.w += add.w;
    *(float4*)xp = cur;
  }
}

// ---------------- host ----------------
extern "C" void kernel_launch(void* const* d_in, const int* in_sizes, int n_in,
                              void* d_out, int out_size, void* d_ws, size_t ws_size,
                              hipStream_t stream) {
  const float* x1 = (const float*)d_in[0];
  const float* xin[4] = {(const float*)d_in[1], (const float*)d_in[2],
                         (const float*)d_in[3], (const float*)d_in[4]};
  const float* cpe_w  = (const float*)d_in[5];
  const float* cpe_b  = (const float*)d_in[6];
  const float* n1_g   = (const float*)d_in[7];
  const float* n1_b   = (const float*)d_in[8];
  const float* qkv_w  = (const float*)d_in[9];
  const float* proj_w = (const float*)d_in[10];
  const float* proj_b = (const float*)d_in[11];
  const float* crpe_w3 = (const float*)d_in[12];
  const float* crpe_b3 = (const float*)d_in[13];
  const float* crpe_w5 = (const float*)d_in[14];
  const float* crpe_b5 = (const float*)d_in[15];
  const float* crpe_w7 = (const float*)d_in[16];
  const float* crpe_b7 = (const float*)d_in[17];
  const float* n2_g   = (const float*)d_in[18];
  const float* n2_b   = (const float*)d_in[19];
  const float* fc1_w  = (const float*)d_in[20];
  const float* fc1_b  = (const float*)d_in[21];
  const float* fc2_w  = (const float*)d_in[22];
  const float* fc2_b  = (const float*)d_in[23];

  float* ws = (float*)d_ws;
  float* XI   = ws;                        // 8,538,112 f32
  float* CC   = XI + 8538112;              // 8,538,112 f32
  u16*   T1   = (u16*)(CC + 8538112);      // bf16 [RTOT][256] -> 4,269,056 f32
  float* T2f  = (float*)(T1 + (size_t)RTOT * 256);  // T2 region start
  u16*   T2   = (u16*)T2f;                 // bf16 [RTOT][768] (phase1) / [RTOT][1024] (phase3) -> 17,076,224 f32
  u16*   KP   = (u16*)(T2f + 17076224);    // bf16 planar 3,276,800 f32
  u16*   VP   = KP + 6553600;              // 3,276,800 f32
  u16*   VPI  = VP + 6553600;              // 3,670,016 f32
  u16*   CVPI = VPI + 7340032;             // 3,670,016 f32 (overlay: kv partials f32)
  float* PRT  = (float*)CVPI;
  float* MX   = (float*)(CVPI + 7340032);  // 2,048
  float* SE   = MX + 2048;                 // 2,048
  float* KV   = SE + 2048;                 // 65,536
  u16*   WQ   = (u16*)(KV + 65536);        // 786,432 u16
  u16*   WP   = WQ + 786432;               // 262,144 u16
  u16*   W1   = WP + 262144;
  u16*   W2   = W1 + 262144;
  float* WT   = (float*)(W2 + 262144);     // 9,216 f32

  float* out = (float*)d_out;

  cvt_bf16<<<1536, 256, 0, stream>>>(qkv_w, WQ, 786432);
  cvt_bf16<<<512, 256, 0, stream>>>(proj_w, WP, 262144);
  cvt_bf16<<<512, 256, 0, stream>>>(fc1_w, W1, 262144);
  cvt_bf16<<<512, 256, 0, stream>>>(fc2_w, W2, 262144);
  tpw_cpe<<<dim3(9, 4), 256, 0, stream>>>(cpe_w, WT);

  copy_f4<<<8192, 256, 0, stream>>>((const float4*)x1, (float4*)out, 25692160 / 4);

  // tiles per scale
  int nmt[4], prefQ[5], prefP[5];
  prefQ[0] = prefP[0] = 0;
  for (int i = 0; i < 4; ++i) {
    nmt[i] = (8 * NS[i] + 127) / 128;
    prefQ[i + 1] = prefQ[i] + nmt[i] * 6;
    prefP[i + 1] = prefP[i] + nmt[i] * 2;
  }

  // ---- phase 1a: CPE + LN1 (all scales) ----
  for (int i = 0; i < 4; ++i) {
    int H = HS[i], N = NS[i], R = 8 * N;
    float* xi = XI + (size_t)ROWOFF[i] * 256;
    int total4 = R * 64;
    int blocks4 = (total4 + 255) / 256; if (blocks4 > 8192) blocks4 = 8192;
    cpe_kernel<<<blocks4, 256, 0, stream>>>(xin[i], WT + i * 2304, cpe_b + i * 256, xi, N, H, total4);
    ln_kernel<<<(R + 3) / 4, 256, 0, stream>>>(xi, n1_g + i * 256, n1_b + i * 256,
                                               T1 + (size_t)ROWOFF[i] * 256, R);
  }

  // ---- phase 1b: grouped qkv GEMM (bf16 out [R][768]) ----
  {
    GrpArgs ga;
    for (int i = 0; i < 4; ++i) {
      ga.A[i] = T1 + (size_t)ROWOFF[i] * 256;
      ga.W[i] = WQ + (size_t)i * 196608;
      ga.bias[i] = nullptr;
      ga.outoff[i] = (size_t)ROWOFF[i] * 768;
      ga.M[i] = 8 * NS[i];
    }
    for (int e = 0; e < 5; ++e) ga.pref[e] = prefQ[e];
    gemm_grp<true><<<prefQ[4], 256, 0, stream>>>(ga, T2, 256, 768, 6);
  }

  // ---- phase 1c: per-scale attention mid section ----
  for (int i = 0; i < 4; ++i) {
    int H = HS[i], N = NS[i];
    const u16* T2i = T2 + (size_t)ROWOFF[i] * 768;

    hipMemsetAsync(VPI, 0, (size_t)2048 * H * 64 * 2, stream);
    tp_kernel<<<dim3((N + 63) / 64, 8, 8), 256, 0, stream>>>(T2i, KP, VP, VPI, N, H);

    ksm_kernel<<<dim3(64, 8), 256, 0, stream>>>(KP, MX, SE, N);

    int NC = (N + 99) / 100; if (NC > 32) NC = 32; if (NC < 1) NC = 1;
    int chunkrows = (N + NC - 1) / NC;
    kv_partial<<<64 * NC, 1024, 0, stream>>>(KP, VP, MX, PRT, N, chunkrows, NC);
    kv_reduce<<<64, 1024, 0, stream>>>(PRT, SE, KV, NC);

    int RS = (H >= 56) ? 2 : 1;
    crpe_k<3, 0, 64><<<dim3(64, 8, RS), 256, 0, stream>>>(VPI, crpe_w3 + i * 576, crpe_b3 + i * 64, CVPI, H, RS);
    crpe_k<5, 64, 96><<<dim3(96, 8, RS), 256, 0, stream>>>(VPI, crpe_w5 + i * 2400, crpe_b5 + i * 96, CVPI, H, RS);
    crpe_k<7, 160, 96><<<dim3(96, 8, RS), 256, 0, stream>>>(VPI, crpe_w7 + i * 4704, crpe_b7 + i * 96, CVPI, H, RS);

    att_combine<<<dim3((N + 15) / 16, 8), 256, 0, stream>>>(T2i, CVPI, KV,
                                                            T1 + (size_t)ROWOFF[i] * 256, N, H);
  }

  // ---- phase 1d: grouped proj GEMM (f32 out into CC) ----
  {
    GrpArgs ga;
    for (int i = 0; i < 4; ++i) {
      ga.A[i] = T1 + (size_t)ROWOFF[i] * 256;
      ga.W[i] = WP + (size_t)i * 65536;
      ga.bias[i] = proj_b + i * 256;
      ga.outoff[i] = (size_t)ROWOFF[i] * 256;
      ga.M[i] = 8 * NS[i];
    }
    for (int e = 0; e < 5; ++e) ga.pref[e] = prefP[e];
    gemm_grp<false><<<prefP[4], 256, 0, stream>>>(ga, CC, 256, 256, 2);
  }

  // ---- phase 2: cross-scale bilinear combine ----
  const int SA[4] = {1, 2, 3, 2};
  const int SB[4] = {2, 0, 0, 0};
  for (int i = 0; i < 4; ++i) {
    int N = NS[i], H = HS[i], R = 8 * N, total4 = R * 64;
    int blocks4 = (total4 + 255) / 256; if (blocks4 > 8192) blocks4 = 8192;
    combine_kernel<<<blocks4, 256, 0, stream>>>(
        XI + (size_t)ROWOFF[i] * 256, CC + (size_t)ROWOFF[i] * 256,
        CC + (size_t)ROWOFF[SA[i]] * 256, HS[SA[i]], NS[SA[i]],
        CC + (size_t)ROWOFF[SB[i]] * 256, HS[SB[i]], NS[SB[i]],
        N, H, total4);
  }

  // ---- phase 3: LN2 (per scale) + fused MLP across scales ----
  for (int i = 0; i < 4; ++i) {
    int R = 8 * NS[i];
    ln_kernel<<<(R + 3) / 4, 256, 0, stream>>>(XI + (size_t)ROWOFF[i] * 256,
                                               n2_g + i * 256, n2_b + i * 256,
                                               T1 + (size_t)ROWOFF[i] * 256, R);
  }
  int nmtT = (RTOT + 127) / 128;
  gemm_mfma<true, true><<<nmtT * 8, 256, 0, stream>>>(T1, W1, fc1_b, nullptr, (void*)T2,
                                                      RTOT, 256, 1024, 8);
  gemm_mfma<false, false><<<nmtT * 2, 256, 0, stream>>>(T2, W2, fc2_b, XI, out + OUTOFF[0],
                                                        RTOT, 1024, 256, 2);
}

// Round 8
// 520.403 us; speedup vs baseline: 4.6962x; 1.3415x over previous
//
#include <hip/hip_runtime.h>
#include <math.h>

typedef unsigned short u16;
typedef __attribute__((ext_vector_type(8))) short bf16x8;
typedef __attribute__((ext_vector_type(4))) float f32x4;

static const int HS[4]     = {56, 28, 14, 7};
static const int NS[4]     = {3137, 785, 197, 50};
static const int ROWOFF[4] = {0, 25096, 31376, 32952};
static const size_t OUTOFF0 = 25692160ull;
#define RTOT 33352

#define DEV __device__ __forceinline__
#define AS1 __attribute__((address_space(1)))
#define AS3 __attribute__((address_space(3)))

DEV u16 f2bf(float x) {
  union { float f; unsigned u; } v; v.f = x;
  unsigned r = v.u + 0x7fffu + ((v.u >> 16) & 1u);
  return (u16)(r >> 16);
}
DEV float bf2f(u16 x) {
  union { unsigned u; float f; } v; v.u = ((unsigned)x) << 16;
  return v.f;
}

struct alignas(8) u16x4s { u16 x, y, z, w; };
struct alignas(16) U16x8 { u16 d[8]; };

// scale constant selectors (avoid runtime-indexed arrays -> scratch)
DEV int selNS(int s)  { return s == 0 ? 3137 : s == 1 ? 785 : s == 2 ? 197 : 50; }
DEV int selHS(int s)  { return s == 0 ? 56 : s == 1 ? 28 : s == 2 ? 14 : 7; }
DEV int selROW(int s) { return s == 0 ? 0 : s == 1 ? 25096 : s == 2 ? 31376 : 32952; }
DEV int selNPS(int s) { return s == 0 ? 3200 : s == 1 ? 832 : s == 2 ? 256 : 64; }
DEV size_t selKPB(int s) { return s == 0 ? 0ull : s == 1 ? 6553600ull : s == 2 ? 8257536ull : 8781824ull; }
DEV size_t selVPB(int s) { return s == 0 ? 0ull : s == 1 ? 7340032ull : s == 2 ? 11010048ull : 12845056ull; }
DEV int selNC(int s)  { return s == 0 ? 32 : s == 1 ? 8 : s == 2 ? 2 : 1; }
DEV int selNCB(int s) { return s == 0 ? 0 : s == 1 ? 2048 : s == 2 ? 2560 : 2688; }
DEV int row2scale(int row) { return (row >= 25096) + (row >= 31376) + (row >= 32952); }

// ---------------- weight fp32 -> bf16 ----------------
__global__ void cvt_bf16(const float* __restrict__ src, u16* __restrict__ dst, int n) {
  for (int i = blockIdx.x * blockDim.x + threadIdx.x; i < n; i += gridDim.x * blockDim.x)
    dst[i] = f2bf(src[i]);
}

// ---------------- cpe weights [4][256][9] -> [4][9][256] ----------------
__global__ void tpw_cpe(const float* __restrict__ src, float* __restrict__ dst) {
  int i = blockIdx.y;
  int e = blockIdx.x * 256 + threadIdx.x;
  if (e < 2304) {
    int c = e / 9, k = e % 9;
    dst[i * 2304 + k * 256 + c] = src[i * 2304 + c * 9 + k];
  }
}

// ---------------- x1 passthrough ----------------
__global__ void copy_f4(const float4* __restrict__ src, float4* __restrict__ dst, int n4) {
  for (int i = blockIdx.x * blockDim.x + threadIdx.x; i < n4; i += gridDim.x * blockDim.x)
    dst[i] = src[i];
}

// ---------------- CPE all scales: depthwise 3x3 + bias + residual ----------------
__global__ void cpe_all(const float* __restrict__ x2, const float* __restrict__ x3,
                        const float* __restrict__ x4, const float* __restrict__ x5,
                        const float* __restrict__ WT, const float* __restrict__ bias,
                        float* __restrict__ out, int total4) {
  for (int idx = blockIdx.x * blockDim.x + threadIdx.x; idx < total4; idx += gridDim.x * blockDim.x) {
    int c4 = (idx & 63) << 2;
    int grow = idx >> 6;
    int s = row2scale(grow);
    int lrow = grow - selROW(s);
    int N = selNS(s), H = selHS(s);
    const float* x = s == 0 ? x2 : s == 1 ? x3 : s == 2 ? x4 : x5;
    int n = lrow % N;
    int b = lrow / N;
    float4 xv = *(const float4*)(x + (size_t)lrow * 256 + c4);
    float4 o = xv;
    if (n > 0) {
      int p = n - 1, h0 = p / H, w0 = p % H;
      float4 acc = *(const float4*)(bias + s * 256 + c4);
      const float* wT = WT + s * 2304;
      #pragma unroll
      for (int kh = 0; kh < 3; ++kh) {
        int hh = h0 + kh - 1;
        if (hh < 0 || hh >= H) continue;
        #pragma unroll
        for (int kw = 0; kw < 3; ++kw) {
          int ww = w0 + kw - 1;
          if (ww < 0 || ww >= H) continue;
          float4 t = *(const float4*)(x + (((size_t)b * N) + 1 + hh * H + ww) * 256 + c4);
          float4 wv = *(const float4*)(wT + (kh * 3 + kw) * 256 + c4);
          acc.x += t.x * wv.x; acc.y += t.y * wv.y;
          acc.z += t.z * wv.z; acc.w += t.w * wv.w;
        }
      }
      o.x += acc.x; o.y += acc.y; o.z += acc.z; o.w += acc.w;
    }
    *(float4*)(out + (size_t)grow * 256 + c4) = o;
  }
}

// ---------------- LayerNorm all scales, bf16 out ----------------
__global__ void ln_all(const float* __restrict__ x, const float* __restrict__ g,
                       const float* __restrict__ bt, u16* __restrict__ out, int rows) {
  int wid = threadIdx.x >> 6, lane = threadIdx.x & 63;
  int row = blockIdx.x * 4 + wid;
  if (row >= rows) return;
  int s = row2scale(row);
  const float* xr = x + (size_t)row * 256;
  float4 v = *(const float4*)(xr + lane * 4);
  float sm = v.x + v.y + v.z + v.w;
  #pragma unroll
  for (int off = 32; off; off >>= 1) sm += __shfl_down(sm, off);
  sm = __shfl(sm, 0);
  float mu = sm * (1.0f / 256.0f);
  float dx = v.x - mu, dy = v.y - mu, dz = v.z - mu, dw = v.w - mu;
  float q = dx * dx + dy * dy + dz * dz + dw * dw;
  #pragma unroll
  for (int off = 32; off; off >>= 1) q += __shfl_down(q, off);
  q = __shfl(q, 0);
  float rs = rsqrtf(q * (1.0f / 256.0f) + 1e-5f);
  float4 gg = *(const float4*)(g + s * 256 + lane * 4);
  float4 bb = *(const float4*)(bt + s * 256 + lane * 4);
  u16x4s o;
  o.x = f2bf(dx * rs * gg.x + bb.x);
  o.y = f2bf(dy * rs * gg.y + bb.y);
  o.z = f2bf(dz * rs * gg.z + bb.z);
  o.w = f2bf(dw * rs * gg.w + bb.w);
  *(u16x4s*)(out + (size_t)row * 256 + lane * 4) = o;
}

// ---------------- MFMA GEMM core: BK=32, 32KB LDS dbuf, swizzled epilogue ----------------
DEV void stage32(const u16* __restrict__ A, const u16* __restrict__ W,
                 u16* dst, int bm, int bn, int M, int K, int k0) {
  int t = threadIdx.x, wv = t >> 6;
  u16* aD = dst;
  u16* bD = dst + 4096;
  #pragma unroll
  for (int iss = 0; iss < 2; ++iss) {
    int s = iss * 256 + t;
    int row = s >> 2, g = s & 3;
    int gel = ((g ^ (row & 3)) << 3);
    int gr = bm + row; if (gr > M - 1) gr = M - 1;
    __builtin_amdgcn_global_load_lds(
        (const AS1 void*)(A + (size_t)gr * K + k0 + gel),
        (AS3 void*)(aD + (size_t)(iss * 256 + wv * 64) * 8), 16, 0, 0);
    __builtin_amdgcn_global_load_lds(
        (const AS1 void*)(W + (size_t)(bn + row) * K + k0 + gel),
        (AS3 void*)(bD + (size_t)(iss * 256 + wv * 64) * 8), 16, 0, 0);
  }
}

template <bool GELU, bool OUT_BF16>
DEV void gemm_core(const u16* __restrict__ A, const u16* __restrict__ W,
                   const float* __restrict__ bias, const float* __restrict__ res,
                   void* __restrict__ outp, int M, int K, int Nout,
                   int bm, int bn, u16* lds) {
  int t = threadIdx.x, lane = t & 63, wv = t >> 6;
  int wr = wv >> 1, wc = wv & 1;
  f32x4 acc[4][4] = {};

  const int nt = K >> 5;
  stage32(A, W, lds, bm, bn, M, K, 0);

  for (int tt = 0; tt < nt; ++tt) {
    __syncthreads();
    if (tt + 1 < nt) stage32(A, W, lds + ((tt + 1) & 1) * 8192, bm, bn, M, K, (tt + 1) << 5);
    const u16* aS = lds + (tt & 1) * 8192;
    const u16* bS = aS + 4096;
    bf16x8 af[4], bfr[4];
    #pragma unroll
    for (int m = 0; m < 4; ++m) {
      int row = wr * 64 + m * 16 + (lane & 15);
      int sg = (lane >> 4) ^ (row & 3);
      af[m] = *(const bf16x8*)(aS + row * 32 + sg * 8);
    }
    #pragma unroll
    for (int n = 0; n < 4; ++n) {
      int row = wc * 64 + n * 16 + (lane & 15);
      int sg = (lane >> 4) ^ (row & 3);
      bfr[n] = *(const bf16x8*)(bS + row * 32 + sg * 8);
    }
    #pragma unroll
    for (int m = 0; m < 4; ++m)
      #pragma unroll
      for (int n = 0; n < 4; ++n)
        acc[m][n] = __builtin_amdgcn_mfma_f32_16x16x32_bf16(af[m], bfr[n], acc[m][n], 0, 0, 0);
  }

  // epilogue: 4 passes of 32 rows through the (now free) staging LDS, col4^row swizzle
  float* eps = (float*)lds;
  #pragma unroll
  for (int pass = 0; pass < 4; ++pass) {
    __syncthreads();
    if (wr == (pass >> 1)) {
      #pragma unroll
      for (int mh = 0; mh < 2; ++mh) {
        int m = (pass & 1) * 2 + mh;
        #pragma unroll
        for (int n = 0; n < 4; ++n) {
          int col = wc * 64 + n * 16 + (lane & 15);
          #pragma unroll
          for (int rg = 0; rg < 4; ++rg) {
            int lr = mh * 16 + ((lane >> 4) << 2) + rg;
            eps[lr * 136 + (((col >> 2) ^ lr) << 2) + (col & 3)] = acc[m][n][rg];
          }
        }
      }
    }
    __syncthreads();
    int lr = t >> 3, c0 = (t & 7) << 4;
    int gr = bm + pass * 32 + lr;
    if (gr >= M) continue;
    int gc = bn + c0;
    float vv[16];
    #pragma unroll
    for (int j = 0; j < 4; ++j) {
      int col = c0 + j * 4;
      float4 f = *(const float4*)(eps + lr * 136 + (((col >> 2) ^ lr) << 2));
      vv[j * 4 + 0] = f.x; vv[j * 4 + 1] = f.y; vv[j * 4 + 2] = f.z; vv[j * 4 + 3] = f.w;
    }
    if (bias) {
      #pragma unroll
      for (int j = 0; j < 4; ++j) {
        float4 bv = *(const float4*)(bias + gc + j * 4);
        vv[j * 4 + 0] += bv.x; vv[j * 4 + 1] += bv.y; vv[j * 4 + 2] += bv.z; vv[j * 4 + 3] += bv.w;
      }
    }
    if (GELU) {
      #pragma unroll
      for (int e = 0; e < 16; ++e) vv[e] = vv[e] / (1.0f + __expf(-1.702f * vv[e]));
    }
    if (res) {
      const float* rp = res + (size_t)gr * Nout + gc;
      #pragma unroll
      for (int j = 0; j < 4; ++j) {
        float4 rv = *(const float4*)(rp + j * 4);
        vv[j * 4 + 0] += rv.x; vv[j * 4 + 1] += rv.y; vv[j * 4 + 2] += rv.z; vv[j * 4 + 3] += rv.w;
      }
    }
    if (OUT_BF16) {
      u16* op = (u16*)outp + (size_t)gr * Nout + gc;
      U16x8 p0, p1;
      #pragma unroll
      for (int e = 0; e < 8; ++e) { p0.d[e] = f2bf(vv[e]); p1.d[e] = f2bf(vv[8 + e]); }
      *(U16x8*)op = p0;
      *(U16x8*)(op + 8) = p1;
    } else {
      float* op = (float*)outp + (size_t)gr * Nout + gc;
      #pragma unroll
      for (int j = 0; j < 4; ++j)
        *(float4*)(op + j * 4) = make_float4(vv[j * 4], vv[j * 4 + 1], vv[j * 4 + 2], vv[j * 4 + 3]);
    }
  }
}

DEV int xcd_swizzle(int orig, int nblk) {
  int q = nblk >> 3, r = nblk & 7;
  int xcd = orig & 7, lin = orig >> 3;
  return (xcd < r ? xcd * (q + 1) : r * (q + 1) + (xcd - r) * q) + lin;
}

template <bool GELU, bool OUT_BF16>
__launch_bounds__(256, 4)
__global__ void gemm_mfma(const u16* __restrict__ A, const u16* __restrict__ W,
                          const float* __restrict__ bias, const float* __restrict__ res,
                          void* __restrict__ outp, int M, int K, int Nout, int nnt) {
  __shared__ __align__(16) u16 lds[16384];
  int wg = xcd_swizzle(blockIdx.x, gridDim.x);
  int bm = (wg / nnt) << 7, bn = (wg % nnt) << 7;
  gemm_core<GELU, OUT_BF16>(A, W, bias, res, outp, M, K, Nout, bm, bn, lds);
}

struct GrpArgs {
  const u16* A[4];
  const u16* W[4];
  const float* bias[4];
  size_t outoff[4];
  int M[4];
  int pref[5];
};

template <bool OUT_BF16>
__launch_bounds__(256, 4)
__global__ void gemm_grp(GrpArgs ga, void* __restrict__ outbase, int K, int Nout, int nnt) {
  __shared__ __align__(16) u16 lds[16384];
  int wg = xcd_swizzle(blockIdx.x, gridDim.x);
  int i = (wg >= ga.pref[1]) + (wg >= ga.pref[2]) + (wg >= ga.pref[3]);
  int local = wg - ga.pref[i];
  int bm = (local / nnt) << 7, bn = (local % nnt) << 7;
  void* outp = OUT_BF16 ? (void*)((u16*)outbase + ga.outoff[i])
                        : (void*)((float*)outbase + ga.outoff[i]);
  gemm_core<false, OUT_BF16>(ga.A[i], ga.W[i], ga.bias[i], nullptr, outp,
                             ga.M[i], K, Nout, bm, bn, lds);
}

// ---------------- transpose k,v (all scales) -> planar + padded v image ----------------
__global__ void tp_all(const u16* __restrict__ T2, u16* __restrict__ KP,
                       u16* __restrict__ VP, u16* __restrict__ VPI) {
  int z = blockIdx.z, s = z >> 3, b = z & 7;
  int N = selNS(s), H = selHS(s);
  int nt0 = blockIdx.x * 64;
  if (nt0 >= N) return;
  int NPs = selNPS(s);
  int hw64 = H * 64;
  const u16* T2i = T2 + (size_t)selROW(s) * 768;
  u16* kpb = KP + selKPB(s);
  u16* vpb = VP + selKPB(s);
  u16* vib = VPI + selVPB(s);
  __shared__ u16 tl[64][66];
  int c0 = blockIdx.y * 64, t = threadIdx.x;
  for (int e = t; e < 4096; e += 256) {
    int n_l = e >> 6, c_l = e & 63;
    int n = nt0 + n_l;
    tl[n_l][c_l] = (n < N) ? T2i[((size_t)b * N + n) * 768 + 256 + c0 + c_l] : (u16)0;
  }
  __syncthreads();
  for (int e = t; e < 4096; e += 256) {
    int c_l = e >> 6, n_l = e & 63;
    int n = nt0 + n_l;
    if (n >= N) continue;
    int cg = c0 + c_l;
    u16 val = tl[n_l][c_l];
    if (cg < 256) {
      kpb[(size_t)(b * 256 + cg) * NPs + n] = val;
    } else {
      int cc = cg - 256;
      vpb[(size_t)(b * 256 + cc) * NPs + n] = val;
      if (n >= 1) {
        int p = n - 1;
        vib[(size_t)(b * 256 + cc) * hw64 + (p / H) * 64 + (p % H)] = val;
      }
    }
  }
}

// ---------------- k softmax stats (all scales) ----------------
__global__ void ksm_all(const u16* __restrict__ KP, float* __restrict__ mx,
                        float* __restrict__ se) {
  int s = blockIdx.z, b = blockIdx.y;
  int N = selNS(s), NPs = selNPS(s);
  int wv = threadIdx.x >> 6, lane = threadIdx.x & 63;
  int cg = blockIdx.x * 4 + wv;
  const u16* kp = KP + selKPB(s) + (size_t)(b * 256 + cg) * NPs;
  float m = -1e30f, sm = 0.f;
  for (int n = lane; n < N; n += 64) {
    float v = bf2f(kp[n]);
    float nm = fmaxf(m, v);
    sm = sm * __expf(m - nm) + __expf(v - nm);
    m = nm;
  }
  #pragma unroll
  for (int off = 1; off < 64; off <<= 1) {
    float mo = __shfl_xor(m, off), so = __shfl_xor(sm, off);
    float nm = fmaxf(m, mo);
    sm = sm * __expf(m - nm) + so * __expf(mo - nm);
    m = nm;
  }
  if (lane == 0) { mx[s * 2048 + b * 256 + cg] = m; se[s * 2048 + b * 256 + cg] = sm; }
}

// ---------------- kv partials (all scales) ----------------
__launch_bounds__(1024)
__global__ void kv_partial_all(const u16* __restrict__ KP, const u16* __restrict__ VP,
                               const float* __restrict__ mx, float* __restrict__ part) {
  __shared__ float kl[32][65];
  __shared__ float vl[32][65];
  int blk = blockIdx.x;
  int s = (blk >= selNCB(1)) + (blk >= selNCB(2)) + (blk >= selNCB(3));
  int local = blk - selNCB(s);
  int NC = selNC(s);
  int chunk = local % NC;
  int bh = local / NC;
  int b = bh >> 3, h = bh & 7;
  int N = selNS(s), NPs = selNPS(s);
  int chunkrows = (N + NC - 1) / NC;
  const u16* kpb = KP + selKPB(s);
  const u16* vpb = VP + selKPB(s);
  int t = threadIdx.x;
  int i = t >> 5, j = t & 31;
  float acc = 0.f;
  int n0s = chunk * chunkrows, n1s = min(N, n0s + chunkrows);
  for (int n0 = n0s; n0 < n1s; n0 += 64) {
    #pragma unroll
    for (int e = t; e < 2048; e += 1024) {
      int c = e >> 6, nn = e & 63;
      int n = n0 + nn;
      bool ok = (n < n1s);
      kl[c][nn] = ok ? bf2f(kpb[(size_t)(b * 256 + h * 32 + c) * NPs + n]) : -1e30f;
      vl[c][nn] = ok ? bf2f(vpb[(size_t)(b * 256 + h * 32 + c) * NPs + n]) : 0.f;
    }
    __syncthreads();
    #pragma unroll
    for (int e = t; e < 2048; e += 1024) {
      int c = e >> 6, nn = e & 63;
      kl[c][nn] = __expf(kl[c][nn] - mx[s * 2048 + b * 256 + h * 32 + c]);
    }
    __syncthreads();
    #pragma unroll
    for (int nn = 0; nn < 64; ++nn) acc += kl[i][nn] * vl[j][nn];
    __syncthreads();
  }
  part[(size_t)blk * 1024 + t] = acc;
}

__global__ void kv_reduce_all(const float* __restrict__ part, const float* __restrict__ se,
                              float* __restrict__ kv) {
  int bh = blockIdx.x, s = blockIdx.y;
  int NC = selNC(s), base = selNCB(s);
  int t = threadIdx.x;
  int i = t >> 5;
  int b = bh >> 3, h = bh & 7;
  float sm = 0.f;
  for (int c = 0; c < NC; ++c) sm += part[(size_t)(base + bh * NC + c) * 1024 + t];
  kv[(size_t)s * 65536 + bh * 1024 + t] = sm / se[s * 2048 + b * 256 + h * 32 + i];
}

// ---------------- CRPE depthwise conv on padded planes (all scales) ----------------
template <int KS, int C0>
__global__ void crpe_all(const u16* __restrict__ VPI, const float* __restrict__ w,
                         const float* __restrict__ bias, u16* __restrict__ CVPI, int CS) {
  constexpr int pad = KS / 2;
  int z = blockIdx.z;
  int s = (z >= 2) + (z >= 3) + (z >= 4);
  int sub = z - (s == 0 ? 0 : s + 1);
  int RS = (s == 0) ? 2 : 1;
  int H = selHS(s);
  int c = blockIdx.x, b = blockIdx.y;
  int G = (H + 7) >> 3;
  int hpb = (H + RS - 1) / RS;
  int h0b = sub * hpb;
  int h1b = min(H, h0b + hpb);
  size_t plane = selVPB(s) + (size_t)(b * 256 + C0 + c) * (size_t)(H * 64);
  const u16* vp = VPI + plane;
  u16* op = CVPI + plane;
  float wreg[KS * KS];
  #pragma unroll
  for (int e = 0; e < KS * KS; ++e) wreg[e] = w[(s * CS + c) * KS * KS + e];
  float bb = bias[s * CS + c];
  int ntask = (h1b - h0b) * G;
  for (int task = threadIdx.x; task < ntask; task += 256) {
    int g = task % G;
    int h = h0b + task / G;
    int w0 = g << 3;
    float o[8];
    #pragma unroll
    for (int e = 0; e < 8; ++e) o[e] = bb;
    #pragma unroll
    for (int kh = 0; kh < KS; ++kh) {
      int hh = h + kh - pad;
      if (hh < 0 || hh >= H) continue;
      const u16* rowp = vp + hh * 64;
      U16x8 ch0 = {}, ch1, ch2;
      if (w0 >= 8) ch0 = *(const U16x8*)(rowp + w0 - 8);
      ch1 = *(const U16x8*)(rowp + w0);
      ch2 = *(const U16x8*)(rowp + w0 + 8);
      float tv[24];
      #pragma unroll
      for (int j2 = 8 - pad; j2 <= 15 + pad; ++j2) {
        u16 raw = (j2 < 8) ? ch0.d[j2] : (j2 < 16 ? ch1.d[j2 - 8] : ch2.d[j2 - 16]);
        tv[j2] = bf2f(raw);
      }
      #pragma unroll
      for (int kw = 0; kw < KS; ++kw) {
        float wv = wreg[kh * KS + kw];
        #pragma unroll
        for (int e = 0; e < 8; ++e) o[e] += tv[8 + e + kw - pad] * wv;
      }
    }
    U16x8 pk;
    #pragma unroll
    for (int e = 0; e < 8; ++e) pk.d[e] = f2bf(o[e]);
    *(U16x8*)(op + h * 64 + w0) = pk;
  }
}

// ---------------- att (all scales): attp = CH^-0.5 * (q @ kv) + q * conv_v ----------------
__global__ void att_all(const u16* __restrict__ T2, const u16* __restrict__ CVPI,
                        const float* __restrict__ kvg, u16* __restrict__ attp) {
  int s = blockIdx.z, b = blockIdx.y;
  int N = selNS(s), H = selHS(s);
  int n0 = blockIdx.x * 16;
  if (n0 >= N) return;
  __shared__ float kvl[8192];
  __shared__ float ql[256];
  __shared__ float cl[16][260];
  int t = threadIdx.x;
  int hw64 = H * 64;
  const u16* T2i = T2 + (size_t)selROW(s) * 768;
  u16* attpi = attp + (size_t)selROW(s) * 256;
  const u16* cvb = CVPI + selVPB(s);
  for (int e = t; e < 8192; e += 256) kvl[e] = kvg[(size_t)s * 65536 + b * 8192 + e];
  for (int e = t; e < 4096; e += 256) {
    int c = e >> 4, nn = e & 15;
    int n = n0 + nn;
    float v = 0.f;
    if (n >= 1 && n < N) {
      int p = n - 1;
      v = bf2f(cvb[(size_t)(b * 256 + c) * hw64 + (p / H) * 64 + (p % H)]);
    }
    cl[nn][c] = v;
  }
  int h = t >> 5, j = t & 31;
  for (int nn = 0; nn < 16; ++nn) {
    int n = n0 + nn;
    if (n >= N) break;
    __syncthreads();
    ql[t] = bf2f(T2i[((size_t)(b * N + n)) * 768 + t]);
    __syncthreads();
    float fa = 0.f;
    const float* kvh = kvl + h * 1024;
    #pragma unroll
    for (int k = 0; k < 32; ++k) fa += ql[h * 32 + k] * kvh[k * 32 + j];
    float v = 0.17677669529663687f * fa + ql[t] * cl[nn][t];
    attpi[(((size_t)b * N) + n) * 256 + t] = f2bf(v);
  }
}

// ---------------- cross-scale bilinear combine (all scales) ----------------
DEV float4 bsample4(const float* __restrict__ src, int b, int Ns, int Hs,
                    int oh, int ow, int Hi, int c4) {
  float scale = (float)Hs / (float)Hi;
  float sy = (oh + 0.5f) * scale - 0.5f;
  float sx = (ow + 0.5f) * scale - 0.5f;
  float fy0 = floorf(sy), fx0 = floorf(sx);
  float fy = sy - fy0, fx = sx - fx0;
  int y0 = (int)fy0, x0 = (int)fx0;
  int y0c = min(max(y0, 0), Hs - 1), y1c = min(max(y0 + 1, 0), Hs - 1);
  int x0c = min(max(x0, 0), Hs - 1), x1c = min(max(x0 + 1, 0), Hs - 1);
  const float* base = src + ((size_t)b * Ns + 1) * 256 + c4;
  float4 v00 = *(const float4*)(base + (size_t)(y0c * Hs + x0c) * 256);
  float4 v01 = *(const float4*)(base + (size_t)(y0c * Hs + x1c) * 256);
  float4 v10 = *(const float4*)(base + (size_t)(y1c * Hs + x0c) * 256);
  float4 v11 = *(const float4*)(base + (size_t)(y1c * Hs + x1c) * 256);
  float w00 = (1.f - fy) * (1.f - fx), w01 = (1.f - fy) * fx;
  float w10 = fy * (1.f - fx), w11 = fy * fx;
  float4 r;
  r.x = w00 * v00.x + w01 * v01.x + w10 * v10.x + w11 * v11.x;
  r.y = w00 * v00.y + w01 * v01.y + w10 * v10.y + w11 * v11.y;
  r.z = w00 * v00.z + w01 * v01.z + w10 * v10.z + w11 * v11.z;
  r.w = w00 * v00.w + w01 * v01.w + w10 * v10.w + w11 * v11.w;
  return r;
}

__global__ void combine_all(float* __restrict__ xi, const float* __restrict__ cc, int total4) {
  for (int idx = blockIdx.x * blockDim.x + threadIdx.x; idx < total4; idx += gridDim.x * blockDim.x) {
    int c4 = (idx & 63) << 2;
    int grow = idx >> 6;
    int s = row2scale(grow);
    int lrow = grow - selROW(s);
    int Ni = selNS(s), Hi = selHS(s);
    int sa = s == 0 ? 1 : s == 1 ? 2 : s == 2 ? 3 : 2;
    int sb = s == 0 ? 2 : 0;
    const float* srcA = cc + (size_t)selROW(sa) * 256;
    const float* srcB = cc + (size_t)selROW(sb) * 256;
    int HsA = selHS(sa), NsA = selNS(sa);
    int HsB = selHS(sb), NsB = selNS(sb);
    int n = lrow % Ni;
    int b = lrow / Ni;
    float4 add = *(const float4*)(cc + (size_t)grow * 256 + c4);
    if (n == 0) {
      float4 a = *(const float4*)(srcA + ((size_t)b * NsA) * 256 + c4);
      float4 bb = *(const float4*)(srcB + ((size_t)b * NsB) * 256 + c4);
      add.x += a.x + bb.x; add.y += a.y + bb.y;
      add.z += a.z + bb.z; add.w += a.w + bb.w;
    } else {
      int p = n - 1, oh = p / Hi, ow = p % Hi;
      float4 a = bsample4(srcA, b, NsA, HsA, oh, ow, Hi, c4);
      float4 bb = bsample4(srcB, b, NsB, HsB, oh, ow, Hi, c4);
      add.x += a.x + bb.x; add.y += a.y + bb.y;
      add.z += a.z + bb.z; add.w += a.w + bb.w;
    }
    float* xp = xi + (size_t)grow * 256 + c4;
    float4 cur = *(const float4*)xp;
    cur.x += add.x; cur.y += add.y; cur.z += add.z; cur.w += add.w;
    *(float4*)xp = cur;
  }
}

// ---------------- host ----------------
extern "C" void kernel_launch(void* const* d_in, const int* in_sizes, int n_in,
                              void* d_out, int out_size, void* d_ws, size_t ws_size,
                              hipStream_t stream) {
  const float* x1 = (const float*)d_in[0];
  const float* x2 = (const float*)d_in[1];
  const float* x3 = (const float*)d_in[2];
  const float* x4 = (const float*)d_in[3];
  const float* x5 = (const float*)d_in[4];
  const float* cpe_w  = (const float*)d_in[5];
  const float* cpe_b  = (const float*)d_in[6];
  const float* n1_g   = (const float*)d_in[7];
  const float* n1_b   = (const float*)d_in[8];
  const float* qkv_w  = (const float*)d_in[9];
  const float* proj_w = (const float*)d_in[10];
  const float* proj_b = (const float*)d_in[11];
  const float* crpe_w3 = (const float*)d_in[12];
  const float* crpe_b3 = (const float*)d_in[13];
  const float* crpe_w5 = (const float*)d_in[14];
  const float* crpe_b5 = (const float*)d_in[15];
  const float* crpe_w7 = (const float*)d_in[16];
  const float* crpe_b7 = (const float*)d_in[17];
  const float* n2_g   = (const float*)d_in[18];
  const float* n2_b   = (const float*)d_in[19];
  const float* fc1_w  = (const float*)d_in[20];
  const float* fc1_b  = (const float*)d_in[21];
  const float* fc2_w  = (const float*)d_in[22];
  const float* fc2_b  = (const float*)d_in[23];

  float* ws = (float*)d_ws;
  float* XI   = ws;                              // 8,538,112 f32
  float* CC   = XI + 8538112;                    // 8,538,112 f32
  u16*   T1   = (u16*)(CC + 8538112);            // RTOT*256 u16
  u16*   T2   = T1 + 8538112;                    // RTOT*1024 u16 (768 used phase-1)
  u16*   KP   = T2 + 34152448;                   // 8,912,896 u16
  u16*   VP   = KP + 8912896;                    // 8,912,896 u16
  u16*   VPI  = VP + 8912896;                    // 13,762,560 u16
  u16*   CVPI = VPI + 13762560;                  // 13,762,560 u16 (overlay: kv partials f32)
  float* PRT  = (float*)CVPI;                    // 2752*1024 f32
  float* MX   = (float*)(CVPI + 13762560);       // 4*2048
  float* SE   = MX + 8192;
  float* KV   = SE + 8192;                       // 4*65536
  u16*   WQ   = (u16*)(KV + 262144);             // 786,432 u16
  u16*   WP   = WQ + 786432;                     // 262,144 u16
  u16*   W1   = WP + 262144;
  u16*   W2   = W1 + 262144;
  float* WT   = (float*)(W2 + 262144);           // 9,216 f32

  float* out = (float*)d_out;

  cvt_bf16<<<1536, 256, 0, stream>>>(qkv_w, WQ, 786432);
  cvt_bf16<<<512, 256, 0, stream>>>(proj_w, WP, 262144);
  cvt_bf16<<<512, 256, 0, stream>>>(fc1_w, W1, 262144);
  cvt_bf16<<<512, 256, 0, stream>>>(fc2_w, W2, 262144);
  tpw_cpe<<<dim3(9, 4), 256, 0, stream>>>(cpe_w, WT);

  copy_f4<<<8192, 256, 0, stream>>>((const float4*)x1, (float4*)out, 25692160 / 4);

  int nmt[4], prefQ[5], prefP[5];
  prefQ[0] = prefP[0] = 0;
  for (int i = 0; i < 4; ++i) {
    nmt[i] = (8 * NS[i] + 127) / 128;
    prefQ[i + 1] = prefQ[i] + nmt[i] * 6;
    prefP[i + 1] = prefP[i] + nmt[i] * 2;
  }

  // phase 1a: CPE + LN1 (all scales, one dispatch each)
  cpe_all<<<8192, 256, 0, stream>>>(x2, x3, x4, x5, WT, cpe_b, XI, RTOT * 64);
  ln_all<<<(RTOT + 3) / 4, 256, 0, stream>>>(XI, n1_g, n1_b, T1, RTOT);

  // phase 1b: grouped qkv GEMM (bf16 out [R][768])
  {
    GrpArgs ga;
    for (int i = 0; i < 4; ++i) {
      ga.A[i] = T1 + (size_t)ROWOFF[i] * 256;
      ga.W[i] = WQ + (size_t)i * 196608;
      ga.bias[i] = nullptr;
      ga.outoff[i] = (size_t)ROWOFF[i] * 768;
      ga.M[i] = 8 * NS[i];
    }
    for (int e = 0; e < 5; ++e) ga.pref[e] = prefQ[e];
    gemm_grp<true><<<prefQ[4], 256, 0, stream>>>(ga, T2, 256, 768, 6);
  }

  // phase 1c: attention mid-section (batched over scales)
  hipMemsetAsync(VPI, 0, 13762560ull * 2, stream);
  tp_all<<<dim3(50, 8, 32), 256, 0, stream>>>(T2, KP, VP, VPI);
  ksm_all<<<dim3(64, 8, 4), 256, 0, stream>>>(KP, MX, SE);
  kv_partial_all<<<2752, 1024, 0, stream>>>(KP, VP, MX, PRT);
  kv_reduce_all<<<dim3(64, 4), 1024, 0, stream>>>(PRT, SE, KV);
  crpe_all<3, 0><<<dim3(64, 8, 5), 256, 0, stream>>>(VPI, crpe_w3, crpe_b3, CVPI, 64);
  crpe_all<5, 64><<<dim3(96, 8, 5), 256, 0, stream>>>(VPI, crpe_w5, crpe_b5, CVPI, 96);
  crpe_all<7, 160><<<dim3(96, 8, 5), 256, 0, stream>>>(VPI, crpe_w7, crpe_b7, CVPI, 96);
  att_all<<<dim3(197, 8, 4), 256, 0, stream>>>(T2, CVPI, KV, T1);

  // phase 1d: grouped proj GEMM (f32 out into CC)
  {
    GrpArgs ga;
    for (int i = 0; i < 4; ++i) {
      ga.A[i] = T1 + (size_t)ROWOFF[i] * 256;
      ga.W[i] = WP + (size_t)i * 65536;
      ga.bias[i] = proj_b + i * 256;
      ga.outoff[i] = (size_t)ROWOFF[i] * 256;
      ga.M[i] = 8 * NS[i];
    }
    for (int e = 0; e < 5; ++e) ga.pref[e] = prefP[e];
    gemm_grp<false><<<prefP[4], 256, 0, stream>>>(ga, CC, 256, 256, 2);
  }

  // phase 2: cross-scale bilinear combine (one dispatch)
  combine_all<<<8192, 256, 0, stream>>>(XI, CC, RTOT * 64);

  // phase 3: LN2 + fused MLP across scales
  ln_all<<<(RTOT + 3) / 4, 256, 0, stream>>>(XI, n2_g, n2_b, T1, RTOT);
  int nmtT = (RTOT + 127) / 128;
  gemm_mfma<true, true><<<nmtT * 8, 256, 0, stream>>>(T1, W1, fc1_b, nullptr, (void*)T2,
                                                      RTOT, 256, 1024, 8);
  gemm_mfma<false, false><<<nmtT * 2, 256, 0, stream>>>(T2, W2, fc2_b, XI, out + OUTOFF0,
                                                        RTOT, 1024, 256, 2);
}

// Round 9
// 489.308 us; speedup vs baseline: 4.9946x; 1.0635x over previous
//
#include <hip/hip_runtime.h>
#include <math.h>

typedef unsigned short u16;
typedef __attribute__((ext_vector_type(8))) short bf16x8;
typedef __attribute__((ext_vector_type(4))) float f32x4;

// padded row space: per (s,b) tokens padded to NPAD; M' = 36864 = 288*128
#define MP 36864
#define OUTOFF0 25692160ull

#define DEV __device__ __forceinline__
#define AS1 __attribute__((address_space(1)))
#define AS3 __attribute__((address_space(3)))

DEV u16 f2bf(float x) {
  union { float f; unsigned u; } v; v.f = x;
  unsigned r = v.u + 0x7fffu + ((v.u >> 16) & 1u);
  return (u16)(r >> 16);
}
DEV float bf2f(u16 x) {
  union { unsigned u; float f; } v; v.u = ((unsigned)x) << 16;
  return v.f;
}

struct alignas(8) u16x4s { u16 x, y, z, w; };
struct alignas(16) U16x8 { u16 d[8]; };

DEV int rs_s(int row)   { return (row >= 25600) + (row >= 33792) + (row >= 35840); }
DEV int selPB(int s)    { return s == 0 ? 0 : s == 1 ? 25600 : s == 2 ? 33792 : 35840; }
DEV int selNPAD(int s)  { return s == 0 ? 3200 : s == 1 ? 1024 : s == 2 ? 256 : 128; }
DEV int selN(int s)     { return s == 0 ? 3137 : s == 1 ? 785 : s == 2 ? 197 : 50; }
DEV int selH(int s)     { return s == 0 ? 56 : s == 1 ? 28 : s == 2 ? 14 : 7; }
DEV int selRO(int s)    { return s == 0 ? 0 : s == 1 ? 25096 : s == 2 ? 31376 : 32952; }
DEV size_t selKPB(int s){ return s == 0 ? 0ull : s == 1 ? 6553600ull : s == 2 ? 8650752ull : 9175040ull; }
DEV size_t selVPB(int s){ return s == 0 ? 0ull : s == 1 ? 7340032ull : s == 2 ? 11010048ull : 12845056ull; }
DEV int selNC(int s)    { return s == 0 ? 32 : s == 1 ? 8 : s == 2 ? 2 : 1; }
DEV int selNCB(int s)   { return s == 0 ? 0 : s == 1 ? 2048 : s == 2 ? 2560 : 2688; }
DEV unsigned selHM(int s){ return s == 0 ? 74899u : s == 1 ? 149797u : s == 2 ? 299594u : 599187u; }

DEV void sbn(int row, int s, int& b, int& n) {
  int l = row - selPB(s);
  if (s == 0)      { b = l / 3200; n = l - b * 3200; }
  else if (s == 1) { b = l >> 10; n = l & 1023; }
  else if (s == 2) { b = l >> 8;  n = l & 255; }
  else             { b = l >> 7;  n = l & 127; }
}

DEV int xcd_swizzle(int orig, int nblk) {
  int q = nblk >> 3, r = nblk & 7;
  int xcd = orig & 7, lin = orig >> 3;
  return (xcd < r ? xcd * (q + 1) : r * (q + 1) + (xcd - r) * q) + lin;
}

// ---------------- small prep kernels ----------------
__global__ void cvt_bf16(const float* __restrict__ src, u16* __restrict__ dst, int n) {
  for (int i = blockIdx.x * blockDim.x + threadIdx.x; i < n; i += gridDim.x * blockDim.x)
    dst[i] = f2bf(src[i]);
}

__global__ void tpw_cpe(const float* __restrict__ src, float* __restrict__ dst) {
  int i = blockIdx.y;
  int e = blockIdx.x * 256 + threadIdx.x;
  if (e < 2304) {
    int c = e / 9, k = e % 9;
    dst[i * 2304 + k * 256 + c] = src[i * 2304 + c * 9 + k];
  }
}

__global__ void copy_f4(const float4* __restrict__ src, float4* __restrict__ dst, int n4) {
  for (int i = blockIdx.x * blockDim.x + threadIdx.x; i < n4; i += gridDim.x * blockDim.x)
    dst[i] = src[i];
}

// ---------------- fused CPE + LN1 (wave per padded row) ----------------
__global__ void cpe_ln_all(const float* __restrict__ x2, const float* __restrict__ x3,
                           const float* __restrict__ x4, const float* __restrict__ x5,
                           const float* __restrict__ WT, const float* __restrict__ cpe_b,
                           const float* __restrict__ n1g, const float* __restrict__ n1b,
                           float* __restrict__ XI, u16* __restrict__ T1) {
  int wid = threadIdx.x >> 6, lane = threadIdx.x & 63;
  int row = blockIdx.x * 4 + wid;
  if (row >= MP) return;
  int s = rs_s(row);
  int b, n; sbn(row, s, b, n);
  int N = selN(s), H = selH(s);
  int c4 = lane * 4;
  float4 v = make_float4(0.f, 0.f, 0.f, 0.f);
  if (n < N) {
    const float* x = s == 0 ? x2 : s == 1 ? x3 : s == 2 ? x4 : x5;
    v = *(const float4*)(x + ((size_t)b * N + n) * 256 + c4);
    if (n > 0) {
      int p = n - 1, h0 = p / H, w0 = p % H;
      float4 acc = *(const float4*)(cpe_b + s * 256 + c4);
      const float* wT = WT + s * 2304;
      #pragma unroll
      for (int kh = 0; kh < 3; ++kh) {
        int hh = h0 + kh - 1;
        if (hh < 0 || hh >= H) continue;
        #pragma unroll
        for (int kw = 0; kw < 3; ++kw) {
          int ww = w0 + kw - 1;
          if (ww < 0 || ww >= H) continue;
          float4 t = *(const float4*)(x + ((size_t)b * N + 1 + hh * H + ww) * 256 + c4);
          float4 wv = *(const float4*)(wT + (kh * 3 + kw) * 256 + c4);
          acc.x += t.x * wv.x; acc.y += t.y * wv.y;
          acc.z += t.z * wv.z; acc.w += t.w * wv.w;
        }
      }
      v.x += acc.x; v.y += acc.y; v.z += acc.z; v.w += acc.w;
    }
  }
  *(float4*)(XI + (size_t)row * 256 + c4) = v;
  // LN
  float sm = v.x + v.y + v.z + v.w;
  #pragma unroll
  for (int off = 32; off; off >>= 1) sm += __shfl_down(sm, off);
  sm = __shfl(sm, 0);
  float mu = sm * (1.0f / 256.0f);
  float dx = v.x - mu, dy = v.y - mu, dz = v.z - mu, dw = v.w - mu;
  float q = dx * dx + dy * dy + dz * dz + dw * dw;
  #pragma unroll
  for (int off = 32; off; off >>= 1) q += __shfl_down(q, off);
  q = __shfl(q, 0);
  float rs = rsqrtf(q * (1.0f / 256.0f) + 1e-5f);
  float4 gg = *(const float4*)(n1g + s * 256 + c4);
  float4 bb = *(const float4*)(n1b + s * 256 + c4);
  u16x4s o;
  o.x = f2bf(dx * rs * gg.x + bb.x);
  o.y = f2bf(dy * rs * gg.y + bb.y);
  o.z = f2bf(dz * rs * gg.z + bb.z);
  o.w = f2bf(dw * rs * gg.w + bb.w);
  *(u16x4s*)(T1 + (size_t)row * 256 + c4) = o;
}

// ---------------- GEMM pieces: BK=32 mainloop + LDS epilogue (stride 132) ----------------
DEV void stage32(const u16* __restrict__ A, const u16* __restrict__ W,
                 u16* dst, int bm, int bn, int K, int k0) {
  int t = threadIdx.x, wv = t >> 6;
  u16* aD = dst;
  u16* bD = dst + 4096;
  #pragma unroll
  for (int iss = 0; iss < 2; ++iss) {
    int sI = iss * 256 + t;
    int row = sI >> 2, g = sI & 3;
    int gel = ((g ^ (row & 3)) << 3);
    __builtin_amdgcn_global_load_lds(
        (const AS1 void*)(A + (size_t)(bm + row) * K + k0 + gel),
        (AS3 void*)(aD + (size_t)(iss * 256 + wv * 64) * 8), 16, 0, 0);
    __builtin_amdgcn_global_load_lds(
        (const AS1 void*)(W + (size_t)(bn + row) * K + k0 + gel),
        (AS3 void*)(bD + (size_t)(iss * 256 + wv * 64) * 8), 16, 0, 0);
  }
}

DEV void mainloop(const u16* __restrict__ A, const u16* __restrict__ W, int K,
                  int bm, int bn, u16* lds, f32x4 (&acc)[4][4]) {
  int t = threadIdx.x, lane = t & 63, wv = t >> 6;
  int wr = wv >> 1, wc = wv & 1;
  const int nt = K >> 5;
  stage32(A, W, lds, bm, bn, K, 0);
  for (int tt = 0; tt < nt; ++tt) {
    __syncthreads();
    if (tt + 1 < nt) stage32(A, W, lds + ((tt + 1) & 1) * 8192, bm, bn, K, (tt + 1) << 5);
    const u16* aS = lds + (tt & 1) * 8192;
    const u16* bS = aS + 4096;
    bf16x8 af[4], bfr[4];
    #pragma unroll
    for (int m = 0; m < 4; ++m) {
      int row = wr * 64 + m * 16 + (lane & 15);
      int sg = (lane >> 4) ^ (row & 3);
      af[m] = *(const bf16x8*)(aS + row * 32 + sg * 8);
    }
    #pragma unroll
    for (int n = 0; n < 4; ++n) {
      int row = wc * 64 + n * 16 + (lane & 15);
      int sg = (lane >> 4) ^ (row & 3);
      bfr[n] = *(const bf16x8*)(bS + row * 32 + sg * 8);
    }
    #pragma unroll
    for (int m = 0; m < 4; ++m)
      #pragma unroll
      for (int n = 0; n < 4; ++n)
        acc[m][n] = __builtin_amdgcn_mfma_f32_16x16x32_bf16(af[m], bfr[n], acc[m][n], 0, 0, 0);
  }
}

DEV void epi_dump(const f32x4 (&acc)[4][4], int pass, float* eps) {
  int t = threadIdx.x, lane = t & 63, wv = t >> 6;
  int wr = wv >> 1, wc = wv & 1;
  if (wr != (pass >> 1)) return;
  #pragma unroll
  for (int mh = 0; mh < 2; ++mh) {
    int m = (pass & 1) * 2 + mh;
    #pragma unroll
    for (int n = 0; n < 4; ++n) {
      int col = wc * 64 + n * 16 + (lane & 15);
      #pragma unroll
      for (int rg = 0; rg < 4; ++rg)
        eps[(mh * 16 + ((lane >> 4) << 2) + rg) * 132 + col] = acc[m][n][rg];
    }
  }
}

template <bool GELU, bool BF16>
DEV void epi_rowmajor(const float* eps, int pass, void* outp, const float* bias,
                      int bm, int bn, int Nout) {
  int t = threadIdx.x;
  int lr = t >> 3, cb = (t & 7) * 4;
  int gr = bm + pass * 32 + lr;
  #pragma unroll
  for (int j = 0; j < 4; ++j) {
    int col = cb + j * 32;
    float4 f = *(const float4*)(eps + lr * 132 + col);
    int gc = bn + col;
    if (bias) {
      float4 bv = *(const float4*)(bias + gc);
      f.x += bv.x; f.y += bv.y; f.z += bv.z; f.w += bv.w;
    }
    if (GELU) {
      f.x /= (1.0f + __expf(-1.702f * f.x));
      f.y /= (1.0f + __expf(-1.702f * f.y));
      f.z /= (1.0f + __expf(-1.702f * f.z));
      f.w /= (1.0f + __expf(-1.702f * f.w));
    }
    if (BF16) {
      u16x4s p;
      p.x = f2bf(f.x); p.y = f2bf(f.y); p.z = f2bf(f.z); p.w = f2bf(f.w);
      *(u16x4s*)((u16*)outp + (size_t)gr * Nout + gc) = p;
    } else {
      *(float4*)((float*)outp + (size_t)gr * Nout + gc) = f;
    }
  }
}

// ---------------- standard GEMM (fc1) ----------------
template <bool GELU, bool BF16>
__launch_bounds__(256, 4)
__global__ void gemm_std(const u16* __restrict__ A, const u16* __restrict__ W,
                         const float* __restrict__ bias, void* __restrict__ outp,
                         int K, int Nout, int nnt) {
  __shared__ __align__(16) u16 lds[16384];
  int wg = xcd_swizzle(blockIdx.x, gridDim.x);
  int bm = (wg / nnt) << 7, bn = (wg % nnt) << 7;
  f32x4 acc[4][4] = {};
  mainloop(A, W, K, bm, bn, lds, acc);
  float* eps = (float*)lds;
  #pragma unroll
  for (int pass = 0; pass < 4; ++pass) {
    __syncthreads();
    epi_dump(acc, pass, eps);
    __syncthreads();
    epi_rowmajor<GELU, BF16>(eps, pass, outp, bias, bm, bn, Nout);
  }
}

// ---------------- qkv GEMM: q row-major bf16; k,v planar-transposed; v image ----------------
__launch_bounds__(256, 4)
__global__ void qkv_gemm(const u16* __restrict__ A, const u16* __restrict__ WQ,
                         u16* __restrict__ Q16, u16* __restrict__ KP,
                         u16* __restrict__ VP, u16* __restrict__ VPI) {
  __shared__ __align__(16) u16 lds[16384];
  int wg = xcd_swizzle(blockIdx.x, gridDim.x);
  int mt = wg / 6, ct = wg % 6;
  int bm = mt << 7, bn = ct << 7;
  int s = rs_s(bm);
  f32x4 acc[4][4] = {};
  mainloop(A, WQ + (size_t)s * 196608, 256, bm, bn, lds, acc);
  float* eps = (float*)lds;
  int b, nb; sbn(bm, s, b, nb);
  int NPAD = selNPAD(s), H = selH(s), HW = H * H;
  unsigned hmag = selHM(s);
  #pragma unroll
  for (int pass = 0; pass < 4; ++pass) {
    __syncthreads();
    epi_dump(acc, pass, eps);
    __syncthreads();
    if (ct < 2) {
      epi_rowmajor<false, true>(eps, pass, Q16, nullptr, bm, bn, 256);
    } else {
      int t = threadIdx.x;
      int c = t >> 1, half = t & 1;
      bool isK = (ct < 4);
      int cg = bn - (isK ? 256 : 512) + c;
      int n0 = nb + pass * 32 + half * 16;
      float vals[16];
      #pragma unroll
      for (int r = 0; r < 16; ++r) vals[r] = eps[(half * 16 + r) * 132 + c];
      U16x8 p0, p1;
      #pragma unroll
      for (int e = 0; e < 8; ++e) { p0.d[e] = f2bf(vals[e]); p1.d[e] = f2bf(vals[8 + e]); }
      u16* pbase = (isK ? KP : VP) + selKPB(s) + (size_t)(b * 256 + cg) * NPAD + n0;
      *(U16x8*)pbase = p0;
      *(U16x8*)(pbase + 8) = p1;
      if (!isK) {
        u16* vplane = VPI + selVPB(s) + (size_t)(b * 256 + cg) * (H * 64);
        #pragma unroll
        for (int r = 0; r < 16; ++r) {
          int n = n0 + r;
          if (n >= 1 && n <= HW) {
            int p = n - 1;
            int qd = (int)(((unsigned)p * hmag) >> 22);
            vplane[qd * 64 + (p - qd * H)] = f2bf(vals[r]);
          }
        }
      }
    }
  }
}

// ---------------- proj GEMM: per-scale W/bias, f32 out ----------------
__launch_bounds__(256, 4)
__global__ void proj_gemm(const u16* __restrict__ A, const u16* __restrict__ WP,
                          const float* __restrict__ proj_b, float* __restrict__ CC) {
  __shared__ __align__(16) u16 lds[16384];
  int wg = xcd_swizzle(blockIdx.x, gridDim.x);
  int bm = (wg >> 1) << 7, bn = (wg & 1) << 7;
  int s = rs_s(bm);
  f32x4 acc[4][4] = {};
  mainloop(A, WP + (size_t)s * 65536, 256, bm, bn, lds, acc);
  float* eps = (float*)lds;
  #pragma unroll
  for (int pass = 0; pass < 4; ++pass) {
    __syncthreads();
    epi_dump(acc, pass, eps);
    __syncthreads();
    epi_rowmajor<false, false>(eps, pass, CC, proj_b + s * 256, bm, bn, 256);
  }
}

// ---------------- fc2 GEMM: +bias +XI residual, remapped f32 out ----------------
__launch_bounds__(256, 4)
__global__ void fc2_gemm(const u16* __restrict__ A, const u16* __restrict__ W2,
                         const float* __restrict__ fc2_b, const float* __restrict__ XI,
                         float* __restrict__ out) {
  __shared__ __align__(16) u16 lds[16384];
  int wg = xcd_swizzle(blockIdx.x, gridDim.x);
  int bm = (wg >> 1) << 7, bn = (wg & 1) << 7;
  f32x4 acc[4][4] = {};
  mainloop(A, W2, 1024, bm, bn, lds, acc);
  float* eps = (float*)lds;
  int s = rs_s(bm);
  int b, nb; sbn(bm, s, b, nb);
  int N = selN(s), RO = selRO(s);
  #pragma unroll
  for (int pass = 0; pass < 4; ++pass) {
    __syncthreads();
    epi_dump(acc, pass, eps);
    __syncthreads();
    int t = threadIdx.x;
    int lr = t >> 3, cb = (t & 7) * 4;
    int n = nb + pass * 32 + lr;
    if (n >= N) continue;
    int prow = bm + pass * 32 + lr;
    size_t orow = (size_t)RO + (size_t)b * N + n;
    #pragma unroll
    for (int j = 0; j < 4; ++j) {
      int col = cb + j * 32;
      float4 f = *(const float4*)(eps + lr * 132 + col);
      int gc = bn + col;
      float4 bv = *(const float4*)(fc2_b + gc);
      float4 rv = *(const float4*)(XI + (size_t)prow * 256 + gc);
      f.x += bv.x + rv.x; f.y += bv.y + rv.y;
      f.z += bv.z + rv.z; f.w += bv.w + rv.w;
      *(float4*)(out + OUTOFF0 + orow * 256 + gc) = f;
    }
  }
}

// ---------------- k softmax stats ----------------
__global__ void ksm_all(const u16* __restrict__ KP, float* __restrict__ mx,
                        float* __restrict__ se) {
  int s = blockIdx.z, b = blockIdx.y;
  int N = selN(s), NPAD = selNPAD(s);
  int wv = threadIdx.x >> 6, lane = threadIdx.x & 63;
  int cg = blockIdx.x * 4 + wv;
  const u16* kp = KP + selKPB(s) + (size_t)(b * 256 + cg) * NPAD;
  float m = -1e30f, sm = 0.f;
  for (int n = lane; n < N; n += 64) {
    float v = bf2f(kp[n]);
    float nm = fmaxf(m, v);
    sm = sm * __expf(m - nm) + __expf(v - nm);
    m = nm;
  }
  #pragma unroll
  for (int off = 1; off < 64; off <<= 1) {
    float mo = __shfl_xor(m, off), so = __shfl_xor(sm, off);
    float nm = fmaxf(m, mo);
    sm = sm * __expf(m - nm) + so * __expf(mo - nm);
    m = nm;
  }
  if (lane == 0) { mx[s * 2048 + b * 256 + cg] = m; se[s * 2048 + b * 256 + cg] = sm; }
}

// ---------------- kv partials ----------------
__launch_bounds__(1024)
__global__ void kv_partial_all(const u16* __restrict__ KP, const u16* __restrict__ VP,
                               const float* __restrict__ mx, float* __restrict__ part) {
  __shared__ float kl[32][65];
  __shared__ float vl[32][65];
  int blk = blockIdx.x;
  int s = (blk >= selNCB(1)) + (blk >= selNCB(2)) + (blk >= selNCB(3));
  int local = blk - selNCB(s);
  int NC = selNC(s);
  int chunk = local % NC;
  int bh = local / NC;
  int b = bh >> 3, h = bh & 7;
  int N = selN(s), NPAD = selNPAD(s);
  int chunkrows = (N + NC - 1) / NC;
  const u16* kpb = KP + selKPB(s);
  const u16* vpb = VP + selKPB(s);
  int t = threadIdx.x;
  int i = t >> 5, j = t & 31;
  float acc = 0.f;
  int n0s = chunk * chunkrows, n1s = min(N, n0s + chunkrows);
  for (int n0 = n0s; n0 < n1s; n0 += 64) {
    #pragma unroll
    for (int e = t; e < 2048; e += 1024) {
      int c = e >> 6, nn = e & 63;
      int n = n0 + nn;
      bool ok = (n < n1s);
      kl[c][nn] = ok ? bf2f(kpb[(size_t)(b * 256 + h * 32 + c) * NPAD + n]) : -1e30f;
      vl[c][nn] = ok ? bf2f(vpb[(size_t)(b * 256 + h * 32 + c) * NPAD + n]) : 0.f;
    }
    __syncthreads();
    #pragma unroll
    for (int e = t; e < 2048; e += 1024) {
      int c = e >> 6, nn = e & 63;
      kl[c][nn] = __expf(kl[c][nn] - mx[s * 2048 + b * 256 + h * 32 + c]);
    }
    __syncthreads();
    #pragma unroll
    for (int nn = 0; nn < 64; ++nn) acc += kl[i][nn] * vl[j][nn];
    __syncthreads();
  }
  part[(size_t)blk * 1024 + t] = acc;
}

__global__ void kv_reduce_all(const float* __restrict__ part, const float* __restrict__ se,
                              float* __restrict__ kv) {
  int bh = blockIdx.x, s = blockIdx.y;
  int NC = selNC(s), base = selNCB(s);
  int t = threadIdx.x;
  int i = t >> 5;
  int b = bh >> 3, h = bh & 7;
  float sm = 0.f;
  for (int c = 0; c < NC; ++c) sm += part[(size_t)(base + bh * NC + c) * 1024 + t];
  kv[(size_t)s * 65536 + bh * 1024 + t] = sm / se[s * 2048 + b * 256 + h * 32 + i];
}

// ---------------- CRPE depthwise conv on padded planes ----------------
template <int KS, int C0>
__global__ void crpe_all(const u16* __restrict__ VPI, const float* __restrict__ w,
                         const float* __restrict__ bias, u16* __restrict__ CVPI, int CS) {
  constexpr int pad = KS / 2;
  int z = blockIdx.z;
  int s = (z >= 2) + (z >= 3) + (z >= 4);
  int sub = z - (s == 0 ? 0 : s + 1);
  int RS = (s == 0) ? 2 : 1;
  int H = selH(s);
  int c = blockIdx.x, b = blockIdx.y;
  int G = (H + 7) >> 3;
  int hpb = (H + RS - 1) / RS;
  int h0b = sub * hpb;
  int h1b = min(H, h0b + hpb);
  size_t plane = selVPB(s) + (size_t)(b * 256 + C0 + c) * (size_t)(H * 64);
  const u16* vp = VPI + plane;
  u16* op = CVPI + plane;
  float wreg[KS * KS];
  #pragma unroll
  for (int e = 0; e < KS * KS; ++e) wreg[e] = w[(s * CS + c) * KS * KS + e];
  float bb = bias[s * CS + c];
  int ntask = (h1b - h0b) * G;
  for (int task = threadIdx.x; task < ntask; task += 256) {
    int g = task % G;
    int h = h0b + task / G;
    int w0 = g << 3;
    float o[8];
    #pragma unroll
    for (int e = 0; e < 8; ++e) o[e] = bb;
    #pragma unroll
    for (int kh = 0; kh < KS; ++kh) {
      int hh = h + kh - pad;
      if (hh < 0 || hh >= H) continue;
      const u16* rowp = vp + hh * 64;
      U16x8 ch0 = {}, ch1, ch2;
      if (w0 >= 8) ch0 = *(const U16x8*)(rowp + w0 - 8);
      ch1 = *(const U16x8*)(rowp + w0);
      ch2 = *(const U16x8*)(rowp + w0 + 8);
      float tv[24];
      #pragma unroll
      for (int j2 = 8 - pad; j2 <= 15 + pad; ++j2) {
        u16 raw = (j2 < 8) ? ch0.d[j2] : (j2 < 16 ? ch1.d[j2 - 8] : ch2.d[j2 - 16]);
        tv[j2] = bf2f(raw);
      }
      #pragma unroll
      for (int kw = 0; kw < KS; ++kw) {
        float wv = wreg[kh * KS + kw];
        #pragma unroll
        for (int e = 0; e < 8; ++e) o[e] += tv[8 + e + kw - pad] * wv;
      }
    }
    U16x8 pk;
    #pragma unroll
    for (int e = 0; e < 8; ++e) pk.d[e] = f2bf(o[e]);
    *(U16x8*)(op + h * 64 + w0) = pk;
  }
}

// ---------------- att: attp = CH^-0.5 * (q @ kv) + q * conv_v ----------------
__global__ void att_all(const u16* __restrict__ Q16, const u16* __restrict__ CVPI,
                        const float* __restrict__ kvg, u16* __restrict__ attp) {
  int s = blockIdx.z, b = blockIdx.y;
  int N = selN(s), H = selH(s);
  int n0 = blockIdx.x * 16;
  if (n0 >= N) return;
  __shared__ float kvl[8192];
  __shared__ float ql[256];
  __shared__ float cl[16][260];
  int t = threadIdx.x;
  int hw64 = H * 64;
  size_t rowbase = (size_t)selPB(s) + (size_t)b * selNPAD(s);
  const u16* cvb = CVPI + selVPB(s);
  for (int e = t; e < 8192; e += 256) kvl[e] = kvg[(size_t)s * 65536 + b * 8192 + e];
  for (int e = t; e < 4096; e += 256) {
    int c = e >> 4, nn = e & 15;
    int n = n0 + nn;
    float v = 0.f;
    if (n >= 1 && n < N) {
      int p = n - 1;
      v = bf2f(cvb[(size_t)(b * 256 + c) * hw64 + (p / H) * 64 + (p % H)]);
    }
    cl[nn][c] = v;
  }
  int h = t >> 5, j = t & 31;
  for (int nn = 0; nn < 16; ++nn) {
    int n = n0 + nn;
    if (n >= N) break;
    __syncthreads();
    ql[t] = bf2f(Q16[(rowbase + n) * 256 + t]);
    __syncthreads();
    float fa = 0.f;
    const float* kvh = kvl + h * 1024;
    #pragma unroll
    for (int k = 0; k < 32; ++k) fa += ql[h * 32 + k] * kvh[k * 32 + j];
    float v = 0.17677669529663687f * fa + ql[t] * cl[nn][t];
    attp[(rowbase + n) * 256 + t] = f2bf(v);
  }
}

// ---------------- fused cross-scale combine + LN2 (wave per padded row) ----------------
DEV float4 bs4(const float* __restrict__ base, int Hs, int oh, int ow, int Hi, int c4) {
  float scale = (float)Hs / (float)Hi;
  float sy = (oh + 0.5f) * scale - 0.5f;
  float sx = (ow + 0.5f) * scale - 0.5f;
  float fy0 = floorf(sy), fx0 = floorf(sx);
  float fy = sy - fy0, fx = sx - fx0;
  int y0 = (int)fy0, x0 = (int)fx0;
  int y0c = min(max(y0, 0), Hs - 1), y1c = min(max(y0 + 1, 0), Hs - 1);
  int x0c = min(max(x0, 0), Hs - 1), x1c = min(max(x0 + 1, 0), Hs - 1);
  const float* ib = base + 256 + c4;   // +256: skip cls token
  float4 v00 = *(const float4*)(ib + (size_t)(y0c * Hs + x0c) * 256);
  float4 v01 = *(const float4*)(ib + (size_t)(y0c * Hs + x1c) * 256);
  float4 v10 = *(const float4*)(ib + (size_t)(y1c * Hs + x0c) * 256);
  float4 v11 = *(const float4*)(ib + (size_t)(y1c * Hs + x1c) * 256);
  float w00 = (1.f - fy) * (1.f - fx), w01 = (1.f - fy) * fx;
  float w10 = fy * (1.f - fx), w11 = fy * fx;
  float4 r;
  r.x = w00 * v00.x + w01 * v01.x + w10 * v10.x + w11 * v11.x;
  r.y = w00 * v00.y + w01 * v01.y + w10 * v10.y + w11 * v11.y;
  r.z = w00 * v00.z + w01 * v01.z + w10 * v10.z + w11 * v11.z;
  r.w = w00 * v00.w + w01 * v01.w + w10 * v10.w + w11 * v11.w;
  return r;
}

__global__ void combine_ln_all(float* __restrict__ XI, const float* __restrict__ CC,
                               const float* __restrict__ n2g, const float* __restrict__ n2b,
                               u16* __restrict__ T1) {
  int wid = threadIdx.x >> 6, lane = threadIdx.x & 63;
  int row = blockIdx.x * 4 + wid;
  if (row >= MP) return;
  int s = rs_s(row);
  int b, n; sbn(row, s, b, n);
  int N = selN(s), Hi = selH(s);
  int c4 = lane * 4;
  float4 v;
  if (n < N) {
    float4 add = *(const float4*)(CC + (size_t)row * 256 + c4);
    int sa = s == 0 ? 1 : s == 1 ? 2 : s == 2 ? 3 : 2;
    int sb_ = s == 0 ? 2 : 0;
    const float* baseA = CC + ((size_t)selPB(sa) + (size_t)b * selNPAD(sa)) * 256;
    const float* baseB = CC + ((size_t)selPB(sb_) + (size_t)b * selNPAD(sb_)) * 256;
    if (n == 0) {
      float4 a = *(const float4*)(baseA + c4);
      float4 bb2 = *(const float4*)(baseB + c4);
      add.x += a.x + bb2.x; add.y += a.y + bb2.y;
      add.z += a.z + bb2.z; add.w += a.w + bb2.w;
    } else {
      int p = n - 1, oh = p / Hi, ow = p % Hi;
      float4 a = bs4(baseA, selH(sa), oh, ow, Hi, c4);
      float4 bb2 = bs4(baseB, selH(sb_), oh, ow, Hi, c4);
      add.x += a.x + bb2.x; add.y += a.y + bb2.y;
      add.z += a.z + bb2.z; add.w += a.w + bb2.w;
    }
    float* xp = XI + (size_t)row * 256 + c4;
    v = *(const float4*)xp;
    v.x += add.x; v.y += add.y; v.z += add.z; v.w += add.w;
    *(float4*)xp = v;
  } else {
    v = make_float4(0.f, 0.f, 0.f, 0.f);
  }
  float sm = v.x + v.y + v.z + v.w;
  #pragma unroll
  for (int off = 32; off; off >>= 1) sm += __shfl_down(sm, off);
  sm = __shfl(sm, 0);
  float mu = sm * (1.0f / 256.0f);
  float dx = v.x - mu, dy = v.y - mu, dz = v.z - mu, dw = v.w - mu;
  float q = dx * dx + dy * dy + dz * dz + dw * dw;
  #pragma unroll
  for (int off = 32; off; off >>= 1) q += __shfl_down(q, off);
  q = __shfl(q, 0);
  float rs = rsqrtf(q * (1.0f / 256.0f) + 1e-5f);
  float4 gg = *(const float4*)(n2g + s * 256 + c4);
  float4 bb = *(const float4*)(n2b + s * 256 + c4);
  u16x4s o;
  o.x = f2bf(dx * rs * gg.x + bb.x);
  o.y = f2bf(dy * rs * gg.y + bb.y);
  o.z = f2bf(dz * rs * gg.z + bb.z);
  o.w = f2bf(dw * rs * gg.w + bb.w);
  *(u16x4s*)(T1 + (size_t)row * 256 + c4) = o;
}

// ---------------- host ----------------
extern "C" void kernel_launch(void* const* d_in, const int* in_sizes, int n_in,
                              void* d_out, int out_size, void* d_ws, size_t ws_size,
                              hipStream_t stream) {
  const float* x1 = (const float*)d_in[0];
  const float* x2 = (const float*)d_in[1];
  const float* x3 = (const float*)d_in[2];
  const float* x4 = (const float*)d_in[3];
  const float* x5 = (const float*)d_in[4];
  const float* cpe_w  = (const float*)d_in[5];
  const float* cpe_b  = (const float*)d_in[6];
  const float* n1_g   = (const float*)d_in[7];
  const float* n1_b   = (const float*)d_in[8];
  const float* qkv_w  = (const float*)d_in[9];
  const float* proj_w = (const float*)d_in[10];
  const float* proj_b = (const float*)d_in[11];
  const float* crpe_w3 = (const float*)d_in[12];
  const float* crpe_b3 = (const float*)d_in[13];
  const float* crpe_w5 = (const float*)d_in[14];
  const float* crpe_b5 = (const float*)d_in[15];
  const float* crpe_w7 = (const float*)d_in[16];
  const float* crpe_b7 = (const float*)d_in[17];
  const float* n2_g   = (const float*)d_in[18];
  const float* n2_b   = (const float*)d_in[19];
  const float* fc1_w  = (const float*)d_in[20];
  const float* fc1_b  = (const float*)d_in[21];
  const float* fc2_w  = (const float*)d_in[22];
  const float* fc2_b  = (const float*)d_in[23];

  float* ws = (float*)d_ws;
  float* XI   = ws;                              // 9,437,184 f32
  float* CC   = XI + 9437184;                    // 9,437,184 f32
  u16*   T1   = (u16*)(CC + 9437184);            // MP*256 u16 = 4,718,592 f32
  float* REG  = (float*)(T1 + 9437184);          // phase-1 region / T2 overlay
  u16*   Q16  = (u16*)REG;                       // MP*256 u16
  u16*   KP   = Q16 + 9437184;                   // 9,437,184 u16
  u16*   VP   = KP + 9437184;                    // 9,437,184 u16
  u16*   VPI  = VP + 9437184;                    // 13,762,560 u16
  u16*   CVPI = VPI + 13762560;                  // 13,762,560 u16
  float* PRT  = (float*)CVPI;                    // overlay (kv partials, dead before crpe)
  u16*   T2   = (u16*)REG;                       // phase-3 overlay: MP*1024 u16
  float* MX   = (float*)(CVPI + 13762560);       // 8,192
  float* SE   = MX + 8192;                       // 8,192
  float* KV   = SE + 8192;                       // 262,144
  u16*   WQ   = (u16*)(KV + 262144);             // 786,432 u16
  u16*   WP   = WQ + 786432;
  u16*   W1   = WP + 262144;
  u16*   W2   = W1 + 262144;
  float* WT   = (float*)(W2 + 262144);           // 9,216 f32

  float* out = (float*)d_out;

  hipMemsetAsync(VPI, 0, 13762560ull * 2, stream);
  cvt_bf16<<<1536, 256, 0, stream>>>(qkv_w, WQ, 786432);
  cvt_bf16<<<512, 256, 0, stream>>>(proj_w, WP, 262144);
  cvt_bf16<<<512, 256, 0, stream>>>(fc1_w, W1, 262144);
  cvt_bf16<<<512, 256, 0, stream>>>(fc2_w, W2, 262144);
  tpw_cpe<<<dim3(9, 4), 256, 0, stream>>>(cpe_w, WT);

  copy_f4<<<8192, 256, 0, stream>>>((const float4*)x1, (float4*)out, 25692160 / 4);

  // phase 1a: fused CPE + LN1
  cpe_ln_all<<<MP / 4, 256, 0, stream>>>(x2, x3, x4, x5, WT, cpe_b, n1_g, n1_b, XI, T1);

  // phase 1b: qkv GEMM with layout-writing epilogue (288 m-tiles x 6 col-tiles)
  qkv_gemm<<<288 * 6, 256, 0, stream>>>(T1, WQ, Q16, KP, VP, VPI);

  // phase 1c: attention mid-section
  ksm_all<<<dim3(64, 8, 4), 256, 0, stream>>>(KP, MX, SE);
  kv_partial_all<<<2752, 1024, 0, stream>>>(KP, VP, MX, PRT);
  kv_reduce_all<<<dim3(64, 4), 1024, 0, stream>>>(PRT, SE, KV);
  crpe_all<3, 0><<<dim3(64, 8, 5), 256, 0, stream>>>(VPI, crpe_w3, crpe_b3, CVPI, 64);
  crpe_all<5, 64><<<dim3(96, 8, 5), 256, 0, stream>>>(VPI, crpe_w5, crpe_b5, CVPI, 96);
  crpe_all<7, 160><<<dim3(96, 8, 5), 256, 0, stream>>>(VPI, crpe_w7, crpe_b7, CVPI, 96);
  att_all<<<dim3(197, 8, 4), 256, 0, stream>>>(Q16, CVPI, KV, T1);

  // phase 1d: proj GEMM (f32 -> CC)
  proj_gemm<<<288 * 2, 256, 0, stream>>>(T1, WP, proj_b, CC);

  // phase 2: fused combine + LN2
  combine_ln_all<<<MP / 4, 256, 0, stream>>>(XI, CC, n2_g, n2_b, T1);

  // phase 3: MLP
  gemm_std<true, true><<<288 * 8, 256, 0, stream>>>(T1, W1, fc1_b, (void*)T2, 256, 1024, 8);
  fc2_gemm<<<288 * 2, 256, 0, stream>>>(T2, W2, fc2_b, XI, out);
}

// Round 10
// 446.465 us; speedup vs baseline: 5.4739x; 1.0960x over previous
//
#include <hip/hip_runtime.h>
#include <math.h>

typedef unsigned short u16;
typedef __attribute__((ext_vector_type(8))) short bf16x8;
typedef __attribute__((ext_vector_type(4))) float f32x4;

// padded row space: per (s,b) tokens padded to NPAD; M' = 36864 = 288*128
#define MP 36864
#define OUTOFF0 25692160ull

#define DEV __device__ __forceinline__
#define AS1 __attribute__((address_space(1)))
#define AS3 __attribute__((address_space(3)))

DEV u16 f2bf(float x) {
  union { float f; unsigned u; } v; v.f = x;
  unsigned r = v.u + 0x7fffu + ((v.u >> 16) & 1u);
  return (u16)(r >> 16);
}
DEV float bf2f(u16 x) {
  union { unsigned u; float f; } v; v.u = ((unsigned)x) << 16;
  return v.f;
}

struct alignas(8) u16x4s { u16 x, y, z, w; };
struct alignas(16) U16x8 { u16 d[8]; };

DEV int rs_s(int row)   { return (row >= 25600) + (row >= 33792) + (row >= 35840); }
DEV int selPB(int s)    { return s == 0 ? 0 : s == 1 ? 25600 : s == 2 ? 33792 : 35840; }
DEV int selNPAD(int s)  { return s == 0 ? 3200 : s == 1 ? 1024 : s == 2 ? 256 : 128; }
DEV int selN(int s)     { return s == 0 ? 3137 : s == 1 ? 785 : s == 2 ? 197 : 50; }
DEV int selH(int s)     { return s == 0 ? 56 : s == 1 ? 28 : s == 2 ? 14 : 7; }
DEV int selRO(int s)    { return s == 0 ? 0 : s == 1 ? 25096 : s == 2 ? 31376 : 32952; }
DEV size_t selKPB(int s){ return s == 0 ? 0ull : s == 1 ? 6553600ull : s == 2 ? 8650752ull : 9175040ull; }
DEV size_t selVPB(int s){ return s == 0 ? 0ull : s == 1 ? 7340032ull : s == 2 ? 11010048ull : 12845056ull; }
DEV int selNC(int s)    { return s == 0 ? 32 : s == 1 ? 8 : s == 2 ? 2 : 1; }
DEV int selNCB(int s)   { return s == 0 ? 0 : s == 1 ? 2048 : s == 2 ? 2560 : 2688; }

DEV void sbn(int row, int s, int& b, int& n) {
  int l = row - selPB(s);
  if (s == 0)      { b = l / 3200; n = l - b * 3200; }
  else if (s == 1) { b = l >> 10; n = l & 1023; }
  else if (s == 2) { b = l >> 8;  n = l & 255; }
  else             { b = l >> 7;  n = l & 127; }
}

DEV int xcd_swizzle(int orig, int nblk) {
  int q = nblk >> 3, r = nblk & 7;
  int xcd = orig & 7, lin = orig >> 3;
  return (xcd < r ? xcd * (q + 1) : r * (q + 1) + (xcd - r) * q) + lin;
}

// ---------------- small prep kernels ----------------
__global__ void cvt_all(const float* __restrict__ qkv_w, const float* __restrict__ proj_w,
                        const float* __restrict__ fc1_w, const float* __restrict__ fc2_w,
                        u16* __restrict__ WQ, u16* __restrict__ WP,
                        u16* __restrict__ W1, u16* __restrict__ W2) {
  int i = blockIdx.x * 256 + threadIdx.x;
  if (i < 786432) WQ[i] = f2bf(qkv_w[i]);
  else if (i < 1048576) WP[i - 786432] = f2bf(proj_w[i - 786432]);
  else if (i < 1310720) W1[i - 1048576] = f2bf(fc1_w[i - 1048576]);
  else if (i < 1572864) W2[i - 1310720] = f2bf(fc2_w[i - 1310720]);
}

__global__ void tpw_cpe(const float* __restrict__ src, float* __restrict__ dst) {
  int i = blockIdx.y;
  int e = blockIdx.x * 256 + threadIdx.x;
  if (e < 2304) {
    int c = e / 9, k = e % 9;
    dst[i * 2304 + k * 256 + c] = src[i * 2304 + c * 9 + k];
  }
}

__global__ void copy_f4(const float4* __restrict__ src, float4* __restrict__ dst, int n4) {
  for (int i = blockIdx.x * blockDim.x + threadIdx.x; i < n4; i += gridDim.x * blockDim.x)
    dst[i] = src[i];
}

// ---------------- fused CPE + LN1 (wave per padded row) ----------------
__global__ void cpe_ln_all(const float* __restrict__ x2, const float* __restrict__ x3,
                           const float* __restrict__ x4, const float* __restrict__ x5,
                           const float* __restrict__ WT, const float* __restrict__ cpe_b,
                           const float* __restrict__ n1g, const float* __restrict__ n1b,
                           float* __restrict__ XI, u16* __restrict__ T1) {
  int wid = threadIdx.x >> 6, lane = threadIdx.x & 63;
  int row = blockIdx.x * 4 + wid;
  if (row >= MP) return;
  int s = rs_s(row);
  int b, n; sbn(row, s, b, n);
  int N = selN(s), H = selH(s);
  int c4 = lane * 4;
  float4 v = make_float4(0.f, 0.f, 0.f, 0.f);
  if (n < N) {
    const float* x = s == 0 ? x2 : s == 1 ? x3 : s == 2 ? x4 : x5;
    v = *(const float4*)(x + ((size_t)b * N + n) * 256 + c4);
    if (n > 0) {
      int p = n - 1, h0 = p / H, w0 = p % H;
      float4 acc = *(const float4*)(cpe_b + s * 256 + c4);
      const float* wT = WT + s * 2304;
      #pragma unroll
      for (int kh = 0; kh < 3; ++kh) {
        int hh = h0 + kh - 1;
        if (hh < 0 || hh >= H) continue;
        #pragma unroll
        for (int kw = 0; kw < 3; ++kw) {
          int ww = w0 + kw - 1;
          if (ww < 0 || ww >= H) continue;
          float4 t = *(const float4*)(x + ((size_t)b * N + 1 + hh * H + ww) * 256 + c4);
          float4 wv = *(const float4*)(wT + (kh * 3 + kw) * 256 + c4);
          acc.x += t.x * wv.x; acc.y += t.y * wv.y;
          acc.z += t.z * wv.z; acc.w += t.w * wv.w;
        }
      }
      v.x += acc.x; v.y += acc.y; v.z += acc.z; v.w += acc.w;
    }
  }
  *(float4*)(XI + (size_t)row * 256 + c4) = v;
  float sm = v.x + v.y + v.z + v.w;
  #pragma unroll
  for (int off = 32; off; off >>= 1) sm += __shfl_down(sm, off);
  sm = __shfl(sm, 0);
  float mu = sm * (1.0f / 256.0f);
  float dx = v.x - mu, dy = v.y - mu, dz = v.z - mu, dw = v.w - mu;
  float q = dx * dx + dy * dy + dz * dz + dw * dw;
  #pragma unroll
  for (int off = 32; off; off >>= 1) q += __shfl_down(q, off);
  q = __shfl(q, 0);
  float rs = rsqrtf(q * (1.0f / 256.0f) + 1e-5f);
  float4 gg = *(const float4*)(n1g + s * 256 + c4);
  float4 bb = *(const float4*)(n1b + s * 256 + c4);
  u16x4s o;
  o.x = f2bf(dx * rs * gg.x + bb.x);
  o.y = f2bf(dy * rs * gg.y + bb.y);
  o.z = f2bf(dz * rs * gg.z + bb.z);
  o.w = f2bf(dw * rs * gg.w + bb.w);
  *(u16x4s*)(T1 + (size_t)row * 256 + c4) = o;
}

// ---------------- GEMM: BK=32, 3-buffer depth-2 pipeline, counted vmcnt ----------------
DEV void stage32(const u16* __restrict__ A, const u16* __restrict__ W,
                 u16* dst, int bm, int bn, int K, int k0) {
  int t = threadIdx.x, wv = t >> 6;
  u16* aD = dst;
  u16* bD = dst + 4096;
  #pragma unroll
  for (int iss = 0; iss < 2; ++iss) {
    int sI = iss * 256 + t;
    int row = sI >> 2, g = sI & 3;
    int gel = ((g ^ (row & 3)) << 3);
    __builtin_amdgcn_global_load_lds(
        (const AS1 void*)(A + (size_t)(bm + row) * K + k0 + gel),
        (AS3 void*)(aD + (size_t)(iss * 256 + wv * 64) * 8), 16, 0, 0);
    __builtin_amdgcn_global_load_lds(
        (const AS1 void*)(W + (size_t)(bn + row) * K + k0 + gel),
        (AS3 void*)(bD + (size_t)(iss * 256 + wv * 64) * 8), 16, 0, 0);
  }
}

DEV void mainloop(const u16* __restrict__ A, const u16* __restrict__ W, int K,
                  int bm, int bn, u16* lds, f32x4 (&acc)[4][4]) {
  int t = threadIdx.x, lane = t & 63, wv = t >> 6;
  int wr = wv >> 1, wc = wv & 1;
  const int nt = K >> 5;
  stage32(A, W, lds, bm, bn, K, 0);
  stage32(A, W, lds + 8192, bm, bn, K, 32);
  int buf = 0;
  for (int tt = 0; tt < nt; ++tt) {
    // wait own stage(tt) loads complete (stage(tt+1)'s 4 may stay in flight)
    if (tt + 1 < nt) asm volatile("s_waitcnt vmcnt(4)" ::: "memory");
    else             asm volatile("s_waitcnt vmcnt(0)" ::: "memory");
    __builtin_amdgcn_s_barrier();
    asm volatile("" ::: "memory");
    if (tt + 2 < nt) {
      int nb = buf + 2; if (nb >= 3) nb -= 3;
      stage32(A, W, lds + nb * 8192, bm, bn, K, (tt + 2) << 5);
    }
    const u16* aS = lds + buf * 8192;
    const u16* bS = aS + 4096;
    bf16x8 af[4], bfr[4];
    #pragma unroll
    for (int m = 0; m < 4; ++m) {
      int row = wr * 64 + m * 16 + (lane & 15);
      int sg = (lane >> 4) ^ (row & 3);
      af[m] = *(const bf16x8*)(aS + row * 32 + sg * 8);
    }
    #pragma unroll
    for (int n = 0; n < 4; ++n) {
      int row = wc * 64 + n * 16 + (lane & 15);
      int sg = (lane >> 4) ^ (row & 3);
      bfr[n] = *(const bf16x8*)(bS + row * 32 + sg * 8);
    }
    #pragma unroll
    for (int m = 0; m < 4; ++m)
      #pragma unroll
      for (int n = 0; n < 4; ++n)
        acc[m][n] = __builtin_amdgcn_mfma_f32_16x16x32_bf16(af[m], bfr[n], acc[m][n], 0, 0, 0);
    buf += 1; if (buf >= 3) buf -= 3;
  }
}

DEV void epi_dump(const f32x4 (&acc)[4][4], int pass, float* eps) {
  int t = threadIdx.x, lane = t & 63, wv = t >> 6;
  int wr = wv >> 1, wc = wv & 1;
  if (wr != (pass >> 1)) return;
  #pragma unroll
  for (int mh = 0; mh < 2; ++mh) {
    int m = (pass & 1) * 2 + mh;
    #pragma unroll
    for (int n = 0; n < 4; ++n) {
      int col = wc * 64 + n * 16 + (lane & 15);
      #pragma unroll
      for (int rg = 0; rg < 4; ++rg)
        eps[(mh * 16 + ((lane >> 4) << 2) + rg) * 132 + col] = acc[m][n][rg];
    }
  }
}

template <bool GELU, bool BF16>
DEV void epi_rowmajor(const float* eps, int pass, void* outp, const float* bias,
                      int bm, int bn, int Nout) {
  int t = threadIdx.x;
  int lr = t >> 3, cb = (t & 7) * 4;
  int gr = bm + pass * 32 + lr;
  #pragma unroll
  for (int j = 0; j < 4; ++j) {
    int col = cb + j * 32;
    float4 f = *(const float4*)(eps + lr * 132 + col);
    int gc = bn + col;
    if (bias) {
      float4 bv = *(const float4*)(bias + gc);
      f.x += bv.x; f.y += bv.y; f.z += bv.z; f.w += bv.w;
    }
    if (GELU) {
      f.x /= (1.0f + __expf(-1.702f * f.x));
      f.y /= (1.0f + __expf(-1.702f * f.y));
      f.z /= (1.0f + __expf(-1.702f * f.z));
      f.w /= (1.0f + __expf(-1.702f * f.w));
    }
    if (BF16) {
      u16x4s p;
      p.x = f2bf(f.x); p.y = f2bf(f.y); p.z = f2bf(f.z); p.w = f2bf(f.w);
      *(u16x4s*)((u16*)outp + (size_t)gr * Nout + gc) = p;
    } else {
      *(float4*)((float*)outp + (size_t)gr * Nout + gc) = f;
    }
  }
}

// ---------------- standard GEMM (fc1) ----------------
template <bool GELU, bool BF16>
__launch_bounds__(256, 3)
__global__ void gemm_std(const u16* __restrict__ A, const u16* __restrict__ W,
                         const float* __restrict__ bias, void* __restrict__ outp,
                         int K, int Nout, int nnt) {
  __shared__ __align__(16) u16 lds[24576];
  int wg = xcd_swizzle(blockIdx.x, gridDim.x);
  int bm = (wg / nnt) << 7, bn = (wg % nnt) << 7;
  f32x4 acc[4][4] = {};
  mainloop(A, W, K, bm, bn, lds, acc);
  float* eps = (float*)lds;
  #pragma unroll
  for (int pass = 0; pass < 4; ++pass) {
    __syncthreads();
    epi_dump(acc, pass, eps);
    __syncthreads();
    epi_rowmajor<GELU, BF16>(eps, pass, outp, bias, bm, bn, Nout);
  }
}

// ---------------- qkv GEMM: q row-major bf16; k,v planar-transposed ----------------
__launch_bounds__(256, 3)
__global__ void qkv_gemm(const u16* __restrict__ A, const u16* __restrict__ WQ,
                         u16* __restrict__ Q16, u16* __restrict__ KP,
                         u16* __restrict__ VP) {
  __shared__ __align__(16) u16 lds[24576];
  int wg = xcd_swizzle(blockIdx.x, gridDim.x);
  int mt = wg / 6, ct = wg % 6;
  int bm = mt << 7, bn = ct << 7;
  int s = rs_s(bm);
  f32x4 acc[4][4] = {};
  mainloop(A, WQ + (size_t)s * 196608, 256, bm, bn, lds, acc);
  float* eps = (float*)lds;
  int b, nb; sbn(bm, s, b, nb);
  int NPAD = selNPAD(s);
  #pragma unroll
  for (int pass = 0; pass < 4; ++pass) {
    __syncthreads();
    epi_dump(acc, pass, eps);
    __syncthreads();
    if (ct < 2) {
      epi_rowmajor<false, true>(eps, pass, Q16, nullptr, bm, bn, 256);
    } else {
      int t = threadIdx.x;
      int c = t >> 1, half = t & 1;
      bool isK = (ct < 4);
      int cg = bn - (isK ? 256 : 512) + c;
      int n0 = nb + pass * 32 + half * 16;
      float vals[16];
      #pragma unroll
      for (int r = 0; r < 16; ++r) vals[r] = eps[(half * 16 + r) * 132 + c];
      U16x8 p0, p1;
      #pragma unroll
      for (int e = 0; e < 8; ++e) { p0.d[e] = f2bf(vals[e]); p1.d[e] = f2bf(vals[8 + e]); }
      u16* pbase = (isK ? KP : VP) + selKPB(s) + (size_t)(b * 256 + cg) * NPAD + n0;
      *(U16x8*)pbase = p0;
      *(U16x8*)(pbase + 8) = p1;
    }
  }
}

// ---------------- proj GEMM ----------------
__launch_bounds__(256, 3)
__global__ void proj_gemm(const u16* __restrict__ A, const u16* __restrict__ WP,
                          const float* __restrict__ proj_b, float* __restrict__ CC) {
  __shared__ __align__(16) u16 lds[24576];
  int wg = xcd_swizzle(blockIdx.x, gridDim.x);
  int bm = (wg >> 1) << 7, bn = (wg & 1) << 7;
  int s = rs_s(bm);
  f32x4 acc[4][4] = {};
  mainloop(A, WP + (size_t)s * 65536, 256, bm, bn, lds, acc);
  float* eps = (float*)lds;
  #pragma unroll
  for (int pass = 0; pass < 4; ++pass) {
    __syncthreads();
    epi_dump(acc, pass, eps);
    __syncthreads();
    epi_rowmajor<false, false>(eps, pass, CC, proj_b + s * 256, bm, bn, 256);
  }
}

// ---------------- fc2 GEMM: +bias +XI residual, remapped f32 out ----------------
__launch_bounds__(256, 3)
__global__ void fc2_gemm(const u16* __restrict__ A, const u16* __restrict__ W2,
                         const float* __restrict__ fc2_b, const float* __restrict__ XI,
                         float* __restrict__ out) {
  __shared__ __align__(16) u16 lds[24576];
  int wg = xcd_swizzle(blockIdx.x, gridDim.x);
  int bm = (wg >> 1) << 7, bn = (wg & 1) << 7;
  f32x4 acc[4][4] = {};
  mainloop(A, W2, 1024, bm, bn, lds, acc);
  float* eps = (float*)lds;
  int s = rs_s(bm);
  int b, nb; sbn(bm, s, b, nb);
  int N = selN(s), RO = selRO(s);
  #pragma unroll
  for (int pass = 0; pass < 4; ++pass) {
    __syncthreads();
    epi_dump(acc, pass, eps);
    __syncthreads();
    int t = threadIdx.x;
    int lr = t >> 3, cb = (t & 7) * 4;
    int n = nb + pass * 32 + lr;
    if (n >= N) continue;
    int prow = bm + pass * 32 + lr;
    size_t orow = (size_t)RO + (size_t)b * N + n;
    #pragma unroll
    for (int j = 0; j < 4; ++j) {
      int col = cb + j * 32;
      float4 f = *(const float4*)(eps + lr * 132 + col);
      int gc = bn + col;
      float4 bv = *(const float4*)(fc2_b + gc);
      float4 rv = *(const float4*)(XI + (size_t)prow * 256 + gc);
      f.x += bv.x + rv.x; f.y += bv.y + rv.y;
      f.z += bv.z + rv.z; f.w += bv.w + rv.w;
      *(float4*)(out + OUTOFF0 + orow * 256 + gc) = f;
    }
  }
}

// ---------------- padded V-image from planar VP (coalesced) ----------------
__global__ void vimg_fill(const u16* __restrict__ VP, u16* __restrict__ VPI) {
  int plane = blockIdx.x;            // 8192 planes: s = plane>>11, pc = plane&2047
  int s = plane >> 11;
  int pc = plane & 2047;
  int H = selH(s), NPAD = selNPAD(s);
  const u16* vp = VP + selKPB(s) + (size_t)pc * NPAD;
  u16* vi = VPI + selVPB(s) + (size_t)pc * (H * 64);
  int tot = H * 64;
  for (int e = threadIdx.x; e < tot; e += 256) {
    int h = e >> 6, w = e & 63;
    vi[e] = (w < H) ? vp[1 + h * H + w] : (u16)0;
  }
}

// ---------------- k softmax stats ----------------
__global__ void ksm_all(const u16* __restrict__ KP, float* __restrict__ mx,
                        float* __restrict__ se) {
  int s = blockIdx.z, b = blockIdx.y;
  int N = selN(s), NPAD = selNPAD(s);
  int wv = threadIdx.x >> 6, lane = threadIdx.x & 63;
  int cg = blockIdx.x * 4 + wv;
  const u16* kp = KP + selKPB(s) + (size_t)(b * 256 + cg) * NPAD;
  float m = -1e30f, sm = 0.f;
  for (int n = lane; n < N; n += 64) {
    float v = bf2f(kp[n]);
    float nm = fmaxf(m, v);
    sm = sm * __expf(m - nm) + __expf(v - nm);
    m = nm;
  }
  #pragma unroll
  for (int off = 1; off < 64; off <<= 1) {
    float mo = __shfl_xor(m, off), so = __shfl_xor(sm, off);
    float nm = fmaxf(m, mo);
    sm = sm * __expf(m - nm) + so * __expf(mo - nm);
    m = nm;
  }
  if (lane == 0) { mx[s * 2048 + b * 256 + cg] = m; se[s * 2048 + b * 256 + cg] = sm; }
}

// ---------------- kv partials ----------------
__launch_bounds__(1024)
__global__ void kv_partial_all(const u16* __restrict__ KP, const u16* __restrict__ VP,
                               const float* __restrict__ mx, float* __restrict__ part) {
  __shared__ float kl[32][65];
  __shared__ float vl[32][65];
  int blk = blockIdx.x;
  int s = (blk >= selNCB(1)) + (blk >= selNCB(2)) + (blk >= selNCB(3));
  int local = blk - selNCB(s);
  int NC = selNC(s);
  int chunk = local % NC;
  int bh = local / NC;
  int b = bh >> 3, h = bh & 7;
  int N = selN(s), NPAD = selNPAD(s);
  int chunkrows = (N + NC - 1) / NC;
  const u16* kpb = KP + selKPB(s);
  const u16* vpb = VP + selKPB(s);
  int t = threadIdx.x;
  int i = t >> 5, j = t & 31;
  float acc = 0.f;
  int n0s = chunk * chunkrows, n1s = min(N, n0s + chunkrows);
  for (int n0 = n0s; n0 < n1s; n0 += 64) {
    #pragma unroll
    for (int e = t; e < 2048; e += 1024) {
      int c = e >> 6, nn = e & 63;
      int n = n0 + nn;
      bool ok = (n < n1s);
      kl[c][nn] = ok ? bf2f(kpb[(size_t)(b * 256 + h * 32 + c) * NPAD + n]) : -1e30f;
      vl[c][nn] = ok ? bf2f(vpb[(size_t)(b * 256 + h * 32 + c) * NPAD + n]) : 0.f;
    }
    __syncthreads();
    #pragma unroll
    for (int e = t; e < 2048; e += 1024) {
      int c = e >> 6, nn = e & 63;
      kl[c][nn] = __expf(kl[c][nn] - mx[s * 2048 + b * 256 + h * 32 + c]);
    }
    __syncthreads();
    #pragma unroll
    for (int nn = 0; nn < 64; ++nn) acc += kl[i][nn] * vl[j][nn];
    __syncthreads();
  }
  part[(size_t)blk * 1024 + t] = acc;
}

__global__ void kv_reduce_all(const float* __restrict__ part, const float* __restrict__ se,
                              float* __restrict__ kv) {
  int bh = blockIdx.x, s = blockIdx.y;
  int NC = selNC(s), base = selNCB(s);
  int t = threadIdx.x;
  int i = t >> 5;
  int b = bh >> 3, h = bh & 7;
  float sm = 0.f;
  for (int c = 0; c < NC; ++c) sm += part[(size_t)(base + bh * NC + c) * 1024 + t];
  kv[(size_t)s * 65536 + bh * 1024 + t] = sm / se[s * 2048 + b * 256 + h * 32 + i];
}

// ---------------- CRPE depthwise conv on padded planes ----------------
template <int KS, int C0>
__global__ void crpe_all(const u16* __restrict__ VPI, const float* __restrict__ w,
                         const float* __restrict__ bias, u16* __restrict__ CVPI, int CS) {
  constexpr int pad = KS / 2;
  int z = blockIdx.z;
  int s = (z >= 2) + (z >= 3) + (z >= 4);
  int sub = z - (s == 0 ? 0 : s + 1);
  int RS = (s == 0) ? 2 : 1;
  int H = selH(s);
  int c = blockIdx.x, b = blockIdx.y;
  int G = (H + 7) >> 3;
  int hpb = (H + RS - 1) / RS;
  int h0b = sub * hpb;
  int h1b = min(H, h0b + hpb);
  size_t plane = selVPB(s) + (size_t)(b * 256 + C0 + c) * (size_t)(H * 64);
  const u16* vp = VPI + plane;
  u16* op = CVPI + plane;
  float wreg[KS * KS];
  #pragma unroll
  for (int e = 0; e < KS * KS; ++e) wreg[e] = w[(s * CS + c) * KS * KS + e];
  float bb = bias[s * CS + c];
  int ntask = (h1b - h0b) * G;
  for (int task = threadIdx.x; task < ntask; task += 256) {
    int g = task % G;
    int h = h0b + task / G;
    int w0 = g << 3;
    float o[8];
    #pragma unroll
    for (int e = 0; e < 8; ++e) o[e] = bb;
    #pragma unroll
    for (int kh = 0; kh < KS; ++kh) {
      int hh = h + kh - pad;
      if (hh < 0 || hh >= H) continue;
      const u16* rowp = vp + hh * 64;
      U16x8 ch0 = {}, ch1, ch2;
      if (w0 >= 8) ch0 = *(const U16x8*)(rowp + w0 - 8);
      ch1 = *(const U16x8*)(rowp + w0);
      ch2 = *(const U16x8*)(rowp + w0 + 8);
      float tv[24];
      #pragma unroll
      for (int j2 = 8 - pad; j2 <= 15 + pad; ++j2) {
        u16 raw = (j2 < 8) ? ch0.d[j2] : (j2 < 16 ? ch1.d[j2 - 8] : ch2.d[j2 - 16]);
        tv[j2] = bf2f(raw);
      }
      #pragma unroll
      for (int kw = 0; kw < KS; ++kw) {
        float wv = wreg[kh * KS + kw];
        #pragma unroll
        for (int e = 0; e < 8; ++e) o[e] += tv[8 + e + kw - pad] * wv;
      }
    }
    U16x8 pk;
    #pragma unroll
    for (int e = 0; e < 8; ++e) pk.d[e] = f2bf(o[e]);
    *(U16x8*)(op + h * 64 + w0) = pk;
  }
}

// ---------------- att: attp = CH^-0.5 * (q @ kv) + q * conv_v ----------------
__global__ void att_all(const u16* __restrict__ Q16, const u16* __restrict__ CVPI,
                        const float* __restrict__ kvg, u16* __restrict__ attp) {
  int s = blockIdx.z, b = blockIdx.y;
  int N = selN(s), H = selH(s);
  int n0 = blockIdx.x * 16;
  if (n0 >= N) return;
  __shared__ float kvl[8192];
  __shared__ float ql[256];
  __shared__ float cl[16][260];
  int t = threadIdx.x;
  int hw64 = H * 64;
  size_t rowbase = (size_t)selPB(s) + (size_t)b * selNPAD(s);
  const u16* cvb = CVPI + selVPB(s);
  for (int e = t; e < 8192; e += 256) kvl[e] = kvg[(size_t)s * 65536 + b * 8192 + e];
  for (int e = t; e < 4096; e += 256) {
    int c = e >> 4, nn = e & 15;
    int n = n0 + nn;
    float v = 0.f;
    if (n >= 1 && n < N) {
      int p = n - 1;
      v = bf2f(cvb[(size_t)(b * 256 + c) * hw64 + (p / H) * 64 + (p % H)]);
    }
    cl[nn][c] = v;
  }
  int h = t >> 5, j = t & 31;
  for (int nn = 0; nn < 16; ++nn) {
    int n = n0 + nn;
    if (n >= N) break;
    __syncthreads();
    ql[t] = bf2f(Q16[(rowbase + n) * 256 + t]);
    __syncthreads();
    float fa = 0.f;
    const float* kvh = kvl + h * 1024;
    #pragma unroll
    for (int k = 0; k < 32; ++k) fa += ql[h * 32 + k] * kvh[k * 32 + j];
    float v = 0.17677669529663687f * fa + ql[t] * cl[nn][t];
    attp[(rowbase + n) * 256 + t] = f2bf(v);
  }
}

// ---------------- fused cross-scale combine + LN2 ----------------
DEV float4 bs4(const float* __restrict__ base, int Hs, int oh, int ow, int Hi, int c4) {
  float scale = (float)Hs / (float)Hi;
  float sy = (oh + 0.5f) * scale - 0.5f;
  float sx = (ow + 0.5f) * scale - 0.5f;
  float fy0 = floorf(sy), fx0 = floorf(sx);
  float fy = sy - fy0, fx = sx - fx0;
  int y0 = (int)fy0, x0 = (int)fx0;
  int y0c = min(max(y0, 0), Hs - 1), y1c = min(max(y0 + 1, 0), Hs - 1);
  int x0c = min(max(x0, 0), Hs - 1), x1c = min(max(x0 + 1, 0), Hs - 1);
  const float* ib = base + 256 + c4;
  float4 v00 = *(const float4*)(ib + (size_t)(y0c * Hs + x0c) * 256);
  float4 v01 = *(const float4*)(ib + (size_t)(y0c * Hs + x1c) * 256);
  float4 v10 = *(const float4*)(ib + (size_t)(y1c * Hs + x0c) * 256);
  float4 v11 = *(const float4*)(ib + (size_t)(y1c * Hs + x1c) * 256);
  float w00 = (1.f - fy) * (1.f - fx), w01 = (1.f - fy) * fx;
  float w10 = fy * (1.f - fx), w11 = fy * fx;
  float4 r;
  r.x = w00 * v00.x + w01 * v01.x + w10 * v10.x + w11 * v11.x;
  r.y = w00 * v00.y + w01 * v01.y + w10 * v10.y + w11 * v11.y;
  r.z = w00 * v00.z + w01 * v01.z + w10 * v10.z + w11 * v11.z;
  r.w = w00 * v00.w + w01 * v01.w + w10 * v10.w + w11 * v11.w;
  return r;
}

__global__ void combine_ln_all(float* __restrict__ XI, const float* __restrict__ CC,
                               const float* __restrict__ n2g, const float* __restrict__ n2b,
                               u16* __restrict__ T1) {
  int wid = threadIdx.x >> 6, lane = threadIdx.x & 63;
  int row = blockIdx.x * 4 + wid;
  if (row >= MP) return;
  int s = rs_s(row);
  int b, n; sbn(row, s, b, n);
  int N = selN(s), Hi = selH(s);
  int c4 = lane * 4;
  float4 v;
  if (n < N) {
    float4 add = *(const float4*)(CC + (size_t)row * 256 + c4);
    int sa = s == 0 ? 1 : s == 1 ? 2 : s == 2 ? 3 : 2;
    int sb_ = s == 0 ? 2 : 0;
    const float* baseA = CC + ((size_t)selPB(sa) + (size_t)b * selNPAD(sa)) * 256;
    const float* baseB = CC + ((size_t)selPB(sb_) + (size_t)b * selNPAD(sb_)) * 256;
    if (n == 0) {
      float4 a = *(const float4*)(baseA + c4);
      float4 bb2 = *(const float4*)(baseB + c4);
      add.x += a.x + bb2.x; add.y += a.y + bb2.y;
      add.z += a.z + bb2.z; add.w += a.w + bb2.w;
    } else {
      int p = n - 1, oh = p / Hi, ow = p % Hi;
      float4 a = bs4(baseA, selH(sa), oh, ow, Hi, c4);
      float4 bb2 = bs4(baseB, selH(sb_), oh, ow, Hi, c4);
      add.x += a.x + bb2.x; add.y += a.y + bb2.y;
      add.z += a.z + bb2.z; add.w += a.w + bb2.w;
    }
    float* xp = XI + (size_t)row * 256 + c4;
    v = *(const float4*)xp;
    v.x += add.x; v.y += add.y; v.z += add.z; v.w += add.w;
    *(float4*)xp = v;
  } else {
    v = make_float4(0.f, 0.f, 0.f, 0.f);
  }
  float sm = v.x + v.y + v.z + v.w;
  #pragma unroll
  for (int off = 32; off; off >>= 1) sm += __shfl_down(sm, off);
  sm = __shfl(sm, 0);
  float mu = sm * (1.0f / 256.0f);
  float dx = v.x - mu, dy = v.y - mu, dz = v.z - mu, dw = v.w - mu;
  float q = dx * dx + dy * dy + dz * dz + dw * dw;
  #pragma unroll
  for (int off = 32; off; off >>= 1) q += __shfl_down(q, off);
  q = __shfl(q, 0);
  float rs = rsqrtf(q * (1.0f / 256.0f) + 1e-5f);
  float4 gg = *(const float4*)(n2g + s * 256 + c4);
  float4 bb = *(const float4*)(n2b + s * 256 + c4);
  u16x4s o;
  o.x = f2bf(dx * rs * gg.x + bb.x);
  o.y = f2bf(dy * rs * gg.y + bb.y);
  o.z = f2bf(dz * rs * gg.z + bb.z);
  o.w = f2bf(dw * rs * gg.w + bb.w);
  *(u16x4s*)(T1 + (size_t)row * 256 + c4) = o;
}

// ---------------- host ----------------
extern "C" void kernel_launch(void* const* d_in, const int* in_sizes, int n_in,
                              void* d_out, int out_size, void* d_ws, size_t ws_size,
                              hipStream_t stream) {
  const float* x1 = (const float*)d_in[0];
  const float* x2 = (const float*)d_in[1];
  const float* x3 = (const float*)d_in[2];
  const float* x4 = (const float*)d_in[3];
  const float* x5 = (const float*)d_in[4];
  const float* cpe_w  = (const float*)d_in[5];
  const float* cpe_b  = (const float*)d_in[6];
  const float* n1_g   = (const float*)d_in[7];
  const float* n1_b   = (const float*)d_in[8];
  const float* qkv_w  = (const float*)d_in[9];
  const float* proj_w = (const float*)d_in[10];
  const float* proj_b = (const float*)d_in[11];
  const float* crpe_w3 = (const float*)d_in[12];
  const float* crpe_b3 = (const float*)d_in[13];
  const float* crpe_w5 = (const float*)d_in[14];
  const float* crpe_b5 = (const float*)d_in[15];
  const float* crpe_w7 = (const float*)d_in[16];
  const float* crpe_b7 = (const float*)d_in[17];
  const float* n2_g   = (const float*)d_in[18];
  const float* n2_b   = (const float*)d_in[19];
  const float* fc1_w  = (const float*)d_in[20];
  const float* fc1_b  = (const float*)d_in[21];
  const float* fc2_w  = (const float*)d_in[22];
  const float* fc2_b  = (const float*)d_in[23];

  float* ws = (float*)d_ws;
  float* XI   = ws;                              // 9,437,184 f32
  float* CC   = XI + 9437184;                    // 9,437,184 f32
  u16*   T1   = (u16*)(CC + 9437184);            // MP*256 u16
  float* REG  = (float*)(T1 + 9437184);
  u16*   Q16  = (u16*)REG;                       // MP*256 u16
  u16*   KP   = Q16 + 9437184;                   // 9,437,184 u16
  u16*   VP   = KP + 9437184;                    // 9,437,184 u16
  u16*   VPI  = VP + 9437184;                    // 13,762,560 u16
  u16*   CVPI = VPI + 13762560;                  // 13,762,560 u16
  float* PRT  = (float*)CVPI;                    // overlay (kv partials)
  u16*   T2   = (u16*)REG;                       // phase-3 overlay: MP*1024 u16
  float* MX   = (float*)(CVPI + 13762560);       // 8,192
  float* SE   = MX + 8192;                       // 8,192
  float* KV   = SE + 8192;                       // 262,144
  u16*   WQ   = (u16*)(KV + 262144);             // 786,432 u16
  u16*   WP   = WQ + 786432;
  u16*   W1   = WP + 262144;
  u16*   W2   = W1 + 262144;
  float* WT   = (float*)(W2 + 262144);           // 9,216 f32

  float* out = (float*)d_out;

  cvt_all<<<6144, 256, 0, stream>>>(qkv_w, proj_w, fc1_w, fc2_w, WQ, WP, W1, W2);
  tpw_cpe<<<dim3(9, 4), 256, 0, stream>>>(cpe_w, WT);

  copy_f4<<<8192, 256, 0, stream>>>((const float4*)x1, (float4*)out, 25692160 / 4);

  // phase 1a: fused CPE + LN1
  cpe_ln_all<<<MP / 4, 256, 0, stream>>>(x2, x3, x4, x5, WT, cpe_b, n1_g, n1_b, XI, T1);

  // phase 1b: qkv GEMM (q row-major, k/v planar)
  qkv_gemm<<<288 * 6, 256, 0, stream>>>(T1, WQ, Q16, KP, VP);
  vimg_fill<<<8192, 256, 0, stream>>>(VP, VPI);

  // phase 1c: attention mid-section
  ksm_all<<<dim3(64, 8, 4), 256, 0, stream>>>(KP, MX, SE);
  kv_partial_all<<<2752, 1024, 0, stream>>>(KP, VP, MX, PRT);
  kv_reduce_all<<<dim3(64, 4), 1024, 0, stream>>>(PRT, SE, KV);
  crpe_all<3, 0><<<dim3(64, 8, 5), 256, 0, stream>>>(VPI, crpe_w3, crpe_b3, CVPI, 64);
  crpe_all<5, 64><<<dim3(96, 8, 5), 256, 0, stream>>>(VPI, crpe_w5, crpe_b5, CVPI, 96);
  crpe_all<7, 160><<<dim3(96, 8, 5), 256, 0, stream>>>(VPI, crpe_w7, crpe_b7, CVPI, 96);
  att_all<<<dim3(197, 8, 4), 256, 0, stream>>>(Q16, CVPI, KV, T1);

  // phase 1d: proj GEMM (f32 -> CC)
  proj_gemm<<<288 * 2, 256, 0, stream>>>(T1, WP, proj_b, CC);

  // phase 2: fused combine + LN2
  combine_ln_all<<<MP / 4, 256, 0, stream>>>(XI, CC, n2_g, n2_b, T1);

  // phase 3: MLP
  gemm_std<true, true><<<288 * 8, 256, 0, stream>>>(T1, W1, fc1_b, (void*)T2, 256, 1024, 8);
  fc2_gemm<<<288 * 2, 256, 0, stream>>>(T2, W2, fc2_b, XI, out);
}